// Round 6
// baseline (1135.945 us; speedup 1.0000x reference)
//
#include <hip/hip_runtime.h>

#define N_NODES 16384
#define N_EDGES 262144
#define TE 64   // edges per workgroup in edge kernel

typedef __attribute__((ext_vector_type(8))) __bf16 bf16x8;
typedef __attribute__((ext_vector_type(4))) __bf16 bf16x4;
typedef __attribute__((ext_vector_type(4))) float f32x4;
typedef __attribute__((ext_vector_type(16))) float f32x16;

__device__ __forceinline__ float silu_f(float x){ return x / (1.f + __expf(-x)); }

__device__ __forceinline__ f32x4 mfma16(bf16x8 a, bf16x8 b, f32x4 c){
  return __builtin_amdgcn_mfma_f32_16x16x32_bf16(a, b, c, 0, 0, 0);
}
__device__ __forceinline__ f32x16 mfma32(bf16x8 a, bf16x8 b, f32x16 c){
  return __builtin_amdgcn_mfma_f32_32x32x16_bf16(a, b, c, 0, 0, 0);
}

// ---------------------------------------------------------------- prep ----
__global__ void prep_kernel(const float* __restrict__ We1, const float* __restrict__ be1,
                            const float* __restrict__ We2,
                            const float* __restrict__ Wc1, const float* __restrict__ Wn1,
                            const float* __restrict__ Wn2,
                            __bf16* wab, __bf16* weaT, __bf16* we2b, __bf16* wc1b,
                            __bf16* wn1b, __bf16* wn2b){
  int i = blockIdx.x * 256 + threadIdx.x;
  if (i < 1024*512){
    int o = i >> 9, k = i & 511;
    float v = (o < 512) ? We1[(size_t)o*1076 + k] : We1[(size_t)(o-512)*1076 + 512 + k];
    wab[i] = (__bf16)v;
  }
  if (i < 512*64){
    int o = i >> 6, k = i & 63;
    float v = (k < 51) ? We1[(size_t)o*1076 + 1024 + k]
            : (k == 51 ? We1[(size_t)o*1076 + 1075]
            : (k == 52 ? be1[o] : 0.f));
    weaT[i] = (__bf16)v;
  }
  if (i < 512*512){ we2b[i] = (__bf16)We2[i]; wc1b[i] = (__bf16)Wc1[i]; }
  if (i < 256*1024){ wn1b[i] = (__bf16)Wn1[i]; }
  if (i < 256*256){ wn2b[i] = (__bf16)Wn2[i]; }
}

// ------------------------------------------------- counting sort by row ----
__global__ void hist_kernel(const int* __restrict__ eidx, int* __restrict__ deg){
  int e = blockIdx.x * 256 + threadIdx.x;
  if (e < N_EDGES) atomicAdd(&deg[eidx[e]], 1);
}

__global__ __launch_bounds__(1024) void scan_kernel(const int* __restrict__ deg,
                                                    int* __restrict__ base){
  __shared__ int part[1024];
  int tid = threadIdx.x;
  int b = tid * 16;
  int local[16];
  int s = 0;
  #pragma unroll
  for (int i = 0; i < 16; ++i){ local[i] = deg[b+i]; s += local[i]; }
  part[tid] = s;
  __syncthreads();
  for (int off = 1; off < 1024; off <<= 1){
    int v = 0;
    if (tid >= off) v = part[tid-off];
    __syncthreads();
    part[tid] += v;
    __syncthreads();
  }
  int run = part[tid] - s;   // exclusive prefix of this chunk
  #pragma unroll
  for (int i = 0; i < 16; ++i){ base[b+i] = run; run += local[i]; }
}

__global__ void scatter_kernel(const int* __restrict__ eidx, const int* __restrict__ base,
                               int* __restrict__ cursor, int* __restrict__ perm){
  int e = blockIdx.x * 256 + threadIdx.x;
  if (e < N_EDGES){
    int r = eidx[e];
    int p = atomicAdd(&cursor[r], 1);
    perm[base[r] + p] = e;
  }
}

// ------------------------------------------------------------- gemm AB ----
__global__ __launch_bounds__(256) void gemm_ab_kernel(const float* __restrict__ h,
                                                      const __bf16* __restrict__ wab,
                                                      __bf16* __restrict__ AB){
  __shared__ __align__(16) __bf16 At[64*512];  // 64KB, swizzled
  int tid = threadIdx.x;
  int r0 = blockIdx.x * 64;
  char* ab = (char*)At;
  for (int it = 0; it < 32; ++it){
    int idx = it*1024 + tid*4;
    int row = idx >> 9, col = idx & 511;
    float4 v = *reinterpret_cast<const float4*>(h + (size_t)(r0+row)*512 + col);
    bf16x4 p = {(__bf16)v.x, (__bf16)v.y, (__bf16)v.z, (__bf16)v.w};
    *reinterpret_cast<bf16x4*>(ab + row*1024 + ((col*2) ^ ((row&7)<<4))) = p;
  }
  __syncthreads();
  int lane = tid & 63, wid = tid >> 6;
  int col16 = lane & 15, g = lane >> 4;
  int arow = wid*16 + col16;
  for (int cc = 0; cc < 8; ++cc){
    f32x4 acc[8];
    #pragma unroll
    for (int t = 0; t < 8; ++t) acc[t] = f32x4{0.f,0.f,0.f,0.f};
    for (int kk = 0; kk < 16; ++kk){
      bf16x8 af = *reinterpret_cast<const bf16x8*>(ab + arow*1024 + ((kk*64 + g*16) ^ ((arow&7)<<4)));
      #pragma unroll
      for (int t = 0; t < 8; ++t){
        int oc = cc*128 + t*16 + col16;
        bf16x8 bfr = *reinterpret_cast<const bf16x8*>(wab + (size_t)oc*512 + kk*32 + g*8);
        acc[t] = mfma16(af, bfr, acc[t]);
      }
    }
    #pragma unroll
    for (int t = 0; t < 8; ++t){
      int oc = cc*128 + t*16 + col16;
      #pragma unroll
      for (int i2 = 0; i2 < 4; ++i2){
        int row = r0 + wid*16 + g*4 + i2;
        AB[(size_t)row*1024 + oc] = (__bf16)acc[t][i2];
      }
    }
  }
}

// --------------------------------------- K=512 phase, SWAPPED operands ----
// mfma(b, a): D rows = weight out-cols (reg-pattern), D cols = edges (lane).
// 4-deep register ring prefetch of B fragments.
__device__ __forceinline__ void gemm_phase_sw(const char* e1b, const __bf16* __restrict__ Brow,
                                              int c31, int hi, f32x16 acc[2][2]){
  bf16x8 bq[4][2];
  #pragma unroll
  for (int s = 0; s < 4; ++s)
    #pragma unroll
    for (int ct = 0; ct < 2; ++ct)
      bq[s][ct] = *reinterpret_cast<const bf16x8*>(Brow + s*16 + ct*16384);
  for (int kkb = 0; kkb < 8; ++kkb){
    #pragma unroll
    for (int s = 0; s < 4; ++s){
      int kk = kkb*4 + s;
      bf16x8 af[2];
      #pragma unroll
      for (int rt = 0; rt < 2; ++rt){
        int arow = rt*32 + c31;
        af[rt] = *reinterpret_cast<const bf16x8*>(e1b + arow*1024 + ((kk*32 + hi*16) ^ ((arow&7)<<4)));
      }
      #pragma unroll
      for (int ct = 0; ct < 2; ++ct)
        #pragma unroll
        for (int rt = 0; rt < 2; ++rt)
          acc[rt][ct] = mfma32(bq[s][ct], af[rt], acc[rt][ct]);
      if (kkb < 7){
        #pragma unroll
        for (int ct = 0; ct < 2; ++ct)
          bq[s][ct] = *reinterpret_cast<const bf16x8*>(Brow + (kk+4)*16 + ct*16384);
      }
    }
  }
}

// ------------------------------------------------------- fused edge op ----
__global__ __launch_bounds__(512, 4) void edge_kernel(
    const int* __restrict__ eidx, const int* __restrict__ perm,
    const float* __restrict__ edge_attr,
    const float* __restrict__ pos,
    const __bf16* __restrict__ AB, const __bf16* __restrict__ weaT,
    const __bf16* __restrict__ we2b, const __bf16* __restrict__ wc1b,
    const float* __restrict__ b2,
    const float* __restrict__ bc1, const float* __restrict__ wc2,
    float* __restrict__ agg, float* __restrict__ pos_out)
{
  __shared__ __align__(16) __bf16 e1t[TE*512];   // 64KB swizzled (e1, later e2)
  __shared__ __align__(16) __bf16 eat[TE*64];    // 8KB  swizzled (ea|radial|1|pad)
  __shared__ float diffs[3][TE];
  __shared__ float rad[TE];
  __shared__ int   rl[TE], cl[TE], el[TE];
  __shared__ float cupart[8][TE];
  __shared__ float cuf[TE];
  __shared__ unsigned long long segmask;

  int tid = threadIdx.x;
  // XCD-aware bijective swizzle: 4096 tiles = 8 XCDs x 512
  int bid = blockIdx.x;
  int tile = ((bid & 7) << 9) | (bid >> 3);
  int e0 = tile * TE;

  if (tid < TE){
    int eid = perm[e0 + tid];
    el[tid] = eid;
    int r = eidx[eid], c = eidx[N_EDGES + eid];
    rl[tid] = r; cl[tid] = c;
    float dx = pos[r*3+0]-pos[c*3+0];
    float dy = pos[r*3+1]-pos[c*3+1];
    float dz = pos[r*3+2]-pos[c*3+2];
    diffs[0][tid]=dx; diffs[1][tid]=dy; diffs[2][tid]=dz;
    float rr = dx*dx + dy*dy + dz*dz;
    rad[tid] = fminf(fmaxf(rr, 1e-8f), 100.f);
  }
  __syncthreads();

  // segment-boundary mask over the sorted 64 rows (wave 0 only)
  if (tid < 64){
    unsigned long long m = __ballot(tid > 0 && rl[tid] != rl[tid-1]);
    if (tid == 0) segmask = m;
  }

  // stage edge_attr (+radial k=51, one k=52, zero pad) swizzled bf16 [TE][64]
  {
    char* eb = (char*)eat;
    for (int i = tid; i < TE*64; i += 512){
      int e = i >> 6, k = i & 63;
      float v = (k < 51) ? edge_attr[(size_t)el[e]*51 + k]
              : (k == 51 ? rad[e] : (k == 52 ? 1.0f : 0.f));
      *reinterpret_cast<__bf16*>(eb + e*128 + ((k*2) ^ ((e&7)<<4))) = (__bf16)v;
    }
  }
  // prefill e1t with gather-sum (bf16, swizzled); bias comes via weaT k=52
  {
    int e = tid >> 3, q = tid & 7;
    size_t baseR = (size_t)rl[e]*1024;
    size_t baseC = (size_t)cl[e]*1024 + 512;
    char* eb = (char*)e1t;
    #pragma unroll
    for (int c = 0; c < 8; ++c){
      int o0 = q*8 + c*64;
      bf16x8 ga = *reinterpret_cast<const bf16x8*>(AB + baseR + o0);
      bf16x8 gb = *reinterpret_cast<const bf16x8*>(AB + baseC + o0);
      bf16x8 outv;
      #pragma unroll
      for (int j = 0; j < 8; ++j) outv[j] = (__bf16)((float)ga[j] + (float)gb[j]);
      *reinterpret_cast<bf16x8*>(eb + e*1024 + ((o0*2) ^ ((e&7)<<4))) = outv;
    }
  }
  __syncthreads();

  int lane = tid & 63, wid = tid >> 6;
  int c31 = lane & 31, hi = lane >> 5;
  int colbase = wid * 64;
  char* e1b = (char*)e1t;

  // P0: e1 = silu(prefill + ea@Wea^T) — swapped operands, vectorized b64 RMW
  {
    f32x16 acc[2][2];
    #pragma unroll
    for (int rt = 0; rt < 2; ++rt)
      #pragma unroll
      for (int ct = 0; ct < 2; ++ct)
        #pragma unroll
        for (int r = 0; r < 16; ++r) acc[rt][ct][r] = 0.f;
    const char* eb = (const char*)eat;
    #pragma unroll
    for (int kk = 0; kk < 4; ++kk){
      bf16x8 af[2];
      #pragma unroll
      for (int rt = 0; rt < 2; ++rt){
        int arow = rt*32 + c31;
        af[rt] = *reinterpret_cast<const bf16x8*>(eb + arow*128 + ((kk*32 + hi*16) ^ ((arow&7)<<4)));
      }
      #pragma unroll
      for (int ct = 0; ct < 2; ++ct){
        int oc = colbase + ct*32 + c31;
        bf16x8 bfr = *reinterpret_cast<const bf16x8*>(weaT + (size_t)oc*64 + kk*16 + hi*8);
        #pragma unroll
        for (int rt = 0; rt < 2; ++rt) acc[rt][ct] = mfma32(bfr, af[rt], acc[rt][ct]);
      }
    }
    #pragma unroll
    for (int rt = 0; rt < 2; ++rt){
      int edge = rt*32 + c31;
      #pragma unroll
      for (int ct = 0; ct < 2; ++ct){
        #pragma unroll
        for (int q = 0; q < 4; ++q){
          int oc0 = colbase + ct*32 + 8*q + 4*hi;
          char* p = e1b + edge*1024 + ((oc0*2) ^ ((edge&7)<<4));
          bf16x4 pre = *reinterpret_cast<const bf16x4*>(p);
          bf16x4 outv;
          #pragma unroll
          for (int j = 0; j < 4; ++j){
            float v = (float)pre[j] + acc[rt][ct][4*q+j];
            outv[j] = (__bf16)silu_f(v);
          }
          *reinterpret_cast<bf16x4*>(p) = outv;
        }
      }
    }
  }
  __syncthreads();

  // P1: e2 = silu(e1 @ We2^T + b2); e2 -> e1t (vectorized b64 stores)
  {
    f32x16 acc[2][2];
    #pragma unroll
    for (int rt = 0; rt < 2; ++rt)
      #pragma unroll
      for (int ct = 0; ct < 2; ++ct)
        #pragma unroll
        for (int r = 0; r < 16; ++r) acc[rt][ct][r] = 0.f;
    gemm_phase_sw(e1b, we2b + (size_t)(colbase + c31)*512 + hi*8, c31, hi, acc);
    f32x4 b2q[2][4];
    #pragma unroll
    for (int ct = 0; ct < 2; ++ct)
      #pragma unroll
      for (int q = 0; q < 4; ++q)
        b2q[ct][q] = *reinterpret_cast<const f32x4*>(b2 + colbase + ct*32 + 8*q + 4*hi);
    __syncthreads();   // all waves done READING e1t
    #pragma unroll
    for (int rt = 0; rt < 2; ++rt){
      int edge = rt*32 + c31;
      #pragma unroll
      for (int ct = 0; ct < 2; ++ct){
        #pragma unroll
        for (int q = 0; q < 4; ++q){
          bf16x4 outv;
          #pragma unroll
          for (int j = 0; j < 4; ++j)
            outv[j] = (__bf16)silu_f(acc[rt][ct][4*q+j] + b2q[ct][q][j]);
          int oc0 = colbase + ct*32 + 8*q + 4*hi;
          *reinterpret_cast<bf16x4*>(e1b + edge*1024 + ((oc0*2) ^ ((edge&7)<<4))) = outv;
        }
      }
    }
  }
  __syncthreads();

  // P2 (+AGG overlapped with B-ring latency):
  //   AGG: 128 col-quads x 4 edge-quarters, b64 reads, segment flush atomics
  //   c1 = silu(e2 @ Wc1^T + bc1); cu = c1 . wc2 (lane-local + 1 shuffle)
  {
    const __bf16* Brow = wc1b + (size_t)(colbase + c31)*512 + hi*8;
    bf16x8 bq[4][2];
    #pragma unroll
    for (int s = 0; s < 4; ++s)
      #pragma unroll
      for (int ct = 0; ct < 2; ++ct)
        bq[s][ct] = *reinterpret_cast<const bf16x8*>(Brow + s*16 + ct*16384);
    f32x4 bcq[2][4], wcq[2][4];
    #pragma unroll
    for (int ct = 0; ct < 2; ++ct)
      #pragma unroll
      for (int q = 0; q < 4; ++q){
        bcq[ct][q] = *reinterpret_cast<const f32x4*>(bc1 + colbase + ct*32 + 8*q + 4*hi);
        wcq[ct][q] = *reinterpret_cast<const f32x4*>(wc2 + colbase + ct*32 + 8*q + 4*hi);
      }

    // ---- AGG (reads e2 from LDS while global B loads are in flight) ----
    {
      int qtr  = tid >> 7;          // 0..3 -> edges qtr*16..+15
      int colq = (tid & 127) * 4;   // 4-col group
      unsigned long long m = segmask;
      float a0=0.f, a1=0.f, a2=0.f, a3=0.f;
      int eb0 = qtr * 16;
      #pragma unroll
      for (int i = 0; i < 16; ++i){
        int e = eb0 + i;
        if (i > 0 && ((m >> e) & 1)){
          int r = rl[e-1];
          atomicAdd(&agg[(size_t)r*512 + colq+0], a0);
          atomicAdd(&agg[(size_t)r*512 + colq+1], a1);
          atomicAdd(&agg[(size_t)r*512 + colq+2], a2);
          atomicAdd(&agg[(size_t)r*512 + colq+3], a3);
          a0=a1=a2=a3=0.f;
        }
        bf16x4 v = *reinterpret_cast<const bf16x4*>(e1b + e*1024 + ((colq*2) ^ ((e&7)<<4)));
        a0 += (float)v[0]; a1 += (float)v[1]; a2 += (float)v[2]; a3 += (float)v[3];
      }
      int r = rl[eb0 + 15];
      atomicAdd(&agg[(size_t)r*512 + colq+0], a0);
      atomicAdd(&agg[(size_t)r*512 + colq+1], a1);
      atomicAdd(&agg[(size_t)r*512 + colq+2], a2);
      atomicAdd(&agg[(size_t)r*512 + colq+3], a3);
    }

    // ---- P2 GEMM (swapped) ----
    f32x16 acc[2][2];
    #pragma unroll
    for (int rt = 0; rt < 2; ++rt)
      #pragma unroll
      for (int ct = 0; ct < 2; ++ct)
        #pragma unroll
        for (int r = 0; r < 16; ++r) acc[rt][ct][r] = 0.f;
    for (int kkb = 0; kkb < 8; ++kkb){
      #pragma unroll
      for (int s = 0; s < 4; ++s){
        int kk = kkb*4 + s;
        bf16x8 af[2];
        #pragma unroll
        for (int rt = 0; rt < 2; ++rt){
          int arow = rt*32 + c31;
          af[rt] = *reinterpret_cast<const bf16x8*>(e1b + arow*1024 + ((kk*32 + hi*16) ^ ((arow&7)<<4)));
        }
        #pragma unroll
        for (int ct = 0; ct < 2; ++ct)
          #pragma unroll
          for (int rt = 0; rt < 2; ++rt)
            acc[rt][ct] = mfma32(bq[s][ct], af[rt], acc[rt][ct]);
        if (kkb < 7){
          #pragma unroll
          for (int ct = 0; ct < 2; ++ct)
            bq[s][ct] = *reinterpret_cast<const bf16x8*>(Brow + (kk+4)*16 + ct*16384);
        }
      }
    }
    // epilogue: per-lane dot with wc2 over own 32 strip cols, 1 shuffle
    #pragma unroll
    for (int rt = 0; rt < 2; ++rt){
      float pv = 0.f;
      #pragma unroll
      for (int ct = 0; ct < 2; ++ct)
        #pragma unroll
        for (int reg = 0; reg < 16; ++reg)
          pv += silu_f(acc[rt][ct][reg] + bcq[ct][reg>>2][reg&3]) * wcq[ct][reg>>2][reg&3];
      pv += __shfl_xor(pv, 32, 64);
      if (hi == 0) cupart[wid][rt*32 + c31] = pv;
    }
  }
  __syncthreads();

  if (tid < TE){
    float cu0 = 0.f;
    #pragma unroll
    for (int w = 0; w < 8; ++w) cu0 += cupart[w][tid];
    float cu = fminf(fmaxf(cu0, -1.f), 1.f);
    if (!isfinite(cu0)) cu = 0.f;
    cuf[tid] = cu;
  }
  __syncthreads();

  // POS: segmented per-axis sum (3 threads), mask-driven, unrolled
  if (tid < 3){
    int d = tid;
    unsigned long long m = segmask;
    float a = 0.f;
    #pragma unroll
    for (int e = 0; e < TE; ++e){
      if (e > 0 && ((m >> e) & 1)){
        atomicAdd(&pos_out[(size_t)rl[e-1]*3 + d], a);
        a = 0.f;
      }
      a += diffs[d][e] * cuf[e];
    }
    atomicAdd(&pos_out[(size_t)rl[TE-1]*3 + d], a);
  }
}

// ------------------------------------------------------------ node MLP ----
__global__ __launch_bounds__(256) void node1_kernel(const float* __restrict__ h,
                                                    const float* __restrict__ agg,
                                                    const __bf16* __restrict__ wn1b,
                                                    const float* __restrict__ bn1,
                                                    __bf16* __restrict__ h1){
  __shared__ __align__(16) __bf16 At[64*1024];  // 128KB, row stride 2048B, swizzled
  int tid = threadIdx.x;
  int r0 = blockIdx.x * 64;
  char* ab = (char*)At;
  for (int it = 0; it < 64; ++it){
    int idx = it*1024 + tid*4;
    int row = idx >> 10, col = idx & 1023;
    float4 v;
    if (col < 512) v = *reinterpret_cast<const float4*>(h   + (size_t)(r0+row)*512 + col);
    else           v = *reinterpret_cast<const float4*>(agg + (size_t)(r0+row)*512 + (col-512));
    bf16x4 p = {(__bf16)v.x, (__bf16)v.y, (__bf16)v.z, (__bf16)v.w};
    *reinterpret_cast<bf16x4*>(ab + row*2048 + ((col*2) ^ ((row&7)<<4))) = p;
  }
  __syncthreads();
  int lane = tid & 63, wid = tid >> 6;
  int col16 = lane & 15, g = lane >> 4;
  int arow = wid*16 + col16;
  f32x4 acc[16];
  #pragma unroll
  for (int t = 0; t < 16; ++t) acc[t] = f32x4{0.f,0.f,0.f,0.f};
  for (int kk = 0; kk < 32; ++kk){
    bf16x8 af = *reinterpret_cast<const bf16x8*>(ab + arow*2048 + ((kk*64 + g*16) ^ ((arow&7)<<4)));
    #pragma unroll
    for (int t = 0; t < 16; ++t){
      int oc = t*16 + col16;
      bf16x8 bfr = *reinterpret_cast<const bf16x8*>(wn1b + (size_t)oc*1024 + kk*32 + g*8);
      acc[t] = mfma16(af, bfr, acc[t]);
    }
  }
  #pragma unroll
  for (int t = 0; t < 16; ++t){
    int oc = t*16 + col16;
    #pragma unroll
    for (int i2 = 0; i2 < 4; ++i2){
      int row = r0 + wid*16 + g*4 + i2;
      h1[(size_t)row*256 + oc] = (__bf16)silu_f(acc[t][i2] + bn1[oc]);
    }
  }
}

__global__ __launch_bounds__(256) void node2_kernel(const __bf16* __restrict__ h1,
                                                    const __bf16* __restrict__ wn2b,
                                                    const float* __restrict__ bn2,
                                                    float* __restrict__ hout){
  __shared__ __align__(16) __bf16 At[64*256];  // 32KB, row stride 512B, swizzled
  int tid = threadIdx.x;
  int r0 = blockIdx.x * 64;
  char* ab = (char*)At;
  for (int it = 0; it < 8; ++it){
    int idx = it*2048 + tid*8;
    int row = idx >> 8, col = idx & 255;
    bf16x8 v = *reinterpret_cast<const bf16x8*>(h1 + (size_t)(r0+row)*256 + col);
    *reinterpret_cast<bf16x8*>(ab + row*512 + ((col*2) ^ ((row&7)<<4))) = v;
  }
  __syncthreads();
  int lane = tid & 63, wid = tid >> 6;
  int col16 = lane & 15, g = lane >> 4;
  int arow = wid*16 + col16;
  f32x4 acc[16];
  #pragma unroll
  for (int t = 0; t < 16; ++t) acc[t] = f32x4{0.f,0.f,0.f,0.f};
  for (int kk = 0; kk < 8; ++kk){
    bf16x8 af = *reinterpret_cast<const bf16x8*>(ab + arow*512 + ((kk*64 + g*16) ^ ((arow&7)<<4)));
    #pragma unroll
    for (int t = 0; t < 16; ++t){
      int oc = t*16 + col16;
      bf16x8 bfr = *reinterpret_cast<const bf16x8*>(wn2b + (size_t)oc*256 + kk*32 + g*8);
      acc[t] = mfma16(af, bfr, acc[t]);
    }
  }
  #pragma unroll
  for (int t = 0; t < 16; ++t){
    int oc = t*16 + col16;
    #pragma unroll
    for (int i2 = 0; i2 < 4; ++i2){
      int row = r0 + wid*16 + g*4 + i2;
      hout[(size_t)row*256 + oc] = acc[t][i2] + bn2[oc];
    }
  }
}

// -------------------------------------------------------------- launch ----
extern "C" void kernel_launch(void* const* d_in, const int* in_sizes, int n_in,
                              void* d_out, int out_size, void* d_ws, size_t ws_size,
                              hipStream_t stream){
  const float* h   = (const float*)d_in[0];
  const int*   ei  = (const int*)d_in[1];
  const float* ea  = (const float*)d_in[2];
  const float* pos = (const float*)d_in[3];
  const float* We1 = (const float*)d_in[4];
  const float* be1 = (const float*)d_in[5];
  const float* We2 = (const float*)d_in[6];
  const float* be2 = (const float*)d_in[7];
  const float* Wc1 = (const float*)d_in[8];
  const float* bc1 = (const float*)d_in[9];
  const float* Wc2 = (const float*)d_in[10];
  const float* Wn1 = (const float*)d_in[11];
  const float* bn1 = (const float*)d_in[12];
  const float* Wn2 = (const float*)d_in[13];
  const float* bn2 = (const float*)d_in[14];

  char* ws = (char*)d_ws;
  size_t off = 0;
  auto carve = [&](size_t bytes) -> char* {
    char* p = ws + off; off += (bytes + 255) & ~(size_t)255; return p;
  };
  __bf16* wab  = (__bf16*)carve((size_t)1024*512*2);
  __bf16* weaT = (__bf16*)carve((size_t)512*64*2);
  __bf16* we2b = (__bf16*)carve((size_t)512*512*2);
  __bf16* wc1b = (__bf16*)carve((size_t)512*512*2);
  __bf16* wn1b = (__bf16*)carve((size_t)256*1024*2);
  __bf16* wn2b = (__bf16*)carve((size_t)256*256*2);
  __bf16* AB   = (__bf16*)carve((size_t)N_NODES*1024*2);
  float*  agg  = (float*) carve((size_t)N_NODES*512*4);
  __bf16* h1   = (__bf16*)carve((size_t)N_NODES*256*2);
  int*    deg    = (int*) carve((size_t)N_NODES*4);
  int*    basep  = (int*) carve((size_t)N_NODES*4);
  int*    cursor = (int*) carve((size_t)N_NODES*4);
  int*    perm   = (int*) carve((size_t)N_EDGES*4);

  float* hout = (float*)d_out;
  float* pout = (float*)d_out + (size_t)N_NODES*256;

  hipMemsetAsync(agg, 0, (size_t)N_NODES*512*4, stream);
  hipMemsetAsync(deg, 0, (size_t)N_NODES*4, stream);
  hipMemsetAsync(cursor, 0, (size_t)N_NODES*4, stream);
  hipMemcpyAsync((void*)pout, (const void*)pos, (size_t)N_NODES*3*4,
                 hipMemcpyDeviceToDevice, stream);

  prep_kernel<<<2048, 256, 0, stream>>>(We1, be1, We2, Wc1, Wn1, Wn2,
                                        wab, weaT, we2b, wc1b, wn1b, wn2b);
  hist_kernel<<<N_EDGES/256, 256, 0, stream>>>(ei, deg);
  scan_kernel<<<1, 1024, 0, stream>>>(deg, basep);
  scatter_kernel<<<N_EDGES/256, 256, 0, stream>>>(ei, basep, cursor, perm);
  gemm_ab_kernel<<<N_NODES/64, 256, 0, stream>>>(h, wab, AB);
  edge_kernel<<<N_EDGES/TE, 512, 0, stream>>>(ei, perm, ea, pos, AB, weaT, we2b, wc1b,
                                              be2, bc1, Wc2, agg, pout);
  node1_kernel<<<N_NODES/64, 256, 0, stream>>>(h, agg, wn1b, bn1, h1);
  node2_kernel<<<N_NODES/64, 256, 0, stream>>>(h1, wn2b, bn2, hout);
}

// Round 7
// 1098.326 us; speedup vs baseline: 1.0343x; 1.0343x over previous
//
#include <hip/hip_runtime.h>

#define N_NODES 16384
#define N_EDGES 262144
#define TE 64   // edges per workgroup in edge kernel

typedef __attribute__((ext_vector_type(8))) __bf16 bf16x8;
typedef __attribute__((ext_vector_type(4))) __bf16 bf16x4;
typedef __attribute__((ext_vector_type(4))) float f32x4;
typedef __attribute__((ext_vector_type(16))) float f32x16;

__device__ __forceinline__ float silu_f(float x){ return x / (1.f + __expf(-x)); }

__device__ __forceinline__ f32x4 mfma16(bf16x8 a, bf16x8 b, f32x4 c){
  return __builtin_amdgcn_mfma_f32_16x16x32_bf16(a, b, c, 0, 0, 0);
}
__device__ __forceinline__ f32x16 mfma32(bf16x8 a, bf16x8 b, f32x16 c){
  return __builtin_amdgcn_mfma_f32_32x32x16_bf16(a, b, c, 0, 0, 0);
}

// ---------------------------------------------------------------- prep ----
__global__ void prep_kernel(const float* __restrict__ We1, const float* __restrict__ be1,
                            const float* __restrict__ We2,
                            const float* __restrict__ Wc1, const float* __restrict__ Wn1,
                            const float* __restrict__ Wn2,
                            __bf16* wab, __bf16* weaT, __bf16* we2b, __bf16* wc1b,
                            __bf16* wn1b, __bf16* wn2b){
  int i = blockIdx.x * 256 + threadIdx.x;
  if (i < 1024*512){
    int o = i >> 9, k = i & 511;
    float v = (o < 512) ? We1[(size_t)o*1076 + k] : We1[(size_t)(o-512)*1076 + 512 + k];
    wab[i] = (__bf16)v;
  }
  if (i < 512*64){
    int o = i >> 6, k = i & 63;
    float v = (k < 51) ? We1[(size_t)o*1076 + 1024 + k]
            : (k == 51 ? We1[(size_t)o*1076 + 1075]
            : (k == 52 ? be1[o] : 0.f));
    weaT[i] = (__bf16)v;
  }
  if (i < 512*512){ we2b[i] = (__bf16)We2[i]; wc1b[i] = (__bf16)Wc1[i]; }
  if (i < 256*1024){ wn1b[i] = (__bf16)Wn1[i]; }
  if (i < 256*256){ wn2b[i] = (__bf16)Wn2[i]; }
}

// ------------------------------------------------- counting sort by row ----
__global__ void hist_kernel(const int* __restrict__ eidx, int* __restrict__ deg){
  int e = blockIdx.x * 256 + threadIdx.x;
  if (e < N_EDGES) atomicAdd(&deg[eidx[e]], 1);
}

__global__ __launch_bounds__(1024) void scan_kernel(const int* __restrict__ deg,
                                                    int* __restrict__ base){
  __shared__ int part[1024];
  int tid = threadIdx.x;
  int b = tid * 16;
  int local[16];
  int s = 0;
  #pragma unroll
  for (int i = 0; i < 16; ++i){ local[i] = deg[b+i]; s += local[i]; }
  part[tid] = s;
  __syncthreads();
  for (int off = 1; off < 1024; off <<= 1){
    int v = 0;
    if (tid >= off) v = part[tid-off];
    __syncthreads();
    part[tid] += v;
    __syncthreads();
  }
  int run = part[tid] - s;   // exclusive prefix of this chunk
  #pragma unroll
  for (int i = 0; i < 16; ++i){ base[b+i] = run; run += local[i]; }
}

__global__ void scatter_kernel(const int* __restrict__ eidx, const int* __restrict__ base,
                               int* __restrict__ cursor, int* __restrict__ perm){
  int e = blockIdx.x * 256 + threadIdx.x;
  if (e < N_EDGES){
    int r = eidx[e];
    int p = atomicAdd(&cursor[r], 1);
    perm[base[r] + p] = e;
  }
}

// ------------------------------------------------------------- gemm AB ----
__global__ __launch_bounds__(256) void gemm_ab_kernel(const float* __restrict__ h,
                                                      const __bf16* __restrict__ wab,
                                                      __bf16* __restrict__ AB){
  __shared__ __align__(16) __bf16 At[64*512];  // 64KB, swizzled
  int tid = threadIdx.x;
  int r0 = blockIdx.x * 64;
  char* ab = (char*)At;
  for (int it = 0; it < 32; ++it){
    int idx = it*1024 + tid*4;
    int row = idx >> 9, col = idx & 511;
    float4 v = *reinterpret_cast<const float4*>(h + (size_t)(r0+row)*512 + col);
    bf16x4 p = {(__bf16)v.x, (__bf16)v.y, (__bf16)v.z, (__bf16)v.w};
    *reinterpret_cast<bf16x4*>(ab + row*1024 + ((col*2) ^ ((row&7)<<4))) = p;
  }
  __syncthreads();
  int lane = tid & 63, wid = tid >> 6;
  int col16 = lane & 15, g = lane >> 4;
  int arow = wid*16 + col16;
  for (int cc = 0; cc < 8; ++cc){
    f32x4 acc[8];
    #pragma unroll
    for (int t = 0; t < 8; ++t) acc[t] = f32x4{0.f,0.f,0.f,0.f};
    for (int kk = 0; kk < 16; ++kk){
      bf16x8 af = *reinterpret_cast<const bf16x8*>(ab + arow*1024 + ((kk*64 + g*16) ^ ((arow&7)<<4)));
      #pragma unroll
      for (int t = 0; t < 8; ++t){
        int oc = cc*128 + t*16 + col16;
        bf16x8 bfr = *reinterpret_cast<const bf16x8*>(wab + (size_t)oc*512 + kk*32 + g*8);
        acc[t] = mfma16(af, bfr, acc[t]);
      }
    }
    #pragma unroll
    for (int t = 0; t < 8; ++t){
      int oc = cc*128 + t*16 + col16;
      #pragma unroll
      for (int i2 = 0; i2 < 4; ++i2){
        int row = r0 + wid*16 + g*4 + i2;
        AB[(size_t)row*1024 + oc] = (__bf16)acc[t][i2];
      }
    }
  }
}

// --------------------------------------- K=512 phase, SWAPPED operands ----
// mfma(b, a): D rows = weight out-cols (reg-pattern), D cols = edges (lane).
// 4-deep register ring prefetch of B fragments.
__device__ __forceinline__ void gemm_phase_sw(const char* e1b, const __bf16* __restrict__ Brow,
                                              int c31, int hi, f32x16 acc[2][2]){
  bf16x8 bq[4][2];
  #pragma unroll
  for (int s = 0; s < 4; ++s)
    #pragma unroll
    for (int ct = 0; ct < 2; ++ct)
      bq[s][ct] = *reinterpret_cast<const bf16x8*>(Brow + s*16 + ct*16384);
  for (int kkb = 0; kkb < 8; ++kkb){
    #pragma unroll
    for (int s = 0; s < 4; ++s){
      int kk = kkb*4 + s;
      bf16x8 af[2];
      #pragma unroll
      for (int rt = 0; rt < 2; ++rt){
        int arow = rt*32 + c31;
        af[rt] = *reinterpret_cast<const bf16x8*>(e1b + arow*1024 + ((kk*32 + hi*16) ^ ((arow&7)<<4)));
      }
      #pragma unroll
      for (int ct = 0; ct < 2; ++ct)
        #pragma unroll
        for (int rt = 0; rt < 2; ++rt)
          acc[rt][ct] = mfma32(bq[s][ct], af[rt], acc[rt][ct]);
      if (kkb < 7){
        #pragma unroll
        for (int ct = 0; ct < 2; ++ct)
          bq[s][ct] = *reinterpret_cast<const bf16x8*>(Brow + (kk+4)*16 + ct*16384);
      }
    }
  }
}

// ------------------------------------------------------- fused edge op ----
__global__ __launch_bounds__(512, 4) void edge_kernel(
    const int* __restrict__ eidx, const int* __restrict__ perm,
    const float* __restrict__ edge_attr,
    const float* __restrict__ pos,
    const __bf16* __restrict__ AB, const __bf16* __restrict__ weaT,
    const __bf16* __restrict__ we2b, const __bf16* __restrict__ wc1b,
    const float* __restrict__ b2,
    const float* __restrict__ bc1, const float* __restrict__ wc2,
    float* __restrict__ agg, float* __restrict__ pos_out)
{
  __shared__ __align__(16) __bf16 e1t[TE*512];   // 64KB swizzled (e1, later e2)
  __shared__ __align__(16) __bf16 eat[TE*64];    // 8KB  swizzled (ea|radial|1|pad)
  __shared__ float diffs[3][TE];
  __shared__ float rad[TE];
  __shared__ int   rl[TE], cl[TE], el[TE];
  __shared__ float cupart[8][TE];
  __shared__ float cuf[TE];
  __shared__ unsigned long long segmask;

  int tid = threadIdx.x;
  int e0 = blockIdx.x * TE;   // NO swizzle: consecutive sorted tiles stay
                              // temporally close -> L2 reuse of AB and agg

  if (tid < TE){
    int eid = perm[e0 + tid];
    el[tid] = eid;
    int r = eidx[eid], c = eidx[N_EDGES + eid];
    rl[tid] = r; cl[tid] = c;
    float dx = pos[r*3+0]-pos[c*3+0];
    float dy = pos[r*3+1]-pos[c*3+1];
    float dz = pos[r*3+2]-pos[c*3+2];
    diffs[0][tid]=dx; diffs[1][tid]=dy; diffs[2][tid]=dz;
    float rr = dx*dx + dy*dy + dz*dz;
    rad[tid] = fminf(fmaxf(rr, 1e-8f), 100.f);
  }
  __syncthreads();

  // segment-boundary mask over the sorted 64 rows (wave 0 only)
  if (tid < 64){
    unsigned long long m = __ballot(tid > 0 && rl[tid] != rl[tid-1]);
    if (tid == 0) segmask = m;
  }

  // stage edge_attr (+radial k=51, one k=52, zero pad) swizzled bf16 [TE][64]
  {
    char* eb = (char*)eat;
    for (int i = tid; i < TE*64; i += 512){
      int e = i >> 6, k = i & 63;
      float v = (k < 51) ? edge_attr[(size_t)el[e]*51 + k]
              : (k == 51 ? rad[e] : (k == 52 ? 1.0f : 0.f));
      *reinterpret_cast<__bf16*>(eb + e*128 + ((k*2) ^ ((e&7)<<4))) = (__bf16)v;
    }
  }
  // prefill e1t with gather-sum (bf16, swizzled); bias comes via weaT k=52
  {
    int e = tid >> 3, q = tid & 7;
    size_t baseR = (size_t)rl[e]*1024;
    size_t baseC = (size_t)cl[e]*1024 + 512;
    char* eb = (char*)e1t;
    #pragma unroll
    for (int c = 0; c < 8; ++c){
      int o0 = q*8 + c*64;
      bf16x8 ga = *reinterpret_cast<const bf16x8*>(AB + baseR + o0);
      bf16x8 gb = *reinterpret_cast<const bf16x8*>(AB + baseC + o0);
      bf16x8 outv;
      #pragma unroll
      for (int j = 0; j < 8; ++j) outv[j] = (__bf16)((float)ga[j] + (float)gb[j]);
      *reinterpret_cast<bf16x8*>(eb + e*1024 + ((o0*2) ^ ((e&7)<<4))) = outv;
    }
  }
  __syncthreads();

  int lane = tid & 63, wid = tid >> 6;
  int c31 = lane & 31, hi = lane >> 5;
  int colbase = wid * 64;
  char* e1b = (char*)e1t;

  // P0: e1 = silu(prefill + ea@Wea^T) — swapped operands, vectorized b64 RMW
  {
    f32x16 acc[2][2];
    #pragma unroll
    for (int rt = 0; rt < 2; ++rt)
      #pragma unroll
      for (int ct = 0; ct < 2; ++ct)
        #pragma unroll
        for (int r = 0; r < 16; ++r) acc[rt][ct][r] = 0.f;
    const char* eb = (const char*)eat;
    #pragma unroll
    for (int kk = 0; kk < 4; ++kk){
      bf16x8 af[2];
      #pragma unroll
      for (int rt = 0; rt < 2; ++rt){
        int arow = rt*32 + c31;
        af[rt] = *reinterpret_cast<const bf16x8*>(eb + arow*128 + ((kk*32 + hi*16) ^ ((arow&7)<<4)));
      }
      #pragma unroll
      for (int ct = 0; ct < 2; ++ct){
        int oc = colbase + ct*32 + c31;
        bf16x8 bfr = *reinterpret_cast<const bf16x8*>(weaT + (size_t)oc*64 + kk*16 + hi*8);
        #pragma unroll
        for (int rt = 0; rt < 2; ++rt) acc[rt][ct] = mfma32(bfr, af[rt], acc[rt][ct]);
      }
    }
    #pragma unroll
    for (int rt = 0; rt < 2; ++rt){
      int edge = rt*32 + c31;
      #pragma unroll
      for (int ct = 0; ct < 2; ++ct){
        #pragma unroll
        for (int q = 0; q < 4; ++q){
          int oc0 = colbase + ct*32 + 8*q + 4*hi;
          char* p = e1b + edge*1024 + ((oc0*2) ^ ((edge&7)<<4));
          bf16x4 pre = *reinterpret_cast<const bf16x4*>(p);
          bf16x4 outv;
          #pragma unroll
          for (int j = 0; j < 4; ++j){
            float v = (float)pre[j] + acc[rt][ct][4*q+j];
            outv[j] = (__bf16)silu_f(v);
          }
          *reinterpret_cast<bf16x4*>(p) = outv;
        }
      }
    }
  }
  __syncthreads();

  // P1: e2 = silu(e1 @ We2^T + b2); e2 -> e1t (vectorized b64 stores)
  {
    f32x16 acc[2][2];
    #pragma unroll
    for (int rt = 0; rt < 2; ++rt)
      #pragma unroll
      for (int ct = 0; ct < 2; ++ct)
        #pragma unroll
        for (int r = 0; r < 16; ++r) acc[rt][ct][r] = 0.f;
    gemm_phase_sw(e1b, we2b + (size_t)(colbase + c31)*512 + hi*8, c31, hi, acc);
    f32x4 b2q[2][4];
    #pragma unroll
    for (int ct = 0; ct < 2; ++ct)
      #pragma unroll
      for (int q = 0; q < 4; ++q)
        b2q[ct][q] = *reinterpret_cast<const f32x4*>(b2 + colbase + ct*32 + 8*q + 4*hi);
    __syncthreads();   // all waves done READING e1t
    #pragma unroll
    for (int rt = 0; rt < 2; ++rt){
      int edge = rt*32 + c31;
      #pragma unroll
      for (int ct = 0; ct < 2; ++ct){
        #pragma unroll
        for (int q = 0; q < 4; ++q){
          bf16x4 outv;
          #pragma unroll
          for (int j = 0; j < 4; ++j)
            outv[j] = (__bf16)silu_f(acc[rt][ct][4*q+j] + b2q[ct][q][j]);
          int oc0 = colbase + ct*32 + 8*q + 4*hi;
          *reinterpret_cast<bf16x4*>(e1b + edge*1024 + ((oc0*2) ^ ((edge&7)<<4))) = outv;
        }
      }
    }
  }
  __syncthreads();

  // P2 (+AGG overlapped with B-ring latency):
  //   AGG: tid=col (coalesced segment-flush atomics), mask-driven
  //   c1 = silu(e2 @ Wc1^T + bc1); cu = c1 . wc2 (lane-local + 1 shuffle)
  {
    const __bf16* Brow = wc1b + (size_t)(colbase + c31)*512 + hi*8;
    bf16x8 bq[4][2];
    #pragma unroll
    for (int s = 0; s < 4; ++s)
      #pragma unroll
      for (int ct = 0; ct < 2; ++ct)
        bq[s][ct] = *reinterpret_cast<const bf16x8*>(Brow + s*16 + ct*16384);
    f32x4 bcq[2][4], wcq[2][4];
    #pragma unroll
    for (int ct = 0; ct < 2; ++ct)
      #pragma unroll
      for (int q = 0; q < 4; ++q){
        bcq[ct][q] = *reinterpret_cast<const f32x4*>(bc1 + colbase + ct*32 + 8*q + 4*hi);
        wcq[ct][q] = *reinterpret_cast<const f32x4*>(wc2 + colbase + ct*32 + 8*q + 4*hi);
      }

    // ---- AGG (coalesced: one column per thread; LDS reads overlap the
    //      in-flight global B loads) ----
    {
      int col = tid;  // 512 threads == 512 cols
      unsigned long long m = segmask;
      float a = 0.f;
      #pragma unroll
      for (int e = 0; e < TE; ++e){
        if (e > 0 && ((m >> e) & 1)){
          atomicAdd(&agg[(size_t)rl[e-1]*512 + col], a);
          a = 0.f;
        }
        a += (float)*reinterpret_cast<const __bf16*>(e1b + e*1024 + ((col*2) ^ ((e&7)<<4)));
      }
      atomicAdd(&agg[(size_t)rl[TE-1]*512 + col], a);
    }

    // ---- P2 GEMM (swapped) ----
    f32x16 acc[2][2];
    #pragma unroll
    for (int rt = 0; rt < 2; ++rt)
      #pragma unroll
      for (int ct = 0; ct < 2; ++ct)
        #pragma unroll
        for (int r = 0; r < 16; ++r) acc[rt][ct][r] = 0.f;
    for (int kkb = 0; kkb < 8; ++kkb){
      #pragma unroll
      for (int s = 0; s < 4; ++s){
        int kk = kkb*4 + s;
        bf16x8 af[2];
        #pragma unroll
        for (int rt = 0; rt < 2; ++rt){
          int arow = rt*32 + c31;
          af[rt] = *reinterpret_cast<const bf16x8*>(e1b + arow*1024 + ((kk*32 + hi*16) ^ ((arow&7)<<4)));
        }
        #pragma unroll
        for (int ct = 0; ct < 2; ++ct)
          #pragma unroll
          for (int rt = 0; rt < 2; ++rt)
            acc[rt][ct] = mfma32(bq[s][ct], af[rt], acc[rt][ct]);
        if (kkb < 7){
          #pragma unroll
          for (int ct = 0; ct < 2; ++ct)
            bq[s][ct] = *reinterpret_cast<const bf16x8*>(Brow + (kk+4)*16 + ct*16384);
        }
      }
    }
    // epilogue: per-lane dot with wc2 over own 32 strip cols, 1 shuffle
    #pragma unroll
    for (int rt = 0; rt < 2; ++rt){
      float pv = 0.f;
      #pragma unroll
      for (int ct = 0; ct < 2; ++ct)
        #pragma unroll
        for (int reg = 0; reg < 16; ++reg)
          pv += silu_f(acc[rt][ct][reg] + bcq[ct][reg>>2][reg&3]) * wcq[ct][reg>>2][reg&3];
      pv += __shfl_xor(pv, 32, 64);
      if (hi == 0) cupart[wid][rt*32 + c31] = pv;
    }
  }
  __syncthreads();

  if (tid < TE){
    float cu0 = 0.f;
    #pragma unroll
    for (int w = 0; w < 8; ++w) cu0 += cupart[w][tid];
    float cu = fminf(fmaxf(cu0, -1.f), 1.f);
    if (!isfinite(cu0)) cu = 0.f;
    cuf[tid] = cu;
  }
  __syncthreads();

  // POS: segmented per-axis sum (3 threads), mask-driven, unrolled
  if (tid < 3){
    int d = tid;
    unsigned long long m = segmask;
    float a = 0.f;
    #pragma unroll
    for (int e = 0; e < TE; ++e){
      if (e > 0 && ((m >> e) & 1)){
        atomicAdd(&pos_out[(size_t)rl[e-1]*3 + d], a);
        a = 0.f;
      }
      a += diffs[d][e] * cuf[e];
    }
    atomicAdd(&pos_out[(size_t)rl[TE-1]*3 + d], a);
  }
}

// ------------------------------------------------------------ node MLP ----
__global__ __launch_bounds__(256) void node1_kernel(const float* __restrict__ h,
                                                    const float* __restrict__ agg,
                                                    const __bf16* __restrict__ wn1b,
                                                    const float* __restrict__ bn1,
                                                    __bf16* __restrict__ h1){
  __shared__ __align__(16) __bf16 At[64*1024];  // 128KB, row stride 2048B, swizzled
  int tid = threadIdx.x;
  int r0 = blockIdx.x * 64;
  char* ab = (char*)At;
  for (int it = 0; it < 64; ++it){
    int idx = it*1024 + tid*4;
    int row = idx >> 10, col = idx & 1023;
    float4 v;
    if (col < 512) v = *reinterpret_cast<const float4*>(h   + (size_t)(r0+row)*512 + col);
    else           v = *reinterpret_cast<const float4*>(agg + (size_t)(r0+row)*512 + (col-512));
    bf16x4 p = {(__bf16)v.x, (__bf16)v.y, (__bf16)v.z, (__bf16)v.w};
    *reinterpret_cast<bf16x4*>(ab + row*2048 + ((col*2) ^ ((row&7)<<4))) = p;
  }
  __syncthreads();
  int lane = tid & 63, wid = tid >> 6;
  int col16 = lane & 15, g = lane >> 4;
  int arow = wid*16 + col16;
  f32x4 acc[16];
  #pragma unroll
  for (int t = 0; t < 16; ++t) acc[t] = f32x4{0.f,0.f,0.f,0.f};
  for (int kk = 0; kk < 32; ++kk){
    bf16x8 af = *reinterpret_cast<const bf16x8*>(ab + arow*2048 + ((kk*64 + g*16) ^ ((arow&7)<<4)));
    #pragma unroll
    for (int t = 0; t < 16; ++t){
      int oc = t*16 + col16;
      bf16x8 bfr = *reinterpret_cast<const bf16x8*>(wn1b + (size_t)oc*1024 + kk*32 + g*8);
      acc[t] = mfma16(af, bfr, acc[t]);
    }
  }
  #pragma unroll
  for (int t = 0; t < 16; ++t){
    int oc = t*16 + col16;
    #pragma unroll
    for (int i2 = 0; i2 < 4; ++i2){
      int row = r0 + wid*16 + g*4 + i2;
      h1[(size_t)row*256 + oc] = (__bf16)silu_f(acc[t][i2] + bn1[oc]);
    }
  }
}

__global__ __launch_bounds__(256) void node2_kernel(const __bf16* __restrict__ h1,
                                                    const __bf16* __restrict__ wn2b,
                                                    const float* __restrict__ bn2,
                                                    float* __restrict__ hout){
  __shared__ __align__(16) __bf16 At[64*256];  // 32KB, row stride 512B, swizzled
  int tid = threadIdx.x;
  int r0 = blockIdx.x * 64;
  char* ab = (char*)At;
  for (int it = 0; it < 8; ++it){
    int idx = it*2048 + tid*8;
    int row = idx >> 8, col = idx & 255;
    bf16x8 v = *reinterpret_cast<const bf16x8*>(h1 + (size_t)(r0+row)*256 + col);
    *reinterpret_cast<bf16x8*>(ab + row*512 + ((col*2) ^ ((row&7)<<4))) = v;
  }
  __syncthreads();
  int lane = tid & 63, wid = tid >> 6;
  int col16 = lane & 15, g = lane >> 4;
  int arow = wid*16 + col16;
  f32x4 acc[16];
  #pragma unroll
  for (int t = 0; t < 16; ++t) acc[t] = f32x4{0.f,0.f,0.f,0.f};
  for (int kk = 0; kk < 8; ++kk){
    bf16x8 af = *reinterpret_cast<const bf16x8*>(ab + arow*512 + ((kk*64 + g*16) ^ ((arow&7)<<4)));
    #pragma unroll
    for (int t = 0; t < 16; ++t){
      int oc = t*16 + col16;
      bf16x8 bfr = *reinterpret_cast<const bf16x8*>(wn2b + (size_t)oc*256 + kk*32 + g*8);
      acc[t] = mfma16(af, bfr, acc[t]);
    }
  }
  #pragma unroll
  for (int t = 0; t < 16; ++t){
    int oc = t*16 + col16;
    #pragma unroll
    for (int i2 = 0; i2 < 4; ++i2){
      int row = r0 + wid*16 + g*4 + i2;
      hout[(size_t)row*256 + oc] = acc[t][i2] + bn2[oc];
    }
  }
}

// -------------------------------------------------------------- launch ----
extern "C" void kernel_launch(void* const* d_in, const int* in_sizes, int n_in,
                              void* d_out, int out_size, void* d_ws, size_t ws_size,
                              hipStream_t stream){
  const float* h   = (const float*)d_in[0];
  const int*   ei  = (const int*)d_in[1];
  const float* ea  = (const float*)d_in[2];
  const float* pos = (const float*)d_in[3];
  const float* We1 = (const float*)d_in[4];
  const float* be1 = (const float*)d_in[5];
  const float* We2 = (const float*)d_in[6];
  const float* be2 = (const float*)d_in[7];
  const float* Wc1 = (const float*)d_in[8];
  const float* bc1 = (const float*)d_in[9];
  const float* Wc2 = (const float*)d_in[10];
  const float* Wn1 = (const float*)d_in[11];
  const float* bn1 = (const float*)d_in[12];
  const float* Wn2 = (const float*)d_in[13];
  const float* bn2 = (const float*)d_in[14];

  char* ws = (char*)d_ws;
  size_t off = 0;
  auto carve = [&](size_t bytes) -> char* {
    char* p = ws + off; off += (bytes + 255) & ~(size_t)255; return p;
  };
  __bf16* wab  = (__bf16*)carve((size_t)1024*512*2);
  __bf16* weaT = (__bf16*)carve((size_t)512*64*2);
  __bf16* we2b = (__bf16*)carve((size_t)512*512*2);
  __bf16* wc1b = (__bf16*)carve((size_t)512*512*2);
  __bf16* wn1b = (__bf16*)carve((size_t)256*1024*2);
  __bf16* wn2b = (__bf16*)carve((size_t)256*256*2);
  __bf16* AB   = (__bf16*)carve((size_t)N_NODES*1024*2);
  float*  agg  = (float*) carve((size_t)N_NODES*512*4);
  __bf16* h1   = (__bf16*)carve((size_t)N_NODES*256*2);
  int*    deg    = (int*) carve((size_t)N_NODES*4);
  int*    basep  = (int*) carve((size_t)N_NODES*4);
  int*    cursor = (int*) carve((size_t)N_NODES*4);
  int*    perm   = (int*) carve((size_t)N_EDGES*4);

  float* hout = (float*)d_out;
  float* pout = (float*)d_out + (size_t)N_NODES*256;

  hipMemsetAsync(agg, 0, (size_t)N_NODES*512*4, stream);
  hipMemsetAsync(deg, 0, (size_t)N_NODES*4, stream);
  hipMemsetAsync(cursor, 0, (size_t)N_NODES*4, stream);
  hipMemcpyAsync((void*)pout, (const void*)pos, (size_t)N_NODES*3*4,
                 hipMemcpyDeviceToDevice, stream);

  prep_kernel<<<2048, 256, 0, stream>>>(We1, be1, We2, Wc1, Wn1, Wn2,
                                        wab, weaT, we2b, wc1b, wn1b, wn2b);
  hist_kernel<<<N_EDGES/256, 256, 0, stream>>>(ei, deg);
  scan_kernel<<<1, 1024, 0, stream>>>(deg, basep);
  scatter_kernel<<<N_EDGES/256, 256, 0, stream>>>(ei, basep, cursor, perm);
  gemm_ab_kernel<<<N_NODES/64, 256, 0, stream>>>(h, wab, AB);
  edge_kernel<<<N_EDGES/TE, 512, 0, stream>>>(ei, perm, ea, pos, AB, weaT, we2b, wc1b,
                                              be2, bc1, Wc2, agg, pout);
  node1_kernel<<<N_NODES/64, 256, 0, stream>>>(h, agg, wn1b, bn1, h1);
  node2_kernel<<<N_NODES/64, 256, 0, stream>>>(h1, wn2b, bn2, hout);
}

// Round 8
// 976.480 us; speedup vs baseline: 1.1633x; 1.1248x over previous
//
#include <hip/hip_runtime.h>

#define N_NODES 16384
#define N_EDGES 262144
#define TE 64   // edges per workgroup in edge kernel

typedef __attribute__((ext_vector_type(8))) __bf16 bf16x8;
typedef __attribute__((ext_vector_type(4))) __bf16 bf16x4;
typedef __attribute__((ext_vector_type(4))) float f32x4;
typedef __attribute__((ext_vector_type(16))) float f32x16;

__device__ __forceinline__ float silu_f(float x){ return x / (1.f + __expf(-x)); }

__device__ __forceinline__ f32x4 mfma16(bf16x8 a, bf16x8 b, f32x4 c){
  return __builtin_amdgcn_mfma_f32_16x16x32_bf16(a, b, c, 0, 0, 0);
}
__device__ __forceinline__ f32x16 mfma32(bf16x8 a, bf16x8 b, f32x16 c){
  return __builtin_amdgcn_mfma_f32_32x32x16_bf16(a, b, c, 0, 0, 0);
}

// ---------------------------------------------------------------- prep ----
__global__ void prep_kernel(const float* __restrict__ We1, const float* __restrict__ be1,
                            const float* __restrict__ We2,
                            const float* __restrict__ Wc1, const float* __restrict__ Wn1,
                            const float* __restrict__ Wn2,
                            __bf16* wab, __bf16* weaT, __bf16* we2b, __bf16* wc1b,
                            __bf16* wn1b, __bf16* wn2b){
  int i = blockIdx.x * 256 + threadIdx.x;
  if (i < 1024*512){
    int o = i >> 9, k = i & 511;
    float v = (o < 512) ? We1[(size_t)o*1076 + k] : We1[(size_t)(o-512)*1076 + 512 + k];
    wab[i] = (__bf16)v;
  }
  if (i < 512*64){
    int o = i >> 6, k = i & 63;
    float v = (k < 51) ? We1[(size_t)o*1076 + 1024 + k]
            : (k == 51 ? We1[(size_t)o*1076 + 1075]
            : (k == 52 ? be1[o] : 0.f));
    weaT[i] = (__bf16)v;
  }
  if (i < 512*512){ we2b[i] = (__bf16)We2[i]; wc1b[i] = (__bf16)Wc1[i]; }
  if (i < 256*1024){ wn1b[i] = (__bf16)Wn1[i]; }
  if (i < 256*256){ wn2b[i] = (__bf16)Wn2[i]; }
}

// ------------------------------------------------- counting sort by row ----
__global__ void hist_kernel(const int* __restrict__ eidx, int* __restrict__ deg){
  int e = blockIdx.x * 256 + threadIdx.x;
  if (e < N_EDGES) atomicAdd(&deg[eidx[e]], 1);
}

__global__ __launch_bounds__(1024) void scan_kernel(const int* __restrict__ deg,
                                                    int* __restrict__ base){
  __shared__ int part[1024];
  int tid = threadIdx.x;
  int b = tid * 16;
  int local[16];
  int s = 0;
  #pragma unroll
  for (int i = 0; i < 16; ++i){ local[i] = deg[b+i]; s += local[i]; }
  part[tid] = s;
  __syncthreads();
  for (int off = 1; off < 1024; off <<= 1){
    int v = 0;
    if (tid >= off) v = part[tid-off];
    __syncthreads();
    part[tid] += v;
    __syncthreads();
  }
  int run = part[tid] - s;   // exclusive prefix of this chunk
  #pragma unroll
  for (int i = 0; i < 16; ++i){ base[b+i] = run; run += local[i]; }
}

__global__ void scatter_kernel(const int* __restrict__ eidx, const int* __restrict__ base,
                               int* __restrict__ cursor, int* __restrict__ perm){
  int e = blockIdx.x * 256 + threadIdx.x;
  if (e < N_EDGES){
    int r = eidx[e];
    int p = atomicAdd(&cursor[r], 1);
    perm[base[r] + p] = e;
  }
}

// ------------------------------------------------------------- gemm AB ----
__global__ __launch_bounds__(256) void gemm_ab_kernel(const float* __restrict__ h,
                                                      const __bf16* __restrict__ wab,
                                                      __bf16* __restrict__ AB){
  __shared__ __align__(16) __bf16 At[64*512];  // 64KB, swizzled
  int tid = threadIdx.x;
  int r0 = blockIdx.x * 64;
  char* ab = (char*)At;
  for (int it = 0; it < 32; ++it){
    int idx = it*1024 + tid*4;
    int row = idx >> 9, col = idx & 511;
    float4 v = *reinterpret_cast<const float4*>(h + (size_t)(r0+row)*512 + col);
    bf16x4 p = {(__bf16)v.x, (__bf16)v.y, (__bf16)v.z, (__bf16)v.w};
    *reinterpret_cast<bf16x4*>(ab + row*1024 + ((col*2) ^ ((row&7)<<4))) = p;
  }
  __syncthreads();
  int lane = tid & 63, wid = tid >> 6;
  int col16 = lane & 15, g = lane >> 4;
  int arow = wid*16 + col16;
  for (int cc = 0; cc < 8; ++cc){
    f32x4 acc[8];
    #pragma unroll
    for (int t = 0; t < 8; ++t) acc[t] = f32x4{0.f,0.f,0.f,0.f};
    for (int kk = 0; kk < 16; ++kk){
      bf16x8 af = *reinterpret_cast<const bf16x8*>(ab + arow*1024 + ((kk*64 + g*16) ^ ((arow&7)<<4)));
      #pragma unroll
      for (int t = 0; t < 8; ++t){
        int oc = cc*128 + t*16 + col16;
        bf16x8 bfr = *reinterpret_cast<const bf16x8*>(wab + (size_t)oc*512 + kk*32 + g*8);
        acc[t] = mfma16(af, bfr, acc[t]);
      }
    }
    #pragma unroll
    for (int t = 0; t < 8; ++t){
      int oc = cc*128 + t*16 + col16;
      #pragma unroll
      for (int i2 = 0; i2 < 4; ++i2){
        int row = r0 + wid*16 + g*4 + i2;
        AB[(size_t)row*1024 + oc] = (__bf16)acc[t][i2];
      }
    }
  }
}

// --------------------------------------- K=512 phase, SWAPPED operands ----
// mfma(b, a): D rows = weight out-cols (reg-pattern), D cols = edges (lane).
// 4-deep register ring prefetch of B fragments.
__device__ __forceinline__ void gemm_phase_sw(const char* e1b, const __bf16* __restrict__ Brow,
                                              int c31, int hi, f32x16 acc[2][2]){
  bf16x8 bq[4][2];
  #pragma unroll
  for (int s = 0; s < 4; ++s)
    #pragma unroll
    for (int ct = 0; ct < 2; ++ct)
      bq[s][ct] = *reinterpret_cast<const bf16x8*>(Brow + s*16 + ct*16384);
  for (int kkb = 0; kkb < 8; ++kkb){
    #pragma unroll
    for (int s = 0; s < 4; ++s){
      int kk = kkb*4 + s;
      bf16x8 af[2];
      #pragma unroll
      for (int rt = 0; rt < 2; ++rt){
        int arow = rt*32 + c31;
        af[rt] = *reinterpret_cast<const bf16x8*>(e1b + arow*1024 + ((kk*32 + hi*16) ^ ((arow&7)<<4)));
      }
      #pragma unroll
      for (int ct = 0; ct < 2; ++ct)
        #pragma unroll
        for (int rt = 0; rt < 2; ++rt)
          acc[rt][ct] = mfma32(bq[s][ct], af[rt], acc[rt][ct]);
      if (kkb < 7){
        #pragma unroll
        for (int ct = 0; ct < 2; ++ct)
          bq[s][ct] = *reinterpret_cast<const bf16x8*>(Brow + (kk+4)*16 + ct*16384);
      }
    }
  }
}

// ------------------------------------------------------- fused edge op ----
__global__ __launch_bounds__(512, 4) void edge_kernel(
    const int* __restrict__ eidx, const int* __restrict__ perm,
    const float* __restrict__ edge_attr,
    const float* __restrict__ pos,
    const __bf16* __restrict__ AB, const __bf16* __restrict__ weaT,
    const __bf16* __restrict__ we2b, const __bf16* __restrict__ wc1b,
    const float* __restrict__ b2,
    const float* __restrict__ bc1, const float* __restrict__ wc2,
    float* __restrict__ agg, float* __restrict__ pos_out)
{
  __shared__ __align__(16) __bf16 e1t[TE*512];   // 64KB swizzled (e1, later e2)
  __shared__ __align__(16) __bf16 eat[TE*64];    // 8KB  swizzled (ea|radial|1|pad)
  __shared__ float diffs[3][TE];
  __shared__ float rad[TE];
  __shared__ int   rl[TE], cl[TE], el[TE];
  __shared__ float cupart[8][TE];
  __shared__ float cuf[TE];
  __shared__ unsigned long long segmask;

  int tid = threadIdx.x;
  int e0 = blockIdx.x * TE;   // no swizzle: sorted tiles stay temporally close

  if (tid < TE){
    int eid = perm[e0 + tid];
    el[tid] = eid;
    int r = eidx[eid], c = eidx[N_EDGES + eid];
    rl[tid] = r; cl[tid] = c;
    float dx = pos[r*3+0]-pos[c*3+0];
    float dy = pos[r*3+1]-pos[c*3+1];
    float dz = pos[r*3+2]-pos[c*3+2];
    diffs[0][tid]=dx; diffs[1][tid]=dy; diffs[2][tid]=dz;
    float rr = dx*dx + dy*dy + dz*dz;
    rad[tid] = fminf(fmaxf(rr, 1e-8f), 100.f);
  }
  __syncthreads();

  // segment-boundary mask over the sorted 64 rows (wave 0 only)
  if (tid < 64){
    unsigned long long m = __ballot(tid > 0 && rl[tid] != rl[tid-1]);
    if (tid == 0) segmask = m;
  }

  // stage edge_attr (+radial k=51, one k=52, zero pad) swizzled bf16 [TE][64]
  {
    char* eb = (char*)eat;
    for (int i = tid; i < TE*64; i += 512){
      int e = i >> 6, k = i & 63;
      float v = (k < 51) ? edge_attr[(size_t)el[e]*51 + k]
              : (k == 51 ? rad[e] : (k == 52 ? 1.0f : 0.f));
      *reinterpret_cast<__bf16*>(eb + e*128 + ((k*2) ^ ((e&7)<<4))) = (__bf16)v;
    }
  }
  // prefill e1t with gather-sum (bf16, swizzled); bias comes via weaT k=52
  {
    int e = tid >> 3, q = tid & 7;
    size_t baseR = (size_t)rl[e]*1024;
    size_t baseC = (size_t)cl[e]*1024 + 512;
    char* eb = (char*)e1t;
    #pragma unroll
    for (int c = 0; c < 8; ++c){
      int o0 = q*8 + c*64;
      bf16x8 ga = *reinterpret_cast<const bf16x8*>(AB + baseR + o0);
      bf16x8 gb = *reinterpret_cast<const bf16x8*>(AB + baseC + o0);
      bf16x8 outv;
      #pragma unroll
      for (int j = 0; j < 8; ++j) outv[j] = (__bf16)((float)ga[j] + (float)gb[j]);
      *reinterpret_cast<bf16x8*>(eb + e*1024 + ((o0*2) ^ ((e&7)<<4))) = outv;
    }
  }
  __syncthreads();

  int lane = tid & 63, wid = tid >> 6;
  int c31 = lane & 31, hi = lane >> 5;
  int colbase = wid * 64;
  char* e1b = (char*)e1t;

  // P0: e1 = silu(prefill + ea@Wea^T) — swapped operands, vectorized b64 RMW
  {
    f32x16 acc[2][2];
    #pragma unroll
    for (int rt = 0; rt < 2; ++rt)
      #pragma unroll
      for (int ct = 0; ct < 2; ++ct)
        #pragma unroll
        for (int r = 0; r < 16; ++r) acc[rt][ct][r] = 0.f;
    const char* eb = (const char*)eat;
    #pragma unroll
    for (int kk = 0; kk < 4; ++kk){
      bf16x8 af[2];
      #pragma unroll
      for (int rt = 0; rt < 2; ++rt){
        int arow = rt*32 + c31;
        af[rt] = *reinterpret_cast<const bf16x8*>(eb + arow*128 + ((kk*32 + hi*16) ^ ((arow&7)<<4)));
      }
      #pragma unroll
      for (int ct = 0; ct < 2; ++ct){
        int oc = colbase + ct*32 + c31;
        bf16x8 bfr = *reinterpret_cast<const bf16x8*>(weaT + (size_t)oc*64 + kk*16 + hi*8);
        #pragma unroll
        for (int rt = 0; rt < 2; ++rt) acc[rt][ct] = mfma32(bfr, af[rt], acc[rt][ct]);
      }
    }
    #pragma unroll
    for (int rt = 0; rt < 2; ++rt){
      int edge = rt*32 + c31;
      #pragma unroll
      for (int ct = 0; ct < 2; ++ct){
        #pragma unroll
        for (int q = 0; q < 4; ++q){
          int oc0 = colbase + ct*32 + 8*q + 4*hi;
          char* p = e1b + edge*1024 + ((oc0*2) ^ ((edge&7)<<4));
          bf16x4 pre = *reinterpret_cast<const bf16x4*>(p);
          bf16x4 outv;
          #pragma unroll
          for (int j = 0; j < 4; ++j){
            float v = (float)pre[j] + acc[rt][ct][4*q+j];
            outv[j] = (__bf16)silu_f(v);
          }
          *reinterpret_cast<bf16x4*>(p) = outv;
        }
      }
    }
  }
  __syncthreads();

  // P1: e2 = silu(e1 @ We2^T + b2); e2 -> e1t (vectorized b64 stores)
  {
    f32x16 acc[2][2];
    #pragma unroll
    for (int rt = 0; rt < 2; ++rt)
      #pragma unroll
      for (int ct = 0; ct < 2; ++ct)
        #pragma unroll
        for (int r = 0; r < 16; ++r) acc[rt][ct][r] = 0.f;
    gemm_phase_sw(e1b, we2b + (size_t)(colbase + c31)*512 + hi*8, c31, hi, acc);
    __syncthreads();   // all waves done READING e1t
    f32x4 b2q[2][4];
    #pragma unroll
    for (int ct = 0; ct < 2; ++ct)
      #pragma unroll
      for (int q = 0; q < 4; ++q)
        b2q[ct][q] = *reinterpret_cast<const f32x4*>(b2 + colbase + ct*32 + 8*q + 4*hi);
    #pragma unroll
    for (int rt = 0; rt < 2; ++rt){
      int edge = rt*32 + c31;
      #pragma unroll
      for (int ct = 0; ct < 2; ++ct){
        #pragma unroll
        for (int q = 0; q < 4; ++q){
          bf16x4 outv;
          #pragma unroll
          for (int j = 0; j < 4; ++j)
            outv[j] = (__bf16)silu_f(acc[rt][ct][4*q+j] + b2q[ct][q][j]);
          int oc0 = colbase + ct*32 + 8*q + 4*hi;
          *reinterpret_cast<bf16x4*>(e1b + edge*1024 + ((oc0*2) ^ ((edge&7)<<4))) = outv;
        }
      }
    }
  }
  __syncthreads();

  // AGG: own scope (round-5 structure) — keeps register pressure low so
  // nothing spills; coalesced one-column-per-thread segment-flush atomics
  {
    int col = tid;  // 512 threads == 512 cols
    unsigned long long m = segmask;
    float a = 0.f;
    #pragma unroll
    for (int e = 0; e < TE; ++e){
      if (e > 0 && ((m >> e) & 1)){
        atomicAdd(&agg[(size_t)rl[e-1]*512 + col], a);
        a = 0.f;
      }
      a += (float)*reinterpret_cast<const __bf16*>(e1b + e*1024 + ((col*2) ^ ((e&7)<<4)));
    }
    atomicAdd(&agg[(size_t)rl[TE-1]*512 + col], a);
  }

  // P2: c1 = silu(e2 @ Wc1^T + bc1); cu = c1 . wc2 (lane-local + 1 shuffle)
  {
    f32x16 acc[2][2];
    #pragma unroll
    for (int rt = 0; rt < 2; ++rt)
      #pragma unroll
      for (int ct = 0; ct < 2; ++ct)
        #pragma unroll
        for (int r = 0; r < 16; ++r) acc[rt][ct][r] = 0.f;
    gemm_phase_sw(e1b, wc1b + (size_t)(colbase + c31)*512 + hi*8, c31, hi, acc);
    // epilogue-only loads (kept out of the GEMM live range)
    f32x4 bcq[2][4], wcq[2][4];
    #pragma unroll
    for (int ct = 0; ct < 2; ++ct)
      #pragma unroll
      for (int q = 0; q < 4; ++q){
        bcq[ct][q] = *reinterpret_cast<const f32x4*>(bc1 + colbase + ct*32 + 8*q + 4*hi);
        wcq[ct][q] = *reinterpret_cast<const f32x4*>(wc2 + colbase + ct*32 + 8*q + 4*hi);
      }
    #pragma unroll
    for (int rt = 0; rt < 2; ++rt){
      float pv = 0.f;
      #pragma unroll
      for (int ct = 0; ct < 2; ++ct)
        #pragma unroll
        for (int reg = 0; reg < 16; ++reg)
          pv += silu_f(acc[rt][ct][reg] + bcq[ct][reg>>2][reg&3]) * wcq[ct][reg>>2][reg&3];
      pv += __shfl_xor(pv, 32, 64);
      if (hi == 0) cupart[wid][rt*32 + c31] = pv;
    }
  }
  __syncthreads();

  if (tid < TE){
    float cu0 = 0.f;
    #pragma unroll
    for (int w = 0; w < 8; ++w) cu0 += cupart[w][tid];
    float cu = fminf(fmaxf(cu0, -1.f), 1.f);
    if (!isfinite(cu0)) cu = 0.f;
    cuf[tid] = cu;
  }
  __syncthreads();

  // POS: segmented per-axis sum (3 threads), mask-driven, unrolled
  if (tid < 3){
    int d = tid;
    unsigned long long m = segmask;
    float a = 0.f;
    #pragma unroll
    for (int e = 0; e < TE; ++e){
      if (e > 0 && ((m >> e) & 1)){
        atomicAdd(&pos_out[(size_t)rl[e-1]*3 + d], a);
        a = 0.f;
      }
      a += diffs[d][e] * cuf[e];
    }
    atomicAdd(&pos_out[(size_t)rl[TE-1]*3 + d], a);
  }
}

// ------------------------------------------------------------ node MLP ----
__global__ __launch_bounds__(256) void node1_kernel(const float* __restrict__ h,
                                                    const float* __restrict__ agg,
                                                    const __bf16* __restrict__ wn1b,
                                                    const float* __restrict__ bn1,
                                                    __bf16* __restrict__ h1){
  __shared__ __align__(16) __bf16 At[64*1024];  // 128KB, row stride 2048B, swizzled
  int tid = threadIdx.x;
  int r0 = blockIdx.x * 64;
  char* ab = (char*)At;
  for (int it = 0; it < 64; ++it){
    int idx = it*1024 + tid*4;
    int row = idx >> 10, col = idx & 1023;
    float4 v;
    if (col < 512) v = *reinterpret_cast<const float4*>(h   + (size_t)(r0+row)*512 + col);
    else           v = *reinterpret_cast<const float4*>(agg + (size_t)(r0+row)*512 + (col-512));
    bf16x4 p = {(__bf16)v.x, (__bf16)v.y, (__bf16)v.z, (__bf16)v.w};
    *reinterpret_cast<bf16x4*>(ab + row*2048 + ((col*2) ^ ((row&7)<<4))) = p;
  }
  __syncthreads();
  int lane = tid & 63, wid = tid >> 6;
  int col16 = lane & 15, g = lane >> 4;
  int arow = wid*16 + col16;
  f32x4 acc[16];
  #pragma unroll
  for (int t = 0; t < 16; ++t) acc[t] = f32x4{0.f,0.f,0.f,0.f};
  for (int kk = 0; kk < 32; ++kk){
    bf16x8 af = *reinterpret_cast<const bf16x8*>(ab + arow*2048 + ((kk*64 + g*16) ^ ((arow&7)<<4)));
    #pragma unroll
    for (int t = 0; t < 16; ++t){
      int oc = t*16 + col16;
      bf16x8 bfr = *reinterpret_cast<const bf16x8*>(wn1b + (size_t)oc*1024 + kk*32 + g*8);
      acc[t] = mfma16(af, bfr, acc[t]);
    }
  }
  #pragma unroll
  for (int t = 0; t < 16; ++t){
    int oc = t*16 + col16;
    #pragma unroll
    for (int i2 = 0; i2 < 4; ++i2){
      int row = r0 + wid*16 + g*4 + i2;
      h1[(size_t)row*256 + oc] = (__bf16)silu_f(acc[t][i2] + bn1[oc]);
    }
  }
}

__global__ __launch_bounds__(256) void node2_kernel(const __bf16* __restrict__ h1,
                                                    const __bf16* __restrict__ wn2b,
                                                    const float* __restrict__ bn2,
                                                    float* __restrict__ hout){
  __shared__ __align__(16) __bf16 At[64*256];  // 32KB, row stride 512B, swizzled
  int tid = threadIdx.x;
  int r0 = blockIdx.x * 64;
  char* ab = (char*)At;
  for (int it = 0; it < 8; ++it){
    int idx = it*2048 + tid*8;
    int row = idx >> 8, col = idx & 255;
    bf16x8 v = *reinterpret_cast<const bf16x8*>(h1 + (size_t)(r0+row)*256 + col);
    *reinterpret_cast<bf16x8*>(ab + row*512 + ((col*2) ^ ((row&7)<<4))) = v;
  }
  __syncthreads();
  int lane = tid & 63, wid = tid >> 6;
  int col16 = lane & 15, g = lane >> 4;
  int arow = wid*16 + col16;
  f32x4 acc[16];
  #pragma unroll
  for (int t = 0; t < 16; ++t) acc[t] = f32x4{0.f,0.f,0.f,0.f};
  for (int kk = 0; kk < 8; ++kk){
    bf16x8 af = *reinterpret_cast<const bf16x8*>(ab + arow*512 + ((kk*64 + g*16) ^ ((arow&7)<<4)));
    #pragma unroll
    for (int t = 0; t < 16; ++t){
      int oc = t*16 + col16;
      bf16x8 bfr = *reinterpret_cast<const bf16x8*>(wn2b + (size_t)oc*256 + kk*32 + g*8);
      acc[t] = mfma16(af, bfr, acc[t]);
    }
  }
  #pragma unroll
  for (int t = 0; t < 16; ++t){
    int oc = t*16 + col16;
    #pragma unroll
    for (int i2 = 0; i2 < 4; ++i2){
      int row = r0 + wid*16 + g*4 + i2;
      hout[(size_t)row*256 + oc] = acc[t][i2] + bn2[oc];
    }
  }
}

// -------------------------------------------------------------- launch ----
extern "C" void kernel_launch(void* const* d_in, const int* in_sizes, int n_in,
                              void* d_out, int out_size, void* d_ws, size_t ws_size,
                              hipStream_t stream){
  const float* h   = (const float*)d_in[0];
  const int*   ei  = (const int*)d_in[1];
  const float* ea  = (const float*)d_in[2];
  const float* pos = (const float*)d_in[3];
  const float* We1 = (const float*)d_in[4];
  const float* be1 = (const float*)d_in[5];
  const float* We2 = (const float*)d_in[6];
  const float* be2 = (const float*)d_in[7];
  const float* Wc1 = (const float*)d_in[8];
  const float* bc1 = (const float*)d_in[9];
  const float* Wc2 = (const float*)d_in[10];
  const float* Wn1 = (const float*)d_in[11];
  const float* bn1 = (const float*)d_in[12];
  const float* Wn2 = (const float*)d_in[13];
  const float* bn2 = (const float*)d_in[14];

  char* ws = (char*)d_ws;
  size_t off = 0;
  auto carve = [&](size_t bytes) -> char* {
    char* p = ws + off; off += (bytes + 255) & ~(size_t)255; return p;
  };
  __bf16* wab  = (__bf16*)carve((size_t)1024*512*2);
  __bf16* weaT = (__bf16*)carve((size_t)512*64*2);
  __bf16* we2b = (__bf16*)carve((size_t)512*512*2);
  __bf16* wc1b = (__bf16*)carve((size_t)512*512*2);
  __bf16* wn1b = (__bf16*)carve((size_t)256*1024*2);
  __bf16* wn2b = (__bf16*)carve((size_t)256*256*2);
  __bf16* AB   = (__bf16*)carve((size_t)N_NODES*1024*2);
  float*  agg  = (float*) carve((size_t)N_NODES*512*4);
  __bf16* h1   = (__bf16*)carve((size_t)N_NODES*256*2);
  int*    deg    = (int*) carve((size_t)N_NODES*4);
  int*    basep  = (int*) carve((size_t)N_NODES*4);
  int*    cursor = (int*) carve((size_t)N_NODES*4);
  int*    perm   = (int*) carve((size_t)N_EDGES*4);

  float* hout = (float*)d_out;
  float* pout = (float*)d_out + (size_t)N_NODES*256;

  hipMemsetAsync(agg, 0, (size_t)N_NODES*512*4, stream);
  hipMemsetAsync(deg, 0, (size_t)N_NODES*4, stream);
  hipMemsetAsync(cursor, 0, (size_t)N_NODES*4, stream);
  hipMemcpyAsync((void*)pout, (const void*)pos, (size_t)N_NODES*3*4,
                 hipMemcpyDeviceToDevice, stream);

  prep_kernel<<<2048, 256, 0, stream>>>(We1, be1, We2, Wc1, Wn1, Wn2,
                                        wab, weaT, we2b, wc1b, wn1b, wn2b);
  hist_kernel<<<N_EDGES/256, 256, 0, stream>>>(ei, deg);
  scan_kernel<<<1, 1024, 0, stream>>>(deg, basep);
  scatter_kernel<<<N_EDGES/256, 256, 0, stream>>>(ei, basep, cursor, perm);
  gemm_ab_kernel<<<N_NODES/64, 256, 0, stream>>>(h, wab, AB);
  edge_kernel<<<N_EDGES/TE, 512, 0, stream>>>(ei, perm, ea, pos, AB, weaT, we2b, wc1b,
                                              be2, bc1, Wc2, agg, pout);
  node1_kernel<<<N_NODES/64, 256, 0, stream>>>(h, agg, wn1b, bn1, h1);
  node2_kernel<<<N_NODES/64, 256, 0, stream>>>(h1, wn2b, bn2, hout);
}

// Round 11
// 949.248 us; speedup vs baseline: 1.1967x; 1.0287x over previous
//
#include <hip/hip_runtime.h>

#define N_NODES 16384
#define N_EDGES 262144
#define TE 64   // edges per workgroup in edge kernel

typedef __attribute__((ext_vector_type(8))) __bf16 bf16x8;
typedef __attribute__((ext_vector_type(4))) __bf16 bf16x4;
typedef __attribute__((ext_vector_type(4))) float f32x4;
typedef __attribute__((ext_vector_type(16))) float f32x16;

// fast silu: v_rcp_f32 instead of precise-division sequence (~10 VALU ops saved)
__device__ __forceinline__ float silu_f(float x){
  return x * __builtin_amdgcn_rcpf(1.f + __expf(-x));
}

__device__ __forceinline__ f32x4 mfma16(bf16x8 a, bf16x8 b, f32x4 c){
  return __builtin_amdgcn_mfma_f32_16x16x32_bf16(a, b, c, 0, 0, 0);
}
__device__ __forceinline__ f32x16 mfma32(bf16x8 a, bf16x8 b, f32x16 c){
  return __builtin_amdgcn_mfma_f32_32x32x16_bf16(a, b, c, 0, 0, 0);
}

// ---------------------------------------------------------------- prep ----
__global__ void prep_kernel(const float* __restrict__ We1, const float* __restrict__ be1,
                            const float* __restrict__ We2,
                            const float* __restrict__ Wc1, const float* __restrict__ Wn1,
                            const float* __restrict__ Wn2,
                            __bf16* wab, __bf16* weaT, __bf16* we2b, __bf16* wc1b,
                            __bf16* wn1b, __bf16* wn2b){
  int i = blockIdx.x * 256 + threadIdx.x;
  if (i < 1024*512){
    int o = i >> 9, k = i & 511;
    float v = (o < 512) ? We1[(size_t)o*1076 + k] : We1[(size_t)(o-512)*1076 + 512 + k];
    wab[i] = (__bf16)v;
  }
  if (i < 512*64){
    int o = i >> 6, k = i & 63;
    float v = (k < 51) ? We1[(size_t)o*1076 + 1024 + k]
            : (k == 51 ? We1[(size_t)o*1076 + 1075]
            : (k == 52 ? be1[o] : 0.f));
    weaT[i] = (__bf16)v;
  }
  if (i < 512*512){ we2b[i] = (__bf16)We2[i]; wc1b[i] = (__bf16)Wc1[i]; }
  if (i < 256*1024){ wn1b[i] = (__bf16)Wn1[i]; }
  if (i < 256*256){ wn2b[i] = (__bf16)Wn2[i]; }
}

// ------------------------------------------------- counting sort by row ----
__global__ void hist_kernel(const int* __restrict__ eidx, int* __restrict__ deg){
  int e = blockIdx.x * 256 + threadIdx.x;
  if (e < N_EDGES) atomicAdd(&deg[eidx[e]], 1);
}

__global__ __launch_bounds__(1024) void scan_kernel(const int* __restrict__ deg,
                                                    int* __restrict__ base){
  __shared__ int part[1024];
  int tid = threadIdx.x;
  int b = tid * 16;
  int local[16];
  int s = 0;
  #pragma unroll
  for (int i = 0; i < 16; ++i){ local[i] = deg[b+i]; s += local[i]; }
  part[tid] = s;
  __syncthreads();
  for (int off = 1; off < 1024; off <<= 1){
    int v = 0;
    if (tid >= off) v = part[tid-off];
    __syncthreads();
    part[tid] += v;
    __syncthreads();
  }
  int run = part[tid] - s;   // exclusive prefix of this chunk
  #pragma unroll
  for (int i = 0; i < 16; ++i){ base[b+i] = run; run += local[i]; }
}

__global__ void scatter_kernel(const int* __restrict__ eidx, const int* __restrict__ base,
                               int* __restrict__ cursor, int* __restrict__ perm){
  int e = blockIdx.x * 256 + threadIdx.x;
  if (e < N_EDGES){
    int r = eidx[e];
    int p = atomicAdd(&cursor[r], 1);
    perm[base[r] + p] = e;
  }
}

// ------------------------------------------------------------- gemm AB ----
__global__ __launch_bounds__(256) void gemm_ab_kernel(const float* __restrict__ h,
                                                      const __bf16* __restrict__ wab,
                                                      __bf16* __restrict__ AB){
  __shared__ __align__(16) __bf16 At[64*512];  // 64KB, swizzled
  int tid = threadIdx.x;
  int r0 = blockIdx.x * 64;
  char* ab = (char*)At;
  for (int it = 0; it < 32; ++it){
    int idx = it*1024 + tid*4;
    int row = idx >> 9, col = idx & 511;
    float4 v = *reinterpret_cast<const float4*>(h + (size_t)(r0+row)*512 + col);
    bf16x4 p = {(__bf16)v.x, (__bf16)v.y, (__bf16)v.z, (__bf16)v.w};
    *reinterpret_cast<bf16x4*>(ab + row*1024 + ((col*2) ^ ((row&7)<<4))) = p;
  }
  __syncthreads();
  int lane = tid & 63, wid = tid >> 6;
  int col16 = lane & 15, g = lane >> 4;
  int arow = wid*16 + col16;
  for (int cc = 0; cc < 8; ++cc){
    f32x4 acc[8];
    #pragma unroll
    for (int t = 0; t < 8; ++t) acc[t] = f32x4{0.f,0.f,0.f,0.f};
    for (int kk = 0; kk < 16; ++kk){
      bf16x8 af = *reinterpret_cast<const bf16x8*>(ab + arow*1024 + ((kk*64 + g*16) ^ ((arow&7)<<4)));
      #pragma unroll
      for (int t = 0; t < 8; ++t){
        int oc = cc*128 + t*16 + col16;
        bf16x8 bfr = *reinterpret_cast<const bf16x8*>(wab + (size_t)oc*512 + kk*32 + g*8);
        acc[t] = mfma16(af, bfr, acc[t]);
      }
    }
    #pragma unroll
    for (int t = 0; t < 8; ++t){
      int oc = cc*128 + t*16 + col16;
      #pragma unroll
      for (int i2 = 0; i2 < 4; ++i2){
        int row = r0 + wid*16 + g*4 + i2;
        AB[(size_t)row*1024 + oc] = (__bf16)acc[t][i2];
      }
    }
  }
}

// --------------------------------------- K=512 phase, SWAPPED operands ----
// mfma(b, a): D rows = weight out-cols (reg-pattern), D cols = edges (lane).
// 4-deep register ring prefetch of B fragments.
__device__ __forceinline__ void gemm_phase_sw(const char* e1b, const __bf16* __restrict__ Brow,
                                              int c31, int hi, f32x16 acc[2][2]){
  bf16x8 bq[4][2];
  #pragma unroll
  for (int s = 0; s < 4; ++s)
    #pragma unroll
    for (int ct = 0; ct < 2; ++ct)
      bq[s][ct] = *reinterpret_cast<const bf16x8*>(Brow + s*16 + ct*16384);
  for (int kkb = 0; kkb < 8; ++kkb){
    #pragma unroll
    for (int s = 0; s < 4; ++s){
      int kk = kkb*4 + s;
      bf16x8 af[2];
      #pragma unroll
      for (int rt = 0; rt < 2; ++rt){
        int arow = rt*32 + c31;
        af[rt] = *reinterpret_cast<const bf16x8*>(e1b + arow*1024 + ((kk*32 + hi*16) ^ ((arow&7)<<4)));
      }
      #pragma unroll
      for (int ct = 0; ct < 2; ++ct)
        #pragma unroll
        for (int rt = 0; rt < 2; ++rt)
          acc[rt][ct] = mfma32(bq[s][ct], af[rt], acc[rt][ct]);
      if (kkb < 7){
        #pragma unroll
        for (int ct = 0; ct < 2; ++ct)
          bq[s][ct] = *reinterpret_cast<const bf16x8*>(Brow + (kk+4)*16 + ct*16384);
      }
    }
  }
}

// ------------------------------------------------------- fused edge op ----
__global__ __launch_bounds__(512, 4) void edge_kernel(
    const int* __restrict__ eidx, const int* __restrict__ perm,
    const float* __restrict__ edge_attr,
    const float* __restrict__ pos,
    const __bf16* __restrict__ AB, const __bf16* __restrict__ weaT,
    const __bf16* __restrict__ we2b, const __bf16* __restrict__ wc1b,
    const float* __restrict__ b2,
    const float* __restrict__ bc1, const float* __restrict__ wc2,
    float* __restrict__ agg, float* __restrict__ pos_out)
{
  __shared__ __align__(16) __bf16 e1t[TE*512];   // 64KB swizzled (e1, later e2)
  // 8KB pool: swizzled ea tile during P0; f32 biases (b2|bc1|wc2) afterwards
  __shared__ __align__(16) char pool[8192];
  __shared__ float diffs[3][TE];
  __shared__ float rad[TE];
  __shared__ int   rl[TE], cl[TE], el[TE];
  __shared__ float cupart[8][TE];
  __shared__ float cuf[TE];
  __shared__ unsigned long long segmask;

  int tid = threadIdx.x;
  int e0 = blockIdx.x * TE;   // no swizzle: sorted tiles stay temporally close

  if (tid < TE){
    int eid = perm[e0 + tid];
    el[tid] = eid;
    int r = eidx[eid], c = eidx[N_EDGES + eid];
    rl[tid] = r; cl[tid] = c;
    float dx = pos[r*3+0]-pos[c*3+0];
    float dy = pos[r*3+1]-pos[c*3+1];
    float dz = pos[r*3+2]-pos[c*3+2];
    diffs[0][tid]=dx; diffs[1][tid]=dy; diffs[2][tid]=dz;
    float rr = dx*dx + dy*dy + dz*dz;
    rad[tid] = fminf(fmaxf(rr, 1e-8f), 100.f);
  }
  __syncthreads();

  // segment-boundary mask over the sorted 64 rows (wave 0 only)
  if (tid < 64){
    unsigned long long m = __ballot(tid > 0 && rl[tid] != rl[tid-1]);
    if (tid == 0) segmask = m;
  }

  // stage edge_attr (+radial k=51, one k=52, zero pad) swizzled bf16 [TE][64]
  {
    char* eb = pool;
    for (int i = tid; i < TE*64; i += 512){
      int e = i >> 6, k = i & 63;
      float v = (k < 51) ? edge_attr[(size_t)el[e]*51 + k]
              : (k == 51 ? rad[e] : (k == 52 ? 1.0f : 0.f));
      *reinterpret_cast<__bf16*>(eb + e*128 + ((k*2) ^ ((e&7)<<4))) = (__bf16)v;
    }
  }
  // prefill e1t with gather-sum (bf16, swizzled); bias comes via weaT k=52
  {
    int e = tid >> 3, q = tid & 7;
    size_t baseR = (size_t)rl[e]*1024;
    size_t baseC = (size_t)cl[e]*1024 + 512;
    char* eb = (char*)e1t;
    #pragma unroll
    for (int c = 0; c < 8; ++c){
      int o0 = q*8 + c*64;
      bf16x8 ga = *reinterpret_cast<const bf16x8*>(AB + baseR + o0);
      bf16x8 gb = *reinterpret_cast<const bf16x8*>(AB + baseC + o0);
      bf16x8 outv;
      #pragma unroll
      for (int j = 0; j < 8; ++j) outv[j] = (__bf16)((float)ga[j] + (float)gb[j]);
      *reinterpret_cast<bf16x8*>(eb + e*1024 + ((o0*2) ^ ((e&7)<<4))) = outv;
    }
  }
  __syncthreads();

  int lane = tid & 63, wid = tid >> 6;
  int c31 = lane & 31, hi = lane >> 5;
  int colbase = wid * 64;
  char* e1b = (char*)e1t;
  float* bpool = (float*)pool;   // [0..512)=b2, [512..1024)=bc1, [1024..1536)=wc2

  // P0: e1 = silu(prefill + ea@Wea^T) — swapped operands, vectorized b64 RMW
  {
    f32x16 acc[2][2];
    #pragma unroll
    for (int rt = 0; rt < 2; ++rt)
      #pragma unroll
      for (int ct = 0; ct < 2; ++ct)
        #pragma unroll
        for (int r = 0; r < 16; ++r) acc[rt][ct][r] = 0.f;
    const char* eb = pool;
    #pragma unroll
    for (int kk = 0; kk < 4; ++kk){
      bf16x8 af[2];
      #pragma unroll
      for (int rt = 0; rt < 2; ++rt){
        int arow = rt*32 + c31;
        af[rt] = *reinterpret_cast<const bf16x8*>(eb + arow*128 + ((kk*32 + hi*16) ^ ((arow&7)<<4)));
      }
      #pragma unroll
      for (int ct = 0; ct < 2; ++ct){
        int oc = colbase + ct*32 + c31;
        bf16x8 bfr = *reinterpret_cast<const bf16x8*>(weaT + (size_t)oc*64 + kk*16 + hi*8);
        #pragma unroll
        for (int rt = 0; rt < 2; ++rt) acc[rt][ct] = mfma32(bfr, af[rt], acc[rt][ct]);
      }
    }
    #pragma unroll
    for (int rt = 0; rt < 2; ++rt){
      int edge = rt*32 + c31;
      #pragma unroll
      for (int ct = 0; ct < 2; ++ct){
        #pragma unroll
        for (int q = 0; q < 4; ++q){
          int oc0 = colbase + ct*32 + 8*q + 4*hi;
          char* p = e1b + edge*1024 + ((oc0*2) ^ ((edge&7)<<4));
          bf16x4 pre = *reinterpret_cast<const bf16x4*>(p);
          bf16x4 outv;
          #pragma unroll
          for (int j = 0; j < 4; ++j){
            float v = (float)pre[j] + acc[rt][ct][4*q+j];
            outv[j] = (__bf16)silu_f(v);
          }
          *reinterpret_cast<bf16x4*>(p) = outv;
        }
      }
    }
  }
  __syncthreads();   // eat reads done -> pool is now free for biases

  // stage biases into the pool (read after the next barrier)
  bpool[tid]        = b2[tid];
  bpool[512 + tid]  = bc1[tid];
  bpool[1024 + tid] = wc2[tid];

  // P1: e2 = silu(e1 @ We2^T + b2); e2 -> e1t (vectorized b64 stores)
  {
    f32x16 acc[2][2];
    #pragma unroll
    for (int rt = 0; rt < 2; ++rt)
      #pragma unroll
      for (int ct = 0; ct < 2; ++ct)
        #pragma unroll
        for (int r = 0; r < 16; ++r) acc[rt][ct][r] = 0.f;
    gemm_phase_sw(e1b, we2b + (size_t)(colbase + c31)*512 + hi*8, c31, hi, acc);
    __syncthreads();   // all waves done READING e1t; biases visible
    #pragma unroll
    for (int rt = 0; rt < 2; ++rt){
      int edge = rt*32 + c31;
      #pragma unroll
      for (int ct = 0; ct < 2; ++ct){
        #pragma unroll
        for (int q = 0; q < 4; ++q){
          f32x4 b2v = *reinterpret_cast<const f32x4*>(bpool + colbase + ct*32 + 8*q + 4*hi);
          bf16x4 outv;
          #pragma unroll
          for (int j = 0; j < 4; ++j)
            outv[j] = (__bf16)silu_f(acc[rt][ct][4*q+j] + b2v[j]);
          int oc0 = colbase + ct*32 + 8*q + 4*hi;
          *reinterpret_cast<bf16x4*>(e1b + edge*1024 + ((oc0*2) ^ ((edge&7)<<4))) = outv;
        }
      }
    }
  }
  __syncthreads();

  // AGG: coalesced one-column-per-thread segment-flush atomics
  {
    int col = tid;  // 512 threads == 512 cols
    unsigned long long m = segmask;
    float a = 0.f;
    #pragma unroll
    for (int e = 0; e < TE; ++e){
      if (e > 0 && ((m >> e) & 1)){
        atomicAdd(&agg[(size_t)rl[e-1]*512 + col], a);
        a = 0.f;
      }
      a += (float)*reinterpret_cast<const __bf16*>(e1b + e*1024 + ((col*2) ^ ((e&7)<<4)));
    }
    atomicAdd(&agg[(size_t)rl[TE-1]*512 + col], a);
  }

  // P2: c1 = silu(e2 @ Wc1^T + bc1); cu = c1 . wc2 (lane-local + 1 shuffle)
  {
    f32x16 acc[2][2];
    #pragma unroll
    for (int rt = 0; rt < 2; ++rt)
      #pragma unroll
      for (int ct = 0; ct < 2; ++ct)
        #pragma unroll
        for (int r = 0; r < 16; ++r) acc[rt][ct][r] = 0.f;
    gemm_phase_sw(e1b, wc1b + (size_t)(colbase + c31)*512 + hi*8, c31, hi, acc);
    #pragma unroll
    for (int rt = 0; rt < 2; ++rt){
      float pv = 0.f;
      #pragma unroll
      for (int ct = 0; ct < 2; ++ct){
        #pragma unroll
        for (int q = 0; q < 4; ++q){
          f32x4 bcv = *reinterpret_cast<const f32x4*>(bpool + 512 + colbase + ct*32 + 8*q + 4*hi);
          f32x4 wcv = *reinterpret_cast<const f32x4*>(bpool + 1024 + colbase + ct*32 + 8*q + 4*hi);
          #pragma unroll
          for (int j = 0; j < 4; ++j)
            pv += silu_f(acc[rt][ct][4*q+j] + bcv[j]) * wcv[j];
        }
      }
      pv += __shfl_xor(pv, 32, 64);
      if (hi == 0) cupart[wid][rt*32 + c31] = pv;
    }
  }
  __syncthreads();

  if (tid < TE){
    float cu0 = 0.f;
    #pragma unroll
    for (int w = 0; w < 8; ++w) cu0 += cupart[w][tid];
    float cu = fminf(fmaxf(cu0, -1.f), 1.f);
    if (!isfinite(cu0)) cu = 0.f;
    cuf[tid] = cu;
  }
  __syncthreads();

  // POS: segmented per-axis sum (3 threads), mask-driven, unrolled
  if (tid < 3){
    int d = tid;
    unsigned long long m = segmask;
    float a = 0.f;
    #pragma unroll
    for (int e = 0; e < TE; ++e){
      if (e > 0 && ((m >> e) & 1)){
        atomicAdd(&pos_out[(size_t)rl[e-1]*3 + d], a);
        a = 0.f;
      }
      a += diffs[d][e] * cuf[e];
    }
    atomicAdd(&pos_out[(size_t)rl[TE-1]*3 + d], a);
  }
}

// ------------------------------------------------------------ node MLP ----
__global__ __launch_bounds__(256) void node1_kernel(const float* __restrict__ h,
                                                    const float* __restrict__ agg,
                                                    const __bf16* __restrict__ wn1b,
                                                    const float* __restrict__ bn1,
                                                    __bf16* __restrict__ h1){
  __shared__ __align__(16) __bf16 At[64*1024];  // 128KB, row stride 2048B, swizzled
  int tid = threadIdx.x;
  int r0 = blockIdx.x * 64;
  char* ab = (char*)At;
  for (int it = 0; it < 64; ++it){
    int idx = it*1024 + tid*4;
    int row = idx >> 10, col = idx & 1023;
    float4 v;
    if (col < 512) v = *reinterpret_cast<const float4*>(h   + (size_t)(r0+row)*512 + col);
    else           v = *reinterpret_cast<const float4*>(agg + (size_t)(r0+row)*512 + (col-512));
    bf16x4 p = {(__bf16)v.x, (__bf16)v.y, (__bf16)v.z, (__bf16)v.w};
    *reinterpret_cast<bf16x4*>(ab + row*2048 + ((col*2) ^ ((row&7)<<4))) = p;
  }
  __syncthreads();
  int lane = tid & 63, wid = tid >> 6;
  int col16 = lane & 15, g = lane >> 4;
  int arow = wid*16 + col16;
  f32x4 acc[16];
  #pragma unroll
  for (int t = 0; t < 16; ++t) acc[t] = f32x4{0.f,0.f,0.f,0.f};
  for (int kk = 0; kk < 32; ++kk){
    bf16x8 af = *reinterpret_cast<const bf16x8*>(ab + arow*2048 + ((kk*64 + g*16) ^ ((arow&7)<<4)));
    #pragma unroll
    for (int t = 0; t < 16; ++t){
      int oc = t*16 + col16;
      bf16x8 bfr = *reinterpret_cast<const bf16x8*>(wn1b + (size_t)oc*1024 + kk*32 + g*8);
      acc[t] = mfma16(af, bfr, acc[t]);
    }
  }
  #pragma unroll
  for (int t = 0; t < 16; ++t){
    int oc = t*16 + col16;
    #pragma unroll
    for (int i2 = 0; i2 < 4; ++i2){
      int row = r0 + wid*16 + g*4 + i2;
      h1[(size_t)row*256 + oc] = (__bf16)silu_f(acc[t][i2] + bn1[oc]);
    }
  }
}

__global__ __launch_bounds__(256) void node2_kernel(const __bf16* __restrict__ h1,
                                                    const __bf16* __restrict__ wn2b,
                                                    const float* __restrict__ bn2,
                                                    float* __restrict__ hout){
  __shared__ __align__(16) __bf16 At[64*256];  // 32KB, row stride 512B, swizzled
  int tid = threadIdx.x;
  int r0 = blockIdx.x * 64;
  char* ab = (char*)At;
  for (int it = 0; it < 8; ++it){
    int idx = it*2048 + tid*8;
    int row = idx >> 8, col = idx & 255;
    bf16x8 v = *reinterpret_cast<const bf16x8*>(h1 + (size_t)(r0+row)*256 + col);
    *reinterpret_cast<bf16x8*>(ab + row*512 + ((col*2) ^ ((row&7)<<4))) = v;
  }
  __syncthreads();
  int lane = tid & 63, wid = tid >> 6;
  int col16 = lane & 15, g = lane >> 4;
  int arow = wid*16 + col16;
  f32x4 acc[16];
  #pragma unroll
  for (int t = 0; t < 16; ++t) acc[t] = f32x4{0.f,0.f,0.f,0.f};
  for (int kk = 0; kk < 8; ++kk){
    bf16x8 af = *reinterpret_cast<const bf16x8*>(ab + arow*512 + ((kk*64 + g*16) ^ ((arow&7)<<4)));
    #pragma unroll
    for (int t = 0; t < 16; ++t){
      int oc = t*16 + col16;
      bf16x8 bfr = *reinterpret_cast<const bf16x8*>(wn2b + (size_t)oc*256 + kk*32 + g*8);
      acc[t] = mfma16(af, bfr, acc[t]);
    }
  }
  #pragma unroll
  for (int t = 0; t < 16; ++t){
    int oc = t*16 + col16;
    #pragma unroll
    for (int i2 = 0; i2 < 4; ++i2){
      int row = r0 + wid*16 + g*4 + i2;
      hout[(size_t)row*256 + oc] = acc[t][i2] + bn2[oc];
    }
  }
}

// -------------------------------------------------------------- launch ----
extern "C" void kernel_launch(void* const* d_in, const int* in_sizes, int n_in,
                              void* d_out, int out_size, void* d_ws, size_t ws_size,
                              hipStream_t stream){
  const float* h   = (const float*)d_in[0];
  const int*   ei  = (const int*)d_in[1];
  const float* ea  = (const float*)d_in[2];
  const float* pos = (const float*)d_in[3];
  const float* We1 = (const float*)d_in[4];
  const float* be1 = (const float*)d_in[5];
  const float* We2 = (const float*)d_in[6];
  const float* be2 = (const float*)d_in[7];
  const float* Wc1 = (const float*)d_in[8];
  const float* bc1 = (const float*)d_in[9];
  const float* Wc2 = (const float*)d_in[10];
  const float* Wn1 = (const float*)d_in[11];
  const float* bn1 = (const float*)d_in[12];
  const float* Wn2 = (const float*)d_in[13];
  const float* bn2 = (const float*)d_in[14];

  char* ws = (char*)d_ws;
  size_t off = 0;
  auto carve = [&](size_t bytes) -> char* {
    char* p = ws + off; off += (bytes + 255) & ~(size_t)255; return p;
  };
  __bf16* wab  = (__bf16*)carve((size_t)1024*512*2);
  __bf16* weaT = (__bf16*)carve((size_t)512*64*2);
  __bf16* we2b = (__bf16*)carve((size_t)512*512*2);
  __bf16* wc1b = (__bf16*)carve((size_t)512*512*2);
  __bf16* wn1b = (__bf16*)carve((size_t)256*1024*2);
  __bf16* wn2b = (__bf16*)carve((size_t)256*256*2);
  __bf16* AB   = (__bf16*)carve((size_t)N_NODES*1024*2);
  float*  agg  = (float*) carve((size_t)N_NODES*512*4);
  __bf16* h1   = (__bf16*)carve((size_t)N_NODES*256*2);
  int*    deg    = (int*) carve((size_t)N_NODES*4);
  int*    basep  = (int*) carve((size_t)N_NODES*4);
  int*    cursor = (int*) carve((size_t)N_NODES*4);
  int*    perm   = (int*) carve((size_t)N_EDGES*4);

  float* hout = (float*)d_out;
  float* pout = (float*)d_out + (size_t)N_NODES*256;

  hipMemsetAsync(agg, 0, (size_t)N_NODES*512*4, stream);
  hipMemsetAsync(deg, 0, (size_t)N_NODES*4, stream);
  hipMemsetAsync(cursor, 0, (size_t)N_NODES*4, stream);
  hipMemcpyAsync((void*)pout, (const void*)pos, (size_t)N_NODES*3*4,
                 hipMemcpyDeviceToDevice, stream);

  prep_kernel<<<2048, 256, 0, stream>>>(We1, be1, We2, Wc1, Wn1, Wn2,
                                        wab, weaT, we2b, wc1b, wn1b, wn2b);
  hist_kernel<<<N_EDGES/256, 256, 0, stream>>>(ei, deg);
  scan_kernel<<<1, 1024, 0, stream>>>(deg, basep);
  scatter_kernel<<<N_EDGES/256, 256, 0, stream>>>(ei, basep, cursor, perm);
  gemm_ab_kernel<<<N_NODES/64, 256, 0, stream>>>(h, wab, AB);
  edge_kernel<<<N_EDGES/TE, 512, 0, stream>>>(ei, perm, ea, pos, AB, weaT, we2b, wc1b,
                                              be2, bc1, Wc2, agg, pout);
  node1_kernel<<<N_NODES/64, 256, 0, stream>>>(h, agg, wn1b, bn1, h1);
  node2_kernel<<<N_NODES/64, 256, 0, stream>>>(h1, wn2b, bn2, hout);
}

// Round 12
// 902.486 us; speedup vs baseline: 1.2587x; 1.0518x over previous
//
#include <hip/hip_runtime.h>

#define N_NODES 16384
#define N_EDGES 262144
#define TE 64   // edges per workgroup in edge kernel

typedef __attribute__((ext_vector_type(8))) __bf16 bf16x8;
typedef __attribute__((ext_vector_type(4))) __bf16 bf16x4;
typedef __attribute__((ext_vector_type(4))) float f32x4;
typedef __attribute__((ext_vector_type(16))) float f32x16;

// fast silu: v_rcp_f32 instead of precise-division sequence
__device__ __forceinline__ float silu_f(float x){
  return x * __builtin_amdgcn_rcpf(1.f + __expf(-x));
}

__device__ __forceinline__ f32x4 mfma16(bf16x8 a, bf16x8 b, f32x4 c){
  return __builtin_amdgcn_mfma_f32_16x16x32_bf16(a, b, c, 0, 0, 0);
}
__device__ __forceinline__ f32x16 mfma32(bf16x8 a, bf16x8 b, f32x16 c){
  return __builtin_amdgcn_mfma_f32_32x32x16_bf16(a, b, c, 0, 0, 0);
}

// ------------------------------------------------------ prep (+hist) ----
__global__ void prep_kernel(const float* __restrict__ We1, const float* __restrict__ be1,
                            const float* __restrict__ We2,
                            const float* __restrict__ Wc1, const float* __restrict__ Wn1,
                            const float* __restrict__ Wn2, const int* __restrict__ eidx,
                            __bf16* wab, __bf16* weaT, __bf16* we2b, __bf16* wc1b,
                            __bf16* wn1b, __bf16* wn2b, int* __restrict__ deg){
  int i = blockIdx.x * 256 + threadIdx.x;
  if (i < 1024*512){
    int o = i >> 9, k = i & 511;
    float v = (o < 512) ? We1[(size_t)o*1076 + k] : We1[(size_t)(o-512)*1076 + 512 + k];
    wab[i] = (__bf16)v;
  }
  if (i < 512*64){
    int o = i >> 6, k = i & 63;
    float v = (k < 51) ? We1[(size_t)o*1076 + 1024 + k]
            : (k == 51 ? We1[(size_t)o*1076 + 1075]
            : (k == 52 ? be1[o] : 0.f));
    weaT[i] = (__bf16)v;
  }
  if (i < 512*512){ we2b[i] = (__bf16)We2[i]; wc1b[i] = (__bf16)Wc1[i]; }
  if (i < 256*1024){ wn1b[i] = (__bf16)Wn1[i]; }
  if (i < 256*256){ wn2b[i] = (__bf16)Wn2[i]; }
  if (i < N_EDGES){ atomicAdd(&deg[eidx[i]], 1); }   // fused hist
}

// ------------------------------------------------- counting sort by row ----
__global__ __launch_bounds__(1024) void scan_kernel(const int* __restrict__ deg,
                                                    int* __restrict__ base){
  __shared__ int part[1024];
  int tid = threadIdx.x;
  int b = tid * 16;
  int local[16];
  int s = 0;
  #pragma unroll
  for (int i = 0; i < 16; ++i){ local[i] = deg[b+i]; s += local[i]; }
  part[tid] = s;
  __syncthreads();
  for (int off = 1; off < 1024; off <<= 1){
    int v = 0;
    if (tid >= off) v = part[tid-off];
    __syncthreads();
    part[tid] += v;
    __syncthreads();
  }
  int run = part[tid] - s;   // exclusive prefix of this chunk
  #pragma unroll
  for (int i = 0; i < 16; ++i){ base[b+i] = run; run += local[i]; }
}

__global__ void scatter_kernel(const int* __restrict__ eidx, const int* __restrict__ base,
                               int* __restrict__ cursor, int* __restrict__ perm){
  int e = blockIdx.x * 256 + threadIdx.x;
  if (e < N_EDGES){
    int r = eidx[e];
    int p = atomicAdd(&cursor[r], 1);
    perm[base[r] + p] = e;
  }
}

// ------------------------------------------------------------- gemm AB ----
// grid 512: bid>>1 = 64-row block, bid&1 = col half (4 of 8 cc blocks).
// 2 wg/CU for latency overlap (was 1 wg/CU at grid 256).
__global__ __launch_bounds__(256) void gemm_ab_kernel(const float* __restrict__ h,
                                                      const __bf16* __restrict__ wab,
                                                      __bf16* __restrict__ AB){
  __shared__ __align__(16) __bf16 At[64*512];  // 64KB, swizzled
  int tid = threadIdx.x;
  int bid = blockIdx.x;
  int r0 = (bid >> 1) * 64;
  int cc0 = (bid & 1) * 4;
  char* ab = (char*)At;
  for (int it = 0; it < 32; ++it){
    int idx = it*1024 + tid*4;
    int row = idx >> 9, col = idx & 511;
    float4 v = *reinterpret_cast<const float4*>(h + (size_t)(r0+row)*512 + col);
    bf16x4 p = {(__bf16)v.x, (__bf16)v.y, (__bf16)v.z, (__bf16)v.w};
    *reinterpret_cast<bf16x4*>(ab + row*1024 + ((col*2) ^ ((row&7)<<4))) = p;
  }
  __syncthreads();
  int lane = tid & 63, wid = tid >> 6;
  int col16 = lane & 15, g = lane >> 4;
  int arow = wid*16 + col16;
  for (int cc = cc0; cc < cc0 + 4; ++cc){
    f32x4 acc[8];
    #pragma unroll
    for (int t = 0; t < 8; ++t) acc[t] = f32x4{0.f,0.f,0.f,0.f};
    for (int kk = 0; kk < 16; ++kk){
      bf16x8 af = *reinterpret_cast<const bf16x8*>(ab + arow*1024 + ((kk*64 + g*16) ^ ((arow&7)<<4)));
      #pragma unroll
      for (int t = 0; t < 8; ++t){
        int oc = cc*128 + t*16 + col16;
        bf16x8 bfr = *reinterpret_cast<const bf16x8*>(wab + (size_t)oc*512 + kk*32 + g*8);
        acc[t] = mfma16(af, bfr, acc[t]);
      }
    }
    #pragma unroll
    for (int t = 0; t < 8; ++t){
      int oc = cc*128 + t*16 + col16;
      #pragma unroll
      for (int i2 = 0; i2 < 4; ++i2){
        int row = r0 + wid*16 + g*4 + i2;
        AB[(size_t)row*1024 + oc] = (__bf16)acc[t][i2];
      }
    }
  }
}

// --------------------------------------- K=512 phase, SWAPPED operands ----
__device__ __forceinline__ void gemm_phase_sw(const char* e1b, const __bf16* __restrict__ Brow,
                                              int c31, int hi, f32x16 acc[2][2]){
  bf16x8 bq[4][2];
  #pragma unroll
  for (int s = 0; s < 4; ++s)
    #pragma unroll
    for (int ct = 0; ct < 2; ++ct)
      bq[s][ct] = *reinterpret_cast<const bf16x8*>(Brow + s*16 + ct*16384);
  for (int kkb = 0; kkb < 8; ++kkb){
    #pragma unroll
    for (int s = 0; s < 4; ++s){
      int kk = kkb*4 + s;
      bf16x8 af[2];
      #pragma unroll
      for (int rt = 0; rt < 2; ++rt){
        int arow = rt*32 + c31;
        af[rt] = *reinterpret_cast<const bf16x8*>(e1b + arow*1024 + ((kk*32 + hi*16) ^ ((arow&7)<<4)));
      }
      #pragma unroll
      for (int ct = 0; ct < 2; ++ct)
        #pragma unroll
        for (int rt = 0; rt < 2; ++rt)
          acc[rt][ct] = mfma32(bq[s][ct], af[rt], acc[rt][ct]);
      if (kkb < 7){
        #pragma unroll
        for (int ct = 0; ct < 2; ++ct)
          bq[s][ct] = *reinterpret_cast<const bf16x8*>(Brow + (kk+4)*16 + ct*16384);
      }
    }
  }
}

// ------------------------------------------------------- fused edge op ----
__global__ __launch_bounds__(512, 4) void edge_kernel(
    const int* __restrict__ eidx, const int* __restrict__ perm,
    const float* __restrict__ edge_attr,
    const float* __restrict__ pos,
    const __bf16* __restrict__ AB, const __bf16* __restrict__ weaT,
    const __bf16* __restrict__ we2b, const __bf16* __restrict__ wc1b,
    const float* __restrict__ b2,
    const float* __restrict__ bc1, const float* __restrict__ wc2,
    float* __restrict__ agg, float* __restrict__ pos_out)
{
  __shared__ __align__(16) __bf16 e1t[TE*512];   // 64KB swizzled (e1, later e2)
  // 8KB pool: swizzled ea tile during P0; f32 biases (b2|bc1|wc2) afterwards
  __shared__ __align__(16) char pool[8192];
  __shared__ float diffs[3][TE];
  __shared__ float rad[TE];
  __shared__ int   rl[TE], cl[TE], el[TE];
  __shared__ float cupart[8][TE];
  __shared__ float cuf[TE];
  __shared__ unsigned long long segmask;

  int tid = threadIdx.x;
  int e0 = blockIdx.x * TE;   // no swizzle: sorted tiles stay temporally close

  if (tid < TE){
    int eid = perm[e0 + tid];
    el[tid] = eid;
    int r = eidx[eid], c = eidx[N_EDGES + eid];
    rl[tid] = r; cl[tid] = c;
    float dx = pos[r*3+0]-pos[c*3+0];
    float dy = pos[r*3+1]-pos[c*3+1];
    float dz = pos[r*3+2]-pos[c*3+2];
    diffs[0][tid]=dx; diffs[1][tid]=dy; diffs[2][tid]=dz;
    float rr = dx*dx + dy*dy + dz*dz;
    rad[tid] = fminf(fmaxf(rr, 1e-8f), 100.f);
  }
  __syncthreads();

  // segment-boundary mask over the sorted 64 rows (wave 0 only)
  if (tid < 64){
    unsigned long long m = __ballot(tid > 0 && rl[tid] != rl[tid-1]);
    if (tid == 0) segmask = m;
  }

  // stage edge_attr (+radial k=51, one k=52, zero pad) swizzled bf16 [TE][64]
  {
    char* eb = pool;
    for (int i = tid; i < TE*64; i += 512){
      int e = i >> 6, k = i & 63;
      float v = (k < 51) ? edge_attr[(size_t)el[e]*51 + k]
              : (k == 51 ? rad[e] : (k == 52 ? 1.0f : 0.f));
      *reinterpret_cast<__bf16*>(eb + e*128 + ((k*2) ^ ((e&7)<<4))) = (__bf16)v;
    }
  }
  // prefill e1t with gather-sum (bf16, swizzled); bias comes via weaT k=52
  {
    int e = tid >> 3, q = tid & 7;
    size_t baseR = (size_t)rl[e]*1024;
    size_t baseC = (size_t)cl[e]*1024 + 512;
    char* eb = (char*)e1t;
    #pragma unroll
    for (int c = 0; c < 8; ++c){
      int o0 = q*8 + c*64;
      bf16x8 ga = *reinterpret_cast<const bf16x8*>(AB + baseR + o0);
      bf16x8 gb = *reinterpret_cast<const bf16x8*>(AB + baseC + o0);
      bf16x8 outv;
      #pragma unroll
      for (int j = 0; j < 8; ++j) outv[j] = (__bf16)((float)ga[j] + (float)gb[j]);
      *reinterpret_cast<bf16x8*>(eb + e*1024 + ((o0*2) ^ ((e&7)<<4))) = outv;
    }
  }
  __syncthreads();

  int lane = tid & 63, wid = tid >> 6;
  int c31 = lane & 31, hi = lane >> 5;
  int colbase = wid * 64;
  char* e1b = (char*)e1t;
  float* bpool = (float*)pool;   // [0..512)=b2, [512..1024)=bc1, [1024..1536)=wc2

  // P0: e1 = silu(prefill + ea@Wea^T) — swapped operands, vectorized b64 RMW
  {
    f32x16 acc[2][2];
    #pragma unroll
    for (int rt = 0; rt < 2; ++rt)
      #pragma unroll
      for (int ct = 0; ct < 2; ++ct)
        #pragma unroll
        for (int r = 0; r < 16; ++r) acc[rt][ct][r] = 0.f;
    const char* eb = pool;
    #pragma unroll
    for (int kk = 0; kk < 4; ++kk){
      bf16x8 af[2];
      #pragma unroll
      for (int rt = 0; rt < 2; ++rt){
        int arow = rt*32 + c31;
        af[rt] = *reinterpret_cast<const bf16x8*>(eb + arow*128 + ((kk*32 + hi*16) ^ ((arow&7)<<4)));
      }
      #pragma unroll
      for (int ct = 0; ct < 2; ++ct){
        int oc = colbase + ct*32 + c31;
        bf16x8 bfr = *reinterpret_cast<const bf16x8*>(weaT + (size_t)oc*64 + kk*16 + hi*8);
        #pragma unroll
        for (int rt = 0; rt < 2; ++rt) acc[rt][ct] = mfma32(bfr, af[rt], acc[rt][ct]);
      }
    }
    #pragma unroll
    for (int rt = 0; rt < 2; ++rt){
      int edge = rt*32 + c31;
      #pragma unroll
      for (int ct = 0; ct < 2; ++ct){
        #pragma unroll
        for (int q = 0; q < 4; ++q){
          int oc0 = colbase + ct*32 + 8*q + 4*hi;
          char* p = e1b + edge*1024 + ((oc0*2) ^ ((edge&7)<<4));
          bf16x4 pre = *reinterpret_cast<const bf16x4*>(p);
          bf16x4 outv;
          #pragma unroll
          for (int j = 0; j < 4; ++j){
            float v = (float)pre[j] + acc[rt][ct][4*q+j];
            outv[j] = (__bf16)silu_f(v);
          }
          *reinterpret_cast<bf16x4*>(p) = outv;
        }
      }
    }
  }
  __syncthreads();   // eat reads done -> pool is now free for biases

  // stage biases into the pool (read after the next barrier)
  bpool[tid]        = b2[tid];
  bpool[512 + tid]  = bc1[tid];
  bpool[1024 + tid] = wc2[tid];

  // P1: e2 = silu(e1 @ We2^T + b2); e2 -> e1t (vectorized b64 stores)
  {
    f32x16 acc[2][2];
    #pragma unroll
    for (int rt = 0; rt < 2; ++rt)
      #pragma unroll
      for (int ct = 0; ct < 2; ++ct)
        #pragma unroll
        for (int r = 0; r < 16; ++r) acc[rt][ct][r] = 0.f;
    gemm_phase_sw(e1b, we2b + (size_t)(colbase + c31)*512 + hi*8, c31, hi, acc);
    __syncthreads();   // all waves done READING e1t; biases visible
    #pragma unroll
    for (int rt = 0; rt < 2; ++rt){
      int edge = rt*32 + c31;
      #pragma unroll
      for (int ct = 0; ct < 2; ++ct){
        #pragma unroll
        for (int q = 0; q < 4; ++q){
          f32x4 b2v = *reinterpret_cast<const f32x4*>(bpool + colbase + ct*32 + 8*q + 4*hi);
          bf16x4 outv;
          #pragma unroll
          for (int j = 0; j < 4; ++j)
            outv[j] = (__bf16)silu_f(acc[rt][ct][4*q+j] + b2v[j]);
          int oc0 = colbase + ct*32 + 8*q + 4*hi;
          *reinterpret_cast<bf16x4*>(e1b + edge*1024 + ((oc0*2) ^ ((edge&7)<<4))) = outv;
        }
      }
    }
  }
  __syncthreads();

  // AGG: coalesced one-column-per-thread segment-flush atomics
  {
    int col = tid;  // 512 threads == 512 cols
    unsigned long long m = segmask;
    float a = 0.f;
    #pragma unroll
    for (int e = 0; e < TE; ++e){
      if (e > 0 && ((m >> e) & 1)){
        atomicAdd(&agg[(size_t)rl[e-1]*512 + col], a);
        a = 0.f;
      }
      a += (float)*reinterpret_cast<const __bf16*>(e1b + e*1024 + ((col*2) ^ ((e&7)<<4)));
    }
    atomicAdd(&agg[(size_t)rl[TE-1]*512 + col], a);
  }

  // P2: c1 = silu(e2 @ Wc1^T + bc1); cu = c1 . wc2 (lane-local + 1 shuffle)
  {
    f32x16 acc[2][2];
    #pragma unroll
    for (int rt = 0; rt < 2; ++rt)
      #pragma unroll
      for (int ct = 0; ct < 2; ++ct)
        #pragma unroll
        for (int r = 0; r < 16; ++r) acc[rt][ct][r] = 0.f;
    gemm_phase_sw(e1b, wc1b + (size_t)(colbase + c31)*512 + hi*8, c31, hi, acc);
    #pragma unroll
    for (int rt = 0; rt < 2; ++rt){
      float pv = 0.f;
      #pragma unroll
      for (int ct = 0; ct < 2; ++ct){
        #pragma unroll
        for (int q = 0; q < 4; ++q){
          f32x4 bcv = *reinterpret_cast<const f32x4*>(bpool + 512 + colbase + ct*32 + 8*q + 4*hi);
          f32x4 wcv = *reinterpret_cast<const f32x4*>(bpool + 1024 + colbase + ct*32 + 8*q + 4*hi);
          #pragma unroll
          for (int j = 0; j < 4; ++j)
            pv += silu_f(acc[rt][ct][4*q+j] + bcv[j]) * wcv[j];
        }
      }
      pv += __shfl_xor(pv, 32, 64);
      if (hi == 0) cupart[wid][rt*32 + c31] = pv;
    }
  }
  __syncthreads();

  if (tid < TE){
    float cu0 = 0.f;
    #pragma unroll
    for (int w = 0; w < 8; ++w) cu0 += cupart[w][tid];
    float cu = fminf(fmaxf(cu0, -1.f), 1.f);
    if (!isfinite(cu0)) cu = 0.f;
    cuf[tid] = cu;
  }
  __syncthreads();

  // POS: segmented per-axis sum (3 threads), mask-driven, unrolled
  if (tid < 3){
    int d = tid;
    unsigned long long m = segmask;
    float a = 0.f;
    #pragma unroll
    for (int e = 0; e < TE; ++e){
      if (e > 0 && ((m >> e) & 1)){
        atomicAdd(&pos_out[(size_t)rl[e-1]*3 + d], a);
        a = 0.f;
      }
      a += diffs[d][e] * cuf[e];
    }
    atomicAdd(&pos_out[(size_t)rl[TE-1]*3 + d], a);
  }
}

// ------------------------------------------------------------ node MLP ----
// 32 rows per wg (LDS 64KB -> 2 wg/CU, grid 512). 4 waves: 2 row-blocks x
// 2 col-halves of the 256 outputs.
__global__ __launch_bounds__(256) void node1_kernel(const float* __restrict__ h,
                                                    const float* __restrict__ agg,
                                                    const __bf16* __restrict__ wn1b,
                                                    const float* __restrict__ bn1,
                                                    __bf16* __restrict__ h1){
  __shared__ __align__(16) __bf16 At[32*1024];  // 64KB, row stride 2048B, swizzled
  int tid = threadIdx.x;
  int r0 = blockIdx.x * 32;
  char* ab = (char*)At;
  for (int it = 0; it < 32; ++it){
    int idx = it*1024 + tid*4;
    int row = idx >> 10, col = idx & 1023;
    float4 v;
    if (col < 512) v = *reinterpret_cast<const float4*>(h   + (size_t)(r0+row)*512 + col);
    else           v = *reinterpret_cast<const float4*>(agg + (size_t)(r0+row)*512 + (col-512));
    bf16x4 p = {(__bf16)v.x, (__bf16)v.y, (__bf16)v.z, (__bf16)v.w};
    *reinterpret_cast<bf16x4*>(ab + row*2048 + ((col*2) ^ ((row&7)<<4))) = p;
  }
  __syncthreads();
  int lane = tid & 63, wid = tid >> 6;
  int col16 = lane & 15, g = lane >> 4;
  int rw = wid & 1, cw = wid >> 1;
  int arow = rw*16 + col16;
  f32x4 acc[8];
  #pragma unroll
  for (int t = 0; t < 8; ++t) acc[t] = f32x4{0.f,0.f,0.f,0.f};
  for (int kk = 0; kk < 32; ++kk){
    bf16x8 af = *reinterpret_cast<const bf16x8*>(ab + arow*2048 + ((kk*64 + g*16) ^ ((arow&7)<<4)));
    #pragma unroll
    for (int t = 0; t < 8; ++t){
      int oc = cw*128 + t*16 + col16;
      bf16x8 bfr = *reinterpret_cast<const bf16x8*>(wn1b + (size_t)oc*1024 + kk*32 + g*8);
      acc[t] = mfma16(af, bfr, acc[t]);
    }
  }
  #pragma unroll
  for (int t = 0; t < 8; ++t){
    int oc = cw*128 + t*16 + col16;
    #pragma unroll
    for (int i2 = 0; i2 < 4; ++i2){
      int row = r0 + rw*16 + g*4 + i2;
      h1[(size_t)row*256 + oc] = (__bf16)silu_f(acc[t][i2] + bn1[oc]);
    }
  }
}

__global__ __launch_bounds__(256) void node2_kernel(const __bf16* __restrict__ h1,
                                                    const __bf16* __restrict__ wn2b,
                                                    const float* __restrict__ bn2,
                                                    float* __restrict__ hout){
  __shared__ __align__(16) __bf16 At[64*256];  // 32KB, row stride 512B, swizzled
  int tid = threadIdx.x;
  int r0 = blockIdx.x * 64;
  char* ab = (char*)At;
  for (int it = 0; it < 8; ++it){
    int idx = it*2048 + tid*8;
    int row = idx >> 8, col = idx & 255;
    bf16x8 v = *reinterpret_cast<const bf16x8*>(h1 + (size_t)(r0+row)*256 + col);
    *reinterpret_cast<bf16x8*>(ab + row*512 + ((col*2) ^ ((row&7)<<4))) = v;
  }
  __syncthreads();
  int lane = tid & 63, wid = tid >> 6;
  int col16 = lane & 15, g = lane >> 4;
  int arow = wid*16 + col16;
  f32x4 acc[16];
  #pragma unroll
  for (int t = 0; t < 16; ++t) acc[t] = f32x4{0.f,0.f,0.f,0.f};
  for (int kk = 0; kk < 8; ++kk){
    bf16x8 af = *reinterpret_cast<const bf16x8*>(ab + arow*512 + ((kk*64 + g*16) ^ ((arow&7)<<4)));
    #pragma unroll
    for (int t = 0; t < 16; ++t){
      int oc = t*16 + col16;
      bf16x8 bfr = *reinterpret_cast<const bf16x8*>(wn2b + (size_t)oc*256 + kk*32 + g*8);
      acc[t] = mfma16(af, bfr, acc[t]);
    }
  }
  #pragma unroll
  for (int t = 0; t < 16; ++t){
    int oc = t*16 + col16;
    #pragma unroll
    for (int i2 = 0; i2 < 4; ++i2){
      int row = r0 + wid*16 + g*4 + i2;
      hout[(size_t)row*256 + oc] = acc[t][i2] + bn2[oc];
    }
  }
}

// -------------------------------------------------------------- launch ----
extern "C" void kernel_launch(void* const* d_in, const int* in_sizes, int n_in,
                              void* d_out, int out_size, void* d_ws, size_t ws_size,
                              hipStream_t stream){
  const float* h   = (const float*)d_in[0];
  const int*   ei  = (const int*)d_in[1];
  const float* ea  = (const float*)d_in[2];
  const float* pos = (const float*)d_in[3];
  const float* We1 = (const float*)d_in[4];
  const float* be1 = (const float*)d_in[5];
  const float* We2 = (const float*)d_in[6];
  const float* be2 = (const float*)d_in[7];
  const float* Wc1 = (const float*)d_in[8];
  const float* bc1 = (const float*)d_in[9];
  const float* Wc2 = (const float*)d_in[10];
  const float* Wn1 = (const float*)d_in[11];
  const float* bn1 = (const float*)d_in[12];
  const float* Wn2 = (const float*)d_in[13];
  const float* bn2 = (const float*)d_in[14];

  char* ws = (char*)d_ws;
  size_t off = 0;
  auto carve = [&](size_t bytes) -> char* {
    char* p = ws + off; off += (bytes + 255) & ~(size_t)255; return p;
  };
  __bf16* wab  = (__bf16*)carve((size_t)1024*512*2);
  __bf16* weaT = (__bf16*)carve((size_t)512*64*2);
  __bf16* we2b = (__bf16*)carve((size_t)512*512*2);
  __bf16* wc1b = (__bf16*)carve((size_t)512*512*2);
  __bf16* wn1b = (__bf16*)carve((size_t)256*1024*2);
  __bf16* wn2b = (__bf16*)carve((size_t)256*256*2);
  __bf16* AB   = (__bf16*)carve((size_t)N_NODES*1024*2);
  float*  agg  = (float*) carve((size_t)N_NODES*512*4);
  __bf16* h1   = (__bf16*)carve((size_t)N_NODES*256*2);
  int*    deg    = (int*) carve((size_t)N_NODES*4);
  int*    basep  = (int*) carve((size_t)N_NODES*4);
  int*    cursor = (int*) carve((size_t)N_NODES*4);
  int*    perm   = (int*) carve((size_t)N_EDGES*4);

  float* hout = (float*)d_out;
  float* pout = (float*)d_out + (size_t)N_NODES*256;

  hipMemsetAsync(agg, 0, (size_t)N_NODES*512*4, stream);
  hipMemsetAsync(deg, 0, (size_t)N_NODES*4, stream);
  hipMemsetAsync(cursor, 0, (size_t)N_NODES*4, stream);
  hipMemcpyAsync((void*)pout, (const void*)pos, (size_t)N_NODES*3*4,
                 hipMemcpyDeviceToDevice, stream);

  prep_kernel<<<2048, 256, 0, stream>>>(We1, be1, We2, Wc1, Wn1, Wn2, ei,
                                        wab, weaT, we2b, wc1b, wn1b, wn2b, deg);
  scan_kernel<<<1, 1024, 0, stream>>>(deg, basep);
  scatter_kernel<<<N_EDGES/256, 256, 0, stream>>>(ei, basep, cursor, perm);
  gemm_ab_kernel<<<512, 256, 0, stream>>>(h, wab, AB);
  edge_kernel<<<N_EDGES/TE, 512, 0, stream>>>(ei, perm, ea, pos, AB, weaT, we2b, wc1b,
                                              be2, bc1, Wc2, agg, pout);
  node1_kernel<<<N_NODES/32, 256, 0, stream>>>(h, agg, wn1b, bn1, h1);
  node2_kernel<<<N_NODES/64, 256, 0, stream>>>(h1, wn2b, bn2, hout);
}

// Round 14
// 742.123 us; speedup vs baseline: 1.5307x; 1.2161x over previous
//
#include <hip/hip_runtime.h>

#define N_NODES 16384
#define N_EDGES 262144
#define TE 64   // edges per workgroup in edge kernel

typedef __attribute__((ext_vector_type(8))) __bf16 bf16x8;
typedef __attribute__((ext_vector_type(4))) __bf16 bf16x4;
typedef __attribute__((ext_vector_type(4))) float f32x4;
typedef __attribute__((ext_vector_type(16))) float f32x16;

// fast silu: v_rcp_f32 instead of precise-division sequence
__device__ __forceinline__ float silu_f(float x){
  return x * __builtin_amdgcn_rcpf(1.f + __expf(-x));
}

__device__ __forceinline__ f32x4 mfma16(bf16x8 a, bf16x8 b, f32x4 c){
  return __builtin_amdgcn_mfma_f32_16x16x32_bf16(a, b, c, 0, 0, 0);
}
__device__ __forceinline__ f32x16 mfma32(bf16x8 a, bf16x8 b, f32x16 c){
  return __builtin_amdgcn_mfma_f32_32x32x16_bf16(a, b, c, 0, 0, 0);
}

// ------------------------------------------------------ prep (+hist) ----
// All GEMM B-operands are PACKED into MFMA-fragment order so each fragment
// load is 64 lanes x 16 B = 1 KB contiguous (was a 32-segment scatter).
//  wabp  [cc=8][t=8][kk=16][lane=64][8] (1024*512 elems!):
//        o=cc*128+t*16+(lane&15), k=kk*32+(lane>>4)*8+j
//  weaTp [cb=16][kk=4][lane=64][8]:      o=cb*32+(lane&31),   k=kk*16+(lane>>5)*8+j
//  we2p/wc1p [cb=16][kk=32][lane=64][8]: row=cb*32+(lane&31), k=kk*16+(lane>>5)*8+j
__global__ void prep_kernel(const float* __restrict__ We1, const float* __restrict__ be1,
                            const float* __restrict__ We2,
                            const float* __restrict__ Wc1, const float* __restrict__ Wn1,
                            const float* __restrict__ Wn2, const int* __restrict__ eidx,
                            __bf16* wabp, __bf16* weaTp, __bf16* we2p, __bf16* wc1p,
                            __bf16* wn1b, __bf16* wn2b, int* __restrict__ deg){
  int i = blockIdx.x * 256 + threadIdx.x;
  if (i < 1024*512){   // FIX: full 1024 output rows (was 512*512 -> poison upper half)
    int j = i & 7, lane = (i>>3) & 63, kk = (i>>9) & 15, t = (i>>13) & 7, cc = i>>16;
    int o = cc*128 + t*16 + (lane & 15);
    int k = kk*32 + (lane>>4)*8 + j;
    float v = (o < 512) ? We1[(size_t)o*1076 + k] : We1[(size_t)(o-512)*1076 + 512 + k];
    wabp[i] = (__bf16)v;
  }
  if (i < 512*64){
    int j = i & 7, lane = (i>>3) & 63, kk = (i>>9) & 3, cb = i>>11;
    int o = cb*32 + (lane & 31);
    int k = kk*16 + (lane>>5)*8 + j;
    float v = (k < 51) ? We1[(size_t)o*1076 + 1024 + k]
            : (k == 51 ? We1[(size_t)o*1076 + 1075]
            : (k == 52 ? be1[o] : 0.f));
    weaTp[i] = (__bf16)v;
  }
  if (i < 512*512){
    int j = i & 7, lane = (i>>3) & 63, kk = (i>>9) & 31, cb = i>>14;
    int row = cb*32 + (lane & 31);
    int k = kk*16 + (lane>>5)*8 + j;
    we2p[i] = (__bf16)We2[(size_t)row*512 + k];
    wc1p[i] = (__bf16)Wc1[(size_t)row*512 + k];
  }
  if (i < 256*1024){ wn1b[i] = (__bf16)Wn1[i]; }
  if (i < 256*256){ wn2b[i] = (__bf16)Wn2[i]; }
  if (i < N_EDGES){ atomicAdd(&deg[eidx[i]], 1); }   // fused hist
}

// ------------------------------------------------- counting sort by row ----
__global__ __launch_bounds__(1024) void scan_kernel(const int* __restrict__ deg,
                                                    int* __restrict__ base){
  __shared__ int part[1024];
  int tid = threadIdx.x;
  int b = tid * 16;
  int local[16];
  int s = 0;
  #pragma unroll
  for (int i = 0; i < 16; ++i){ local[i] = deg[b+i]; s += local[i]; }
  part[tid] = s;
  __syncthreads();
  for (int off = 1; off < 1024; off <<= 1){
    int v = 0;
    if (tid >= off) v = part[tid-off];
    __syncthreads();
    part[tid] += v;
    __syncthreads();
  }
  int run = part[tid] - s;   // exclusive prefix of this chunk
  #pragma unroll
  for (int i = 0; i < 16; ++i){ base[b+i] = run; run += local[i]; }
}

__global__ void scatter_kernel(const int* __restrict__ eidx, const int* __restrict__ base,
                               int* __restrict__ cursor, int* __restrict__ perm){
  int e = blockIdx.x * 256 + threadIdx.x;
  if (e < N_EDGES){
    int r = eidx[e];
    int p = atomicAdd(&cursor[r], 1);
    perm[base[r] + p] = e;
  }
}

// ------------------------------------------------------------- gemm AB ----
// grid 512: bid>>1 = 64-row block, bid&1 = col half (4 of 8 cc blocks).
// B loads from wabp are fully coalesced (1KB/instr).
__global__ __launch_bounds__(256) void gemm_ab_kernel(const float* __restrict__ h,
                                                      const __bf16* __restrict__ wabp,
                                                      __bf16* __restrict__ AB){
  __shared__ __align__(16) __bf16 At[64*512];  // 64KB, swizzled
  int tid = threadIdx.x;
  int bid = blockIdx.x;
  int r0 = (bid >> 1) * 64;
  int cc0 = (bid & 1) * 4;
  char* ab = (char*)At;
  for (int it = 0; it < 32; ++it){
    int idx = it*1024 + tid*4;
    int row = idx >> 9, col = idx & 511;
    float4 v = *reinterpret_cast<const float4*>(h + (size_t)(r0+row)*512 + col);
    bf16x4 p = {(__bf16)v.x, (__bf16)v.y, (__bf16)v.z, (__bf16)v.w};
    *reinterpret_cast<bf16x4*>(ab + row*1024 + ((col*2) ^ ((row&7)<<4))) = p;
  }
  __syncthreads();
  int lane = tid & 63, wid = tid >> 6;
  int col16 = lane & 15, g = lane >> 4;
  int arow = wid*16 + col16;
  for (int cc = cc0; cc < cc0 + 4; ++cc){
    f32x4 acc[8];
    #pragma unroll
    for (int t = 0; t < 8; ++t) acc[t] = f32x4{0.f,0.f,0.f,0.f};
    for (int kk = 0; kk < 16; ++kk){
      bf16x8 af = *reinterpret_cast<const bf16x8*>(ab + arow*1024 + ((kk*64 + g*16) ^ ((arow&7)<<4)));
      #pragma unroll
      for (int t = 0; t < 8; ++t){
        bf16x8 bfr = *reinterpret_cast<const bf16x8*>(wabp + (size_t)(((cc*8+t)*16+kk)*512) + lane*8);
        acc[t] = mfma16(af, bfr, acc[t]);
      }
    }
    #pragma unroll
    for (int t = 0; t < 8; ++t){
      int oc = cc*128 + t*16 + col16;
      #pragma unroll
      for (int i2 = 0; i2 < 4; ++i2){
        int row = r0 + wid*16 + g*4 + i2;
        AB[(size_t)row*1024 + oc] = (__bf16)acc[t][i2];
      }
    }
  }
}

// --------------------------------------- K=512 phase, SWAPPED operands ----
// Bw = packed base + wid*32768 + lane*8; fragment (ct,kk) at +ct*16384+kk*512
// (1KB contiguous per load). 4-deep register ring prefetch.
__device__ __forceinline__ void gemm_phase_sw(const char* e1b, const __bf16* __restrict__ Bw,
                                              int c31, int hi, f32x16 acc[2][2]){
  bf16x8 bq[4][2];
  #pragma unroll
  for (int s = 0; s < 4; ++s)
    #pragma unroll
    for (int ct = 0; ct < 2; ++ct)
      bq[s][ct] = *reinterpret_cast<const bf16x8*>(Bw + ct*16384 + s*512);
  for (int kkb = 0; kkb < 8; ++kkb){
    #pragma unroll
    for (int s = 0; s < 4; ++s){
      int kk = kkb*4 + s;
      bf16x8 af[2];
      #pragma unroll
      for (int rt = 0; rt < 2; ++rt){
        int arow = rt*32 + c31;
        af[rt] = *reinterpret_cast<const bf16x8*>(e1b + arow*1024 + ((kk*32 + hi*16) ^ ((arow&7)<<4)));
      }
      #pragma unroll
      for (int ct = 0; ct < 2; ++ct)
        #pragma unroll
        for (int rt = 0; rt < 2; ++rt)
          acc[rt][ct] = mfma32(bq[s][ct], af[rt], acc[rt][ct]);
      if (kkb < 7){
        #pragma unroll
        for (int ct = 0; ct < 2; ++ct)
          bq[s][ct] = *reinterpret_cast<const bf16x8*>(Bw + ct*16384 + (kk+4)*512);
      }
    }
  }
}

// ------------------------------------------------------- fused edge op ----
__global__ __launch_bounds__(512, 4) void edge_kernel(
    const int* __restrict__ eidx, const int* __restrict__ perm,
    const float* __restrict__ edge_attr,
    const float* __restrict__ pos,
    const __bf16* __restrict__ AB, const __bf16* __restrict__ weaTp,
    const __bf16* __restrict__ we2p, const __bf16* __restrict__ wc1p,
    const float* __restrict__ b2,
    const float* __restrict__ bc1, const float* __restrict__ wc2,
    float* __restrict__ agg, float* __restrict__ pos_out)
{
  __shared__ __align__(16) __bf16 e1t[TE*512];   // 64KB swizzled (e1, later e2)
  // 8KB pool: swizzled ea tile during P0; f32 biases (b2|bc1|wc2) afterwards
  __shared__ __align__(16) char pool[8192];
  __shared__ float diffs[3][TE];
  __shared__ float rad[TE];
  __shared__ int   rl[TE], cl[TE], el[TE];
  __shared__ float cupart[8][TE];
  __shared__ float cuf[TE];
  __shared__ unsigned long long segmask;

  int tid = threadIdx.x;
  int e0 = blockIdx.x * TE;   // no swizzle: sorted tiles stay temporally close

  if (tid < TE){
    int eid = perm[e0 + tid];
    el[tid] = eid;
    int r = eidx[eid], c = eidx[N_EDGES + eid];
    rl[tid] = r; cl[tid] = c;
    float dx = pos[r*3+0]-pos[c*3+0];
    float dy = pos[r*3+1]-pos[c*3+1];
    float dz = pos[r*3+2]-pos[c*3+2];
    diffs[0][tid]=dx; diffs[1][tid]=dy; diffs[2][tid]=dz;
    float rr = dx*dx + dy*dy + dz*dz;
    rad[tid] = fminf(fmaxf(rr, 1e-8f), 100.f);
  }
  __syncthreads();

  // segment-boundary mask over the sorted 64 rows (wave 0 only)
  if (tid < 64){
    unsigned long long m = __ballot(tid > 0 && rl[tid] != rl[tid-1]);
    if (tid == 0) segmask = m;
  }

  // stage edge_attr (+radial k=51, one k=52, zero pad) swizzled bf16 [TE][64]
  {
    char* eb = pool;
    for (int i = tid; i < TE*64; i += 512){
      int e = i >> 6, k = i & 63;
      float v = (k < 51) ? edge_attr[(size_t)el[e]*51 + k]
              : (k == 51 ? rad[e] : (k == 52 ? 1.0f : 0.f));
      *reinterpret_cast<__bf16*>(eb + e*128 + ((k*2) ^ ((e&7)<<4))) = (__bf16)v;
    }
  }
  // prefill e1t with gather-sum (bf16, swizzled); bias comes via weaT k=52
  {
    int e = tid >> 3, q = tid & 7;
    size_t baseR = (size_t)rl[e]*1024;
    size_t baseC = (size_t)cl[e]*1024 + 512;
    char* eb = (char*)e1t;
    #pragma unroll
    for (int c = 0; c < 8; ++c){
      int o0 = q*8 + c*64;
      bf16x8 ga = *reinterpret_cast<const bf16x8*>(AB + baseR + o0);
      bf16x8 gb = *reinterpret_cast<const bf16x8*>(AB + baseC + o0);
      bf16x8 outv;
      #pragma unroll
      for (int j = 0; j < 8; ++j) outv[j] = (__bf16)((float)ga[j] + (float)gb[j]);
      *reinterpret_cast<bf16x8*>(eb + e*1024 + ((o0*2) ^ ((e&7)<<4))) = outv;
    }
  }
  __syncthreads();

  int lane = tid & 63, wid = tid >> 6;
  int c31 = lane & 31, hi = lane >> 5;
  int colbase = wid * 64;
  char* e1b = (char*)e1t;
  float* bpool = (float*)pool;   // [0..512)=b2, [512..1024)=bc1, [1024..1536)=wc2

  // P0: e1 = silu(prefill + ea@Wea^T) — swapped operands, vectorized b64 RMW
  {
    f32x16 acc[2][2];
    #pragma unroll
    for (int rt = 0; rt < 2; ++rt)
      #pragma unroll
      for (int ct = 0; ct < 2; ++ct)
        #pragma unroll
        for (int r = 0; r < 16; ++r) acc[rt][ct][r] = 0.f;
    const char* eb = pool;
    #pragma unroll
    for (int kk = 0; kk < 4; ++kk){
      bf16x8 af[2];
      #pragma unroll
      for (int rt = 0; rt < 2; ++rt){
        int arow = rt*32 + c31;
        af[rt] = *reinterpret_cast<const bf16x8*>(eb + arow*128 + ((kk*32 + hi*16) ^ ((arow&7)<<4)));
      }
      #pragma unroll
      for (int ct = 0; ct < 2; ++ct){
        bf16x8 bfr = *reinterpret_cast<const bf16x8*>(weaTp + (wid*2+ct)*2048 + kk*512 + lane*8);
        #pragma unroll
        for (int rt = 0; rt < 2; ++rt) acc[rt][ct] = mfma32(bfr, af[rt], acc[rt][ct]);
      }
    }
    #pragma unroll
    for (int rt = 0; rt < 2; ++rt){
      int edge = rt*32 + c31;
      #pragma unroll
      for (int ct = 0; ct < 2; ++ct){
        #pragma unroll
        for (int q = 0; q < 4; ++q){
          int oc0 = colbase + ct*32 + 8*q + 4*hi;
          char* p = e1b + edge*1024 + ((oc0*2) ^ ((edge&7)<<4));
          bf16x4 pre = *reinterpret_cast<const bf16x4*>(p);
          bf16x4 outv;
          #pragma unroll
          for (int j = 0; j < 4; ++j){
            float v = (float)pre[j] + acc[rt][ct][4*q+j];
            outv[j] = (__bf16)silu_f(v);
          }
          *reinterpret_cast<bf16x4*>(p) = outv;
        }
      }
    }
  }
  __syncthreads();   // eat reads done -> pool is now free for biases

  // stage biases into the pool (read after the next barrier)
  bpool[tid]        = b2[tid];
  bpool[512 + tid]  = bc1[tid];
  bpool[1024 + tid] = wc2[tid];

  // P1: e2 = silu(e1 @ We2^T + b2); e2 -> e1t (vectorized b64 stores)
  {
    f32x16 acc[2][2];
    #pragma unroll
    for (int rt = 0; rt < 2; ++rt)
      #pragma unroll
      for (int ct = 0; ct < 2; ++ct)
        #pragma unroll
        for (int r = 0; r < 16; ++r) acc[rt][ct][r] = 0.f;
    gemm_phase_sw(e1b, we2p + wid*32768 + lane*8, c31, hi, acc);
    __syncthreads();   // all waves done READING e1t; biases visible
    #pragma unroll
    for (int rt = 0; rt < 2; ++rt){
      int edge = rt*32 + c31;
      #pragma unroll
      for (int ct = 0; ct < 2; ++ct){
        #pragma unroll
        for (int q = 0; q < 4; ++q){
          f32x4 b2v = *reinterpret_cast<const f32x4*>(bpool + colbase + ct*32 + 8*q + 4*hi);
          bf16x4 outv;
          #pragma unroll
          for (int j = 0; j < 4; ++j)
            outv[j] = (__bf16)silu_f(acc[rt][ct][4*q+j] + b2v[j]);
          int oc0 = colbase + ct*32 + 8*q + 4*hi;
          *reinterpret_cast<bf16x4*>(e1b + edge*1024 + ((oc0*2) ^ ((edge&7)<<4))) = outv;
        }
      }
    }
  }
  __syncthreads();

  // AGG: coalesced one-column-per-thread segment-flush atomics
  {
    int col = tid;  // 512 threads == 512 cols
    unsigned long long m = segmask;
    float a = 0.f;
    #pragma unroll
    for (int e = 0; e < TE; ++e){
      if (e > 0 && ((m >> e) & 1)){
        atomicAdd(&agg[(size_t)rl[e-1]*512 + col], a);
        a = 0.f;
      }
      a += (float)*reinterpret_cast<const __bf16*>(e1b + e*1024 + ((col*2) ^ ((e&7)<<4)));
    }
    atomicAdd(&agg[(size_t)rl[TE-1]*512 + col], a);
  }

  // P2: c1 = silu(e2 @ Wc1^T + bc1); cu = c1 . wc2 (lane-local + 1 shuffle)
  {
    f32x16 acc[2][2];
    #pragma unroll
    for (int rt = 0; rt < 2; ++rt)
      #pragma unroll
      for (int ct = 0; ct < 2; ++ct)
        #pragma unroll
        for (int r = 0; r < 16; ++r) acc[rt][ct][r] = 0.f;
    gemm_phase_sw(e1b, wc1p + wid*32768 + lane*8, c31, hi, acc);
    #pragma unroll
    for (int rt = 0; rt < 2; ++rt){
      float pv = 0.f;
      #pragma unroll
      for (int ct = 0; ct < 2; ++ct){
        #pragma unroll
        for (int q = 0; q < 4; ++q){
          f32x4 bcv = *reinterpret_cast<const f32x4*>(bpool + 512 + colbase + ct*32 + 8*q + 4*hi);
          f32x4 wcv = *reinterpret_cast<const f32x4*>(bpool + 1024 + colbase + ct*32 + 8*q + 4*hi);
          #pragma unroll
          for (int j = 0; j < 4; ++j)
            pv += silu_f(acc[rt][ct][4*q+j] + bcv[j]) * wcv[j];
        }
      }
      pv += __shfl_xor(pv, 32, 64);
      if (hi == 0) cupart[wid][rt*32 + c31] = pv;
    }
  }
  __syncthreads();

  if (tid < TE){
    float cu0 = 0.f;
    #pragma unroll
    for (int w = 0; w < 8; ++w) cu0 += cupart[w][tid];
    float cu = fminf(fmaxf(cu0, -1.f), 1.f);
    if (!isfinite(cu0)) cu = 0.f;
    cuf[tid] = cu;
  }
  __syncthreads();

  // POS: segmented per-axis sum (3 threads), mask-driven, unrolled
  if (tid < 3){
    int d = tid;
    unsigned long long m = segmask;
    float a = 0.f;
    #pragma unroll
    for (int e = 0; e < TE; ++e){
      if (e > 0 && ((m >> e) & 1)){
        atomicAdd(&pos_out[(size_t)rl[e-1]*3 + d], a);
        a = 0.f;
      }
      a += diffs[d][e] * cuf[e];
    }
    atomicAdd(&pos_out[(size_t)rl[TE-1]*3 + d], a);
  }
}

// ------------------------------------------------------------ node MLP ----
__global__ __launch_bounds__(256) void node1_kernel(const float* __restrict__ h,
                                                    const float* __restrict__ agg,
                                                    const __bf16* __restrict__ wn1b,
                                                    const float* __restrict__ bn1,
                                                    __bf16* __restrict__ h1){
  __shared__ __align__(16) __bf16 At[32*1024];  // 64KB, row stride 2048B, swizzled
  int tid = threadIdx.x;
  int r0 = blockIdx.x * 32;
  char* ab = (char*)At;
  for (int it = 0; it < 32; ++it){
    int idx = it*1024 + tid*4;
    int row = idx >> 10, col = idx & 1023;
    float4 v;
    if (col < 512) v = *reinterpret_cast<const float4*>(h   + (size_t)(r0+row)*512 + col);
    else           v = *reinterpret_cast<const float4*>(agg + (size_t)(r0+row)*512 + (col-512));
    bf16x4 p = {(__bf16)v.x, (__bf16)v.y, (__bf16)v.z, (__bf16)v.w};
    *reinterpret_cast<bf16x4*>(ab + row*2048 + ((col*2) ^ ((row&7)<<4))) = p;
  }
  __syncthreads();
  int lane = tid & 63, wid = tid >> 6;
  int col16 = lane & 15, g = lane >> 4;
  int rw = wid & 1, cw = wid >> 1;
  int arow = rw*16 + col16;
  f32x4 acc[8];
  #pragma unroll
  for (int t = 0; t < 8; ++t) acc[t] = f32x4{0.f,0.f,0.f,0.f};
  for (int kk = 0; kk < 32; ++kk){
    bf16x8 af = *reinterpret_cast<const bf16x8*>(ab + arow*2048 + ((kk*64 + g*16) ^ ((arow&7)<<4)));
    #pragma unroll
    for (int t = 0; t < 8; ++t){
      int oc = cw*128 + t*16 + col16;
      bf16x8 bfr = *reinterpret_cast<const bf16x8*>(wn1b + (size_t)oc*1024 + kk*32 + g*8);
      acc[t] = mfma16(af, bfr, acc[t]);
    }
  }
  #pragma unroll
  for (int t = 0; t < 8; ++t){
    int oc = cw*128 + t*16 + col16;
    #pragma unroll
    for (int i2 = 0; i2 < 4; ++i2){
      int row = r0 + rw*16 + g*4 + i2;
      h1[(size_t)row*256 + oc] = (__bf16)silu_f(acc[t][i2] + bn1[oc]);
    }
  }
}

__global__ __launch_bounds__(256) void node2_kernel(const __bf16* __restrict__ h1,
                                                    const __bf16* __restrict__ wn2b,
                                                    const float* __restrict__ bn2,
                                                    float* __restrict__ hout){
  __shared__ __align__(16) __bf16 At[64*256];  // 32KB, row stride 512B, swizzled
  int tid = threadIdx.x;
  int r0 = blockIdx.x * 64;
  char* ab = (char*)At;
  for (int it = 0; it < 8; ++it){
    int idx = it*2048 + tid*8;
    int row = idx >> 8, col = idx & 255;
    bf16x8 v = *reinterpret_cast<const bf16x8*>(h1 + (size_t)(r0+row)*256 + col);
    *reinterpret_cast<bf16x8*>(ab + row*512 + ((col*2) ^ ((row&7)<<4))) = v;
  }
  __syncthreads();
  int lane = tid & 63, wid = tid >> 6;
  int col16 = lane & 15, g = lane >> 4;
  int arow = wid*16 + col16;
  f32x4 acc[16];
  #pragma unroll
  for (int t = 0; t < 16; ++t) acc[t] = f32x4{0.f,0.f,0.f,0.f};
  for (int kk = 0; kk < 8; ++kk){
    bf16x8 af = *reinterpret_cast<const bf16x8*>(ab + arow*512 + ((kk*64 + g*16) ^ ((arow&7)<<4)));
    #pragma unroll
    for (int t = 0; t < 16; ++t){
      int oc = t*16 + col16;
      bf16x8 bfr = *reinterpret_cast<const bf16x8*>(wn2b + (size_t)oc*256 + kk*32 + g*8);
      acc[t] = mfma16(af, bfr, acc[t]);
    }
  }
  #pragma unroll
  for (int t = 0; t < 16; ++t){
    int oc = t*16 + col16;
    #pragma unroll
    for (int i2 = 0; i2 < 4; ++i2){
      int row = r0 + wid*16 + g*4 + i2;
      hout[(size_t)row*256 + oc] = acc[t][i2] + bn2[oc];
    }
  }
}

// -------------------------------------------------------------- launch ----
extern "C" void kernel_launch(void* const* d_in, const int* in_sizes, int n_in,
                              void* d_out, int out_size, void* d_ws, size_t ws_size,
                              hipStream_t stream){
  const float* h   = (const float*)d_in[0];
  const int*   ei  = (const int*)d_in[1];
  const float* ea  = (const float*)d_in[2];
  const float* pos = (const float*)d_in[3];
  const float* We1 = (const float*)d_in[4];
  const float* be1 = (const float*)d_in[5];
  const float* We2 = (const float*)d_in[6];
  const float* be2 = (const float*)d_in[7];
  const float* Wc1 = (const float*)d_in[8];
  const float* bc1 = (const float*)d_in[9];
  const float* Wc2 = (const float*)d_in[10];
  const float* Wn1 = (const float*)d_in[11];
  const float* bn1 = (const float*)d_in[12];
  const float* Wn2 = (const float*)d_in[13];
  const float* bn2 = (const float*)d_in[14];

  char* ws = (char*)d_ws;
  size_t off = 0;
  auto carve = [&](size_t bytes) -> char* {
    char* p = ws + off; off += (bytes + 255) & ~(size_t)255; return p;
  };
  __bf16* wabp  = (__bf16*)carve((size_t)1024*512*2);   // FIX: full size
  __bf16* weaTp = (__bf16*)carve((size_t)512*64*2);
  __bf16* we2p  = (__bf16*)carve((size_t)512*512*2);
  __bf16* wc1p  = (__bf16*)carve((size_t)512*512*2);
  __bf16* wn1b  = (__bf16*)carve((size_t)256*1024*2);
  __bf16* wn2b  = (__bf16*)carve((size_t)256*256*2);
  __bf16* AB    = (__bf16*)carve((size_t)N_NODES*1024*2);
  float*  agg   = (float*) carve((size_t)N_NODES*512*4);
  __bf16* h1    = (__bf16*)carve((size_t)N_NODES*256*2);
  int*    deg    = (int*) carve((size_t)N_NODES*4);
  int*    basep  = (int*) carve((size_t)N_NODES*4);
  int*    cursor = (int*) carve((size_t)N_NODES*4);
  int*    perm   = (int*) carve((size_t)N_EDGES*4);

  float* hout = (float*)d_out;
  float* pout = (float*)d_out + (size_t)N_NODES*256;

  hipMemsetAsync(agg, 0, (size_t)N_NODES*512*4, stream);
  hipMemsetAsync(deg, 0, (size_t)N_NODES*4, stream);
  hipMemsetAsync(cursor, 0, (size_t)N_NODES*4, stream);
  hipMemcpyAsync((void*)pout, (const void*)pos, (size_t)N_NODES*3*4,
                 hipMemcpyDeviceToDevice, stream);

  prep_kernel<<<2048, 256, 0, stream>>>(We1, be1, We2, Wc1, Wn1, Wn2, ei,
                                        wabp, weaTp, we2p, wc1p, wn1b, wn2b, deg);
  scan_kernel<<<1, 1024, 0, stream>>>(deg, basep);
  scatter_kernel<<<N_EDGES/256, 256, 0, stream>>>(ei, basep, cursor, perm);
  gemm_ab_kernel<<<512, 256, 0, stream>>>(h, wabp, AB);
  edge_kernel<<<N_EDGES/TE, 512, 0, stream>>>(ei, perm, ea, pos, AB, weaTp, we2p, wc1p,
                                              be2, bc1, Wc2, agg, pout);
  node1_kernel<<<N_NODES/32, 256, 0, stream>>>(h, agg, wn1b, bn1, h1);
  node2_kernel<<<N_NODES/64, 256, 0, stream>>>(h1, wn2b, bn2, hout);
}

// Round 16
// 587.899 us; speedup vs baseline: 1.9322x; 1.2623x over previous
//
#include <hip/hip_runtime.h>

#define N_NODES 16384
#define N_EDGES 262144
#define TE 64   // edges per workgroup in edge kernel

typedef __attribute__((ext_vector_type(8))) __bf16 bf16x8;
typedef __attribute__((ext_vector_type(4))) __bf16 bf16x4;
typedef __attribute__((ext_vector_type(4))) float f32x4;
typedef __attribute__((ext_vector_type(16))) float f32x16;

// fast silu: v_rcp_f32 instead of precise-division sequence
__device__ __forceinline__ float silu_f(float x){
  return x * __builtin_amdgcn_rcpf(1.f + __expf(-x));
}

__device__ __forceinline__ f32x4 mfma16(bf16x8 a, bf16x8 b, f32x4 c){
  return __builtin_amdgcn_mfma_f32_16x16x32_bf16(a, b, c, 0, 0, 0);
}
__device__ __forceinline__ f32x16 mfma32(bf16x8 a, bf16x8 b, f32x16 c){
  return __builtin_amdgcn_mfma_f32_32x32x16_bf16(a, b, c, 0, 0, 0);
}

// ------------------------------------------------------ prep (+hist) ----
// All GEMM B-operands PACKED into MFMA-fragment order (1 KB contiguous per
// fragment load).
//  wabp  [cc=8][t=8][kk=16][lane=64][8] (1024*512 elems):
//        o=cc*128+t*16+(lane&15), k=kk*32+(lane>>4)*8+j
//  weaTp [cb=16][kk=4][lane=64][8]:      o=cb*32+(lane&31),   k=kk*16+(lane>>5)*8+j
//  we2p/wc1p [cb=16][kk=32][lane=64][8]: row=cb*32+(lane&31), k=kk*16+(lane>>5)*8+j
__global__ void prep_kernel(const float* __restrict__ We1, const float* __restrict__ be1,
                            const float* __restrict__ We2,
                            const float* __restrict__ Wc1, const float* __restrict__ Wn1,
                            const float* __restrict__ Wn2, const int* __restrict__ eidx,
                            __bf16* wabp, __bf16* weaTp, __bf16* we2p, __bf16* wc1p,
                            __bf16* wn1b, __bf16* wn2b, int* __restrict__ deg){
  int i = blockIdx.x * 256 + threadIdx.x;
  if (i < 1024*512){
    int j = i & 7, lane = (i>>3) & 63, kk = (i>>9) & 15, t = (i>>13) & 7, cc = i>>16;
    int o = cc*128 + t*16 + (lane & 15);
    int k = kk*32 + (lane>>4)*8 + j;
    float v = (o < 512) ? We1[(size_t)o*1076 + k] : We1[(size_t)(o-512)*1076 + 512 + k];
    wabp[i] = (__bf16)v;
  }
  if (i < 512*64){
    int j = i & 7, lane = (i>>3) & 63, kk = (i>>9) & 3, cb = i>>11;
    int o = cb*32 + (lane & 31);
    int k = kk*16 + (lane>>5)*8 + j;
    float v = (k < 51) ? We1[(size_t)o*1076 + 1024 + k]
            : (k == 51 ? We1[(size_t)o*1076 + 1075]
            : (k == 52 ? be1[o] : 0.f));
    weaTp[i] = (__bf16)v;
  }
  if (i < 512*512){
    int j = i & 7, lane = (i>>3) & 63, kk = (i>>9) & 31, cb = i>>14;
    int row = cb*32 + (lane & 31);
    int k = kk*16 + (lane>>5)*8 + j;
    we2p[i] = (__bf16)We2[(size_t)row*512 + k];
    wc1p[i] = (__bf16)Wc1[(size_t)row*512 + k];
  }
  if (i < 256*1024){ wn1b[i] = (__bf16)Wn1[i]; }
  if (i < 256*256){ wn2b[i] = (__bf16)Wn2[i]; }
  if (i < N_EDGES){ atomicAdd(&deg[eidx[i]], 1); }   // fused hist
}

// ------------------------------------------------- counting sort by row ----
__global__ __launch_bounds__(1024) void scan_kernel(const int* __restrict__ deg,
                                                    int* __restrict__ base){
  __shared__ int part[1024];
  int tid = threadIdx.x;
  int b = tid * 16;
  int local[16];
  int s = 0;
  #pragma unroll
  for (int i = 0; i < 16; ++i){ local[i] = deg[b+i]; s += local[i]; }
  part[tid] = s;
  __syncthreads();
  for (int off = 1; off < 1024; off <<= 1){
    int v = 0;
    if (tid >= off) v = part[tid-off];
    __syncthreads();
    part[tid] += v;
    __syncthreads();
  }
  int run = part[tid] - s;   // exclusive prefix of this chunk
  #pragma unroll
  for (int i = 0; i < 16; ++i){ base[b+i] = run; run += local[i]; }
}

__global__ void scatter_kernel(const int* __restrict__ eidx, const int* __restrict__ base,
                               int* __restrict__ cursor, int* __restrict__ perm){
  int e = blockIdx.x * 256 + threadIdx.x;
  if (e < N_EDGES){
    int r = eidx[e];
    int p = atomicAdd(&cursor[r], 1);
    perm[base[r] + p] = e;
  }
}

// ------------------------------------------------------------- gemm AB ----
__global__ __launch_bounds__(256) void gemm_ab_kernel(const float* __restrict__ h,
                                                      const __bf16* __restrict__ wabp,
                                                      __bf16* __restrict__ AB){
  __shared__ __align__(16) __bf16 At[64*512];  // 64KB, swizzled
  int tid = threadIdx.x;
  int bid = blockIdx.x;
  int r0 = (bid >> 1) * 64;
  int cc0 = (bid & 1) * 4;
  char* ab = (char*)At;
  for (int it = 0; it < 32; ++it){
    int idx = it*1024 + tid*4;
    int row = idx >> 9, col = idx & 511;
    float4 v = *reinterpret_cast<const float4*>(h + (size_t)(r0+row)*512 + col);
    bf16x4 p = {(__bf16)v.x, (__bf16)v.y, (__bf16)v.z, (__bf16)v.w};
    *reinterpret_cast<bf16x4*>(ab + row*1024 + ((col*2) ^ ((row&7)<<4))) = p;
  }
  __syncthreads();
  int lane = tid & 63, wid = tid >> 6;
  int col16 = lane & 15, g = lane >> 4;
  int arow = wid*16 + col16;
  for (int cc = cc0; cc < cc0 + 4; ++cc){
    f32x4 acc[8];
    #pragma unroll
    for (int t = 0; t < 8; ++t) acc[t] = f32x4{0.f,0.f,0.f,0.f};
    for (int kk = 0; kk < 16; ++kk){
      bf16x8 af = *reinterpret_cast<const bf16x8*>(ab + arow*1024 + ((kk*64 + g*16) ^ ((arow&7)<<4)));
      #pragma unroll
      for (int t = 0; t < 8; ++t){
        bf16x8 bfr = *reinterpret_cast<const bf16x8*>(wabp + (size_t)(((cc*8+t)*16+kk)*512) + lane*8);
        acc[t] = mfma16(af, bfr, acc[t]);
      }
    }
    #pragma unroll
    for (int t = 0; t < 8; ++t){
      int oc = cc*128 + t*16 + col16;
      #pragma unroll
      for (int i2 = 0; i2 < 4; ++i2){
        int row = r0 + wid*16 + g*4 + i2;
        AB[(size_t)row*1024 + oc] = (__bf16)acc[t][i2];
      }
    }
  }
}

// --------------------------------------- K=512 phase, SWAPPED operands ----
// Ring depth 2 (bq pre-primed with kk=0,1 by caller); packed contiguous
// 1KB fragment loads (L2-warm ~200cy covered by ~256cy of MFMA wall).
__device__ __forceinline__ void gemm_phase_sw(const char* e1b, const __bf16* __restrict__ Bw,
                                              int c31, int hi, f32x16 acc[2][2],
                                              bf16x8 bq[2][2]){
  for (int kkb = 0; kkb < 16; ++kkb){
    #pragma unroll
    for (int s = 0; s < 2; ++s){
      int kk = kkb*2 + s;
      bf16x8 af[2];
      #pragma unroll
      for (int rt = 0; rt < 2; ++rt){
        int arow = rt*32 + c31;
        af[rt] = *reinterpret_cast<const bf16x8*>(e1b + arow*1024 + ((kk*32 + hi*16) ^ ((arow&7)<<4)));
      }
      #pragma unroll
      for (int ct = 0; ct < 2; ++ct)
        #pragma unroll
        for (int rt = 0; rt < 2; ++rt)
          acc[rt][ct] = mfma32(bq[s][ct], af[rt], acc[rt][ct]);
      if (kk < 30){
        #pragma unroll
        for (int ct = 0; ct < 2; ++ct)
          bq[s][ct] = *reinterpret_cast<const bf16x8*>(Bw + ct*16384 + (kk+2)*512);
      }
    }
  }
}

// ------------------------------------------------------- fused edge op ----
__global__ __launch_bounds__(512, 4) void edge_kernel(
    const int* __restrict__ eidx, const int* __restrict__ perm,
    const float* __restrict__ edge_attr,
    const float* __restrict__ pos,
    const __bf16* __restrict__ AB, const __bf16* __restrict__ weaTp,
    const __bf16* __restrict__ we2p, const __bf16* __restrict__ wc1p,
    const float* __restrict__ b2,
    const float* __restrict__ bc1, const float* __restrict__ wc2,
    float* __restrict__ agg, float* __restrict__ pos_out)
{
  __shared__ __align__(16) __bf16 e1t[TE*512];   // 64KB swizzled (e1, later e2)
  // 8KB pool: swizzled ea tile during P0; f32 biases (b2|bc1|wc2) afterwards
  __shared__ __align__(16) char pool[8192];
  __shared__ float diffs[3][TE];
  __shared__ float rad[TE];
  __shared__ int   rl[TE], cl[TE], el[TE];
  __shared__ float cupart[8][TE];
  __shared__ float cuf[TE];
  __shared__ unsigned long long segmask;

  int tid = threadIdx.x;
  int e0 = blockIdx.x * TE;   // no swizzle: sorted tiles stay temporally close

  if (tid < TE){
    int eid = perm[e0 + tid];
    el[tid] = eid;
    int r = eidx[eid], c = eidx[N_EDGES + eid];
    rl[tid] = r; cl[tid] = c;
    float dx = pos[r*3+0]-pos[c*3+0];
    float dy = pos[r*3+1]-pos[c*3+1];
    float dz = pos[r*3+2]-pos[c*3+2];
    diffs[0][tid]=dx; diffs[1][tid]=dy; diffs[2][tid]=dz;
    float rr = dx*dx + dy*dy + dz*dz;
    rad[tid] = fminf(fmaxf(rr, 1e-8f), 100.f);
  }
  __syncthreads();

  // segment-boundary mask over the sorted 64 rows (wave 0 only)
  if (tid < 64){
    unsigned long long m = __ballot(tid > 0 && rl[tid] != rl[tid-1]);
    if (tid == 0) segmask = m;
  }

  // stage edge_attr (+radial k=51, one k=52, zero pad) swizzled bf16 [TE][64]
  {
    char* eb = pool;
    for (int i = tid; i < TE*64; i += 512){
      int e = i >> 6, k = i & 63;
      float v = (k < 51) ? edge_attr[(size_t)el[e]*51 + k]
              : (k == 51 ? rad[e] : (k == 52 ? 1.0f : 0.f));
      *reinterpret_cast<__bf16*>(eb + e*128 + ((k*2) ^ ((e&7)<<4))) = (__bf16)v;
    }
  }
  // prefill e1t with gather-sum (bf16, swizzled); bias comes via weaT k=52
  {
    int e = tid >> 3, q = tid & 7;
    size_t baseR = (size_t)rl[e]*1024;
    size_t baseC = (size_t)cl[e]*1024 + 512;
    char* eb = (char*)e1t;
    #pragma unroll
    for (int c = 0; c < 8; ++c){
      int o0 = q*8 + c*64;
      bf16x8 ga = *reinterpret_cast<const bf16x8*>(AB + baseR + o0);
      bf16x8 gb = *reinterpret_cast<const bf16x8*>(AB + baseC + o0);
      bf16x8 outv;
      #pragma unroll
      for (int j = 0; j < 8; ++j) outv[j] = (__bf16)((float)ga[j] + (float)gb[j]);
      *reinterpret_cast<bf16x8*>(eb + e*1024 + ((o0*2) ^ ((e&7)<<4))) = outv;
    }
  }
  __syncthreads();

  int lane = tid & 63, wid = tid >> 6;
  int c31 = lane & 31, hi = lane >> 5;
  int colbase = wid * 64;
  char* e1b = (char*)e1t;
  float* bpool = (float*)pool;   // [0..512)=b2, [512..1024)=bc1, [1024..1536)=wc2

  // P0: e1 = silu(prefill + ea@Wea^T) — swapped operands, vectorized b64 RMW
  {
    f32x16 acc[2][2];
    #pragma unroll
    for (int rt = 0; rt < 2; ++rt)
      #pragma unroll
      for (int ct = 0; ct < 2; ++ct)
        #pragma unroll
        for (int r = 0; r < 16; ++r) acc[rt][ct][r] = 0.f;
    const char* eb = pool;
    #pragma unroll
    for (int kk = 0; kk < 4; ++kk){
      bf16x8 af[2];
      #pragma unroll
      for (int rt = 0; rt < 2; ++rt){
        int arow = rt*32 + c31;
        af[rt] = *reinterpret_cast<const bf16x8*>(eb + arow*128 + ((kk*32 + hi*16) ^ ((arow&7)<<4)));
      }
      #pragma unroll
      for (int ct = 0; ct < 2; ++ct){
        bf16x8 bfr = *reinterpret_cast<const bf16x8*>(weaTp + (wid*2+ct)*2048 + kk*512 + lane*8);
        #pragma unroll
        for (int rt = 0; rt < 2; ++rt) acc[rt][ct] = mfma32(bfr, af[rt], acc[rt][ct]);
      }
    }
    #pragma unroll
    for (int rt = 0; rt < 2; ++rt){
      int edge = rt*32 + c31;
      #pragma unroll
      for (int ct = 0; ct < 2; ++ct){
        #pragma unroll
        for (int q = 0; q < 4; ++q){
          int oc0 = colbase + ct*32 + 8*q + 4*hi;
          char* p = e1b + edge*1024 + ((oc0*2) ^ ((edge&7)<<4));
          bf16x4 pre = *reinterpret_cast<const bf16x4*>(p);
          bf16x4 outv;
          #pragma unroll
          for (int j = 0; j < 4; ++j){
            float v = (float)pre[j] + acc[rt][ct][4*q+j];
            outv[j] = (__bf16)silu_f(v);
          }
          *reinterpret_cast<bf16x4*>(p) = outv;
        }
      }
    }
  }

  // prime P1's B-ring BEFORE the barrier (independent of LDS state)
  const __bf16* Bw1 = we2p + wid*32768 + lane*8;
  bf16x8 bq1[2][2];
  #pragma unroll
  for (int s = 0; s < 2; ++s)
    #pragma unroll
    for (int ct = 0; ct < 2; ++ct)
      bq1[s][ct] = *reinterpret_cast<const bf16x8*>(Bw1 + ct*16384 + s*512);

  __syncthreads();   // eat reads done -> pool is now free for biases

  // stage biases into the pool (read after the next barrier)
  bpool[tid]        = b2[tid];
  bpool[512 + tid]  = bc1[tid];
  bpool[1024 + tid] = wc2[tid];

  // P1: e2 = silu(e1 @ We2^T + b2); e2 -> e1t (vectorized b64 stores)
  {
    f32x16 acc[2][2];
    #pragma unroll
    for (int rt = 0; rt < 2; ++rt)
      #pragma unroll
      for (int ct = 0; ct < 2; ++ct)
        #pragma unroll
        for (int r = 0; r < 16; ++r) acc[rt][ct][r] = 0.f;
    gemm_phase_sw(e1b, Bw1, c31, hi, acc, bq1);
    __syncthreads();   // all waves done READING e1t; biases visible
    #pragma unroll
    for (int rt = 0; rt < 2; ++rt){
      int edge = rt*32 + c31;
      #pragma unroll
      for (int ct = 0; ct < 2; ++ct){
        #pragma unroll
        for (int q = 0; q < 4; ++q){
          f32x4 b2v = *reinterpret_cast<const f32x4*>(bpool + colbase + ct*32 + 8*q + 4*hi);
          bf16x4 outv;
          #pragma unroll
          for (int j = 0; j < 4; ++j)
            outv[j] = (__bf16)silu_f(acc[rt][ct][4*q+j] + b2v[j]);
          int oc0 = colbase + ct*32 + 8*q + 4*hi;
          *reinterpret_cast<bf16x4*>(e1b + edge*1024 + ((oc0*2) ^ ((edge&7)<<4))) = outv;
        }
      }
    }
  }
  __syncthreads();

  // prime P2's B-ring; its flight time is covered by the AGG block below
  const __bf16* Bw2 = wc1p + wid*32768 + lane*8;
  bf16x8 bq2[2][2];
  #pragma unroll
  for (int s = 0; s < 2; ++s)
    #pragma unroll
    for (int ct = 0; ct < 2; ++ct)
      bq2[s][ct] = *reinterpret_cast<const bf16x8*>(Bw2 + ct*16384 + s*512);

  // AGG: coalesced one-column-per-thread segment-flush atomics
  {
    int col = tid;  // 512 threads == 512 cols
    unsigned long long m = segmask;
    float a = 0.f;
    #pragma unroll
    for (int e = 0; e < TE; ++e){
      if (e > 0 && ((m >> e) & 1)){
        atomicAdd(&agg[(size_t)rl[e-1]*512 + col], a);
        a = 0.f;
      }
      a += (float)*reinterpret_cast<const __bf16*>(e1b + e*1024 + ((col*2) ^ ((e&7)<<4)));
    }
    atomicAdd(&agg[(size_t)rl[TE-1]*512 + col], a);
  }

  // P2: c1 = silu(e2 @ Wc1^T + bc1); cu = c1 . wc2 (lane-local + 1 shuffle)
  {
    f32x16 acc[2][2];
    #pragma unroll
    for (int rt = 0; rt < 2; ++rt)
      #pragma unroll
      for (int ct = 0; ct < 2; ++ct)
        #pragma unroll
        for (int r = 0; r < 16; ++r) acc[rt][ct][r] = 0.f;
    gemm_phase_sw(e1b, Bw2, c31, hi, acc, bq2);
    #pragma unroll
    for (int rt = 0; rt < 2; ++rt){
      float pv = 0.f;
      #pragma unroll
      for (int ct = 0; ct < 2; ++ct){
        #pragma unroll
        for (int q = 0; q < 4; ++q){
          f32x4 bcv = *reinterpret_cast<const f32x4*>(bpool + 512 + colbase + ct*32 + 8*q + 4*hi);
          f32x4 wcv = *reinterpret_cast<const f32x4*>(bpool + 1024 + colbase + ct*32 + 8*q + 4*hi);
          #pragma unroll
          for (int j = 0; j < 4; ++j)
            pv += silu_f(acc[rt][ct][4*q+j] + bcv[j]) * wcv[j];
        }
      }
      pv += __shfl_xor(pv, 32, 64);
      if (hi == 0) cupart[wid][rt*32 + c31] = pv;
    }
  }
  __syncthreads();

  if (tid < TE){
    float cu0 = 0.f;
    #pragma unroll
    for (int w = 0; w < 8; ++w) cu0 += cupart[w][tid];
    float cu = fminf(fmaxf(cu0, -1.f), 1.f);
    if (!isfinite(cu0)) cu = 0.f;
    cuf[tid] = cu;
  }
  __syncthreads();

  // POS: segmented per-axis sum (3 threads), mask-driven, unrolled
  if (tid < 3){
    int d = tid;
    unsigned long long m = segmask;
    float a = 0.f;
    #pragma unroll
    for (int e = 0; e < TE; ++e){
      if (e > 0 && ((m >> e) & 1)){
        atomicAdd(&pos_out[(size_t)rl[e-1]*3 + d], a);
        a = 0.f;
      }
      a += diffs[d][e] * cuf[e];
    }
    atomicAdd(&pos_out[(size_t)rl[TE-1]*3 + d], a);
  }
}

// ------------------------------------------------------------ node MLP ----
__global__ __launch_bounds__(256) void node1_kernel(const float* __restrict__ h,
                                                    const float* __restrict__ agg,
                                                    const __bf16* __restrict__ wn1b,
                                                    const float* __restrict__ bn1,
                                                    __bf16* __restrict__ h1){
  __shared__ __align__(16) __bf16 At[32*1024];  // 64KB, row stride 2048B, swizzled
  int tid = threadIdx.x;
  int r0 = blockIdx.x * 32;
  char* ab = (char*)At;
  for (int it = 0; it < 32; ++it){
    int idx = it*1024 + tid*4;
    int row = idx >> 10, col = idx & 1023;
    float4 v;
    if (col < 512) v = *reinterpret_cast<const float4*>(h   + (size_t)(r0+row)*512 + col);
    else           v = *reinterpret_cast<const float4*>(agg + (size_t)(r0+row)*512 + (col-512));
    bf16x4 p = {(__bf16)v.x, (__bf16)v.y, (__bf16)v.z, (__bf16)v.w};
    *reinterpret_cast<bf16x4*>(ab + row*2048 + ((col*2) ^ ((row&7)<<4))) = p;
  }
  __syncthreads();
  int lane = tid & 63, wid = tid >> 6;
  int col16 = lane & 15, g = lane >> 4;
  int rw = wid & 1, cw = wid >> 1;
  int arow = rw*16 + col16;
  f32x4 acc[8];
  #pragma unroll
  for (int t = 0; t < 8; ++t) acc[t] = f32x4{0.f,0.f,0.f,0.f};
  for (int kk = 0; kk < 32; ++kk){
    bf16x8 af = *reinterpret_cast<const bf16x8*>(ab + arow*2048 + ((kk*64 + g*16) ^ ((arow&7)<<4)));
    #pragma unroll
    for (int t = 0; t < 8; ++t){
      int oc = cw*128 + t*16 + col16;
      bf16x8 bfr = *reinterpret_cast<const bf16x8*>(wn1b + (size_t)oc*1024 + kk*32 + g*8);
      acc[t] = mfma16(af, bfr, acc[t]);
    }
  }
  #pragma unroll
  for (int t = 0; t < 8; ++t){
    int oc = cw*128 + t*16 + col16;
    #pragma unroll
    for (int i2 = 0; i2 < 4; ++i2){
      int row = r0 + rw*16 + g*4 + i2;
      h1[(size_t)row*256 + oc] = (__bf16)silu_f(acc[t][i2] + bn1[oc]);
    }
  }
}

__global__ __launch_bounds__(256) void node2_kernel(const __bf16* __restrict__ h1,
                                                    const __bf16* __restrict__ wn2b,
                                                    const float* __restrict__ bn2,
                                                    float* __restrict__ hout){
  __shared__ __align__(16) __bf16 At[64*256];  // 32KB, row stride 512B, swizzled
  int tid = threadIdx.x;
  int r0 = blockIdx.x * 64;
  char* ab = (char*)At;
  for (int it = 0; it < 8; ++it){
    int idx = it*2048 + tid*8;
    int row = idx >> 8, col = idx & 255;
    bf16x8 v = *reinterpret_cast<const bf16x8*>(h1 + (size_t)(r0+row)*256 + col);
    *reinterpret_cast<bf16x8*>(ab + row*512 + ((col*2) ^ ((row&7)<<4))) = v;
  }
  __syncthreads();
  int lane = tid & 63, wid = tid >> 6;
  int col16 = lane & 15, g = lane >> 4;
  int arow = wid*16 + col16;
  f32x4 acc[16];
  #pragma unroll
  for (int t = 0; t < 16; ++t) acc[t] = f32x4{0.f,0.f,0.f,0.f};
  for (int kk = 0; kk < 8; ++kk){
    bf16x8 af = *reinterpret_cast<const bf16x8*>(ab + arow*512 + ((kk*64 + g*16) ^ ((arow&7)<<4)));
    #pragma unroll
    for (int t = 0; t < 16; ++t){
      int oc = t*16 + col16;
      bf16x8 bfr = *reinterpret_cast<const bf16x8*>(wn2b + (size_t)oc*256 + kk*32 + g*8);
      acc[t] = mfma16(af, bfr, acc[t]);
    }
  }
  #pragma unroll
  for (int t = 0; t < 16; ++t){
    int oc = t*16 + col16;
    #pragma unroll
    for (int i2 = 0; i2 < 4; ++i2){
      int row = r0 + wid*16 + g*4 + i2;
      hout[(size_t)row*256 + oc] = acc[t][i2] + bn2[oc];
    }
  }
}

// -------------------------------------------------------------- launch ----
extern "C" void kernel_launch(void* const* d_in, const int* in_sizes, int n_in,
                              void* d_out, int out_size, void* d_ws, size_t ws_size,
                              hipStream_t stream){
  const float* h   = (const float*)d_in[0];
  const int*   ei  = (const int*)d_in[1];
  const float* ea  = (const float*)d_in[2];
  const float* pos = (const float*)d_in[3];
  const float* We1 = (const float*)d_in[4];
  const float* be1 = (const float*)d_in[5];
  const float* We2 = (const float*)d_in[6];
  const float* be2 = (const float*)d_in[7];
  const float* Wc1 = (const float*)d_in[8];
  const float* bc1 = (const float*)d_in[9];
  const float* Wc2 = (const float*)d_in[10];
  const float* Wn1 = (const float*)d_in[11];
  const float* bn1 = (const float*)d_in[12];
  const float* Wn2 = (const float*)d_in[13];
  const float* bn2 = (const float*)d_in[14];

  char* ws = (char*)d_ws;
  size_t off = 0;
  auto carve = [&](size_t bytes) -> char* {
    char* p = ws + off; off += (bytes + 255) & ~(size_t)255; return p;
  };
  __bf16* wabp  = (__bf16*)carve((size_t)1024*512*2);
  __bf16* weaTp = (__bf16*)carve((size_t)512*64*2);
  __bf16* we2p  = (__bf16*)carve((size_t)512*512*2);
  __bf16* wc1p  = (__bf16*)carve((size_t)512*512*2);
  __bf16* wn1b  = (__bf16*)carve((size_t)256*1024*2);
  __bf16* wn2b  = (__bf16*)carve((size_t)256*256*2);
  __bf16* AB    = (__bf16*)carve((size_t)N_NODES*1024*2);
  float*  agg   = (float*) carve((size_t)N_NODES*512*4);
  __bf16* h1    = (__bf16*)carve((size_t)N_NODES*256*2);
  int*    deg    = (int*) carve((size_t)N_NODES*4);
  int*    basep  = (int*) carve((size_t)N_NODES*4);
  int*    cursor = (int*) carve((size_t)N_NODES*4);
  int*    perm   = (int*) carve((size_t)N_EDGES*4);

  float* hout = (float*)d_out;
  float* pout = (float*)d_out + (size_t)N_NODES*256;

  hipMemsetAsync(agg, 0, (size_t)N_NODES*512*4, stream);
  hipMemsetAsync(deg, 0, (size_t)N_NODES*4, stream);
  hipMemsetAsync(cursor, 0, (size_t)N_NODES*4, stream);
  hipMemcpyAsync((void*)pout, (const void*)pos, (size_t)N_NODES*3*4,
                 hipMemcpyDeviceToDevice, stream);

  prep_kernel<<<2048, 256, 0, stream>>>(We1, be1, We2, Wc1, Wn1, Wn2, ei,
                                        wabp, weaTp, we2p, wc1p, wn1b, wn2b, deg);
  scan_kernel<<<1, 1024, 0, stream>>>(deg, basep);
  scatter_kernel<<<N_EDGES/256, 256, 0, stream>>>(ei, basep, cursor, perm);
  gemm_ab_kernel<<<512, 256, 0, stream>>>(h, wabp, AB);
  edge_kernel<<<N_EDGES/TE, 512, 0, stream>>>(ei, perm, ea, pos, AB, weaTp, we2p, wc1p,
                                              be2, bc1, Wc2, agg, pout);
  node1_kernel<<<N_NODES/32, 256, 0, stream>>>(h, agg, wn1b, bn1, h1);
  node2_kernel<<<N_NODES/64, 256, 0, stream>>>(h1, wn2b, bn2, hout);
}

// Round 17
// 582.804 us; speedup vs baseline: 1.9491x; 1.0087x over previous
//
#include <hip/hip_runtime.h>

#define N_NODES 16384
#define N_EDGES 262144
#define TE 64   // edges per workgroup in edge kernel

typedef __attribute__((ext_vector_type(8))) __bf16 bf16x8;
typedef __attribute__((ext_vector_type(4))) __bf16 bf16x4;
typedef __attribute__((ext_vector_type(4))) float f32x4;
typedef __attribute__((ext_vector_type(16))) float f32x16;

// fast silu: v_rcp_f32 instead of precise-division sequence
__device__ __forceinline__ float silu_f(float x){
  return x * __builtin_amdgcn_rcpf(1.f + __expf(-x));
}

__device__ __forceinline__ f32x4 mfma16(bf16x8 a, bf16x8 b, f32x4 c){
  return __builtin_amdgcn_mfma_f32_16x16x32_bf16(a, b, c, 0, 0, 0);
}
__device__ __forceinline__ f32x16 mfma32(bf16x8 a, bf16x8 b, f32x16 c){
  return __builtin_amdgcn_mfma_f32_32x32x16_bf16(a, b, c, 0, 0, 0);
}

// ------------------------------------------------------ prep (+hist) ----
// All GEMM B-operands PACKED into MFMA-fragment order (1 KB contiguous per
// fragment load).
__global__ void prep_kernel(const float* __restrict__ We1, const float* __restrict__ be1,
                            const float* __restrict__ We2,
                            const float* __restrict__ Wc1, const float* __restrict__ Wn1,
                            const float* __restrict__ Wn2, const int* __restrict__ eidx,
                            __bf16* wabp, __bf16* weaTp, __bf16* we2p, __bf16* wc1p,
                            __bf16* wn1b, __bf16* wn2b, int* __restrict__ deg){
  int i = blockIdx.x * 256 + threadIdx.x;
  if (i < 1024*512){
    int j = i & 7, lane = (i>>3) & 63, kk = (i>>9) & 15, t = (i>>13) & 7, cc = i>>16;
    int o = cc*128 + t*16 + (lane & 15);
    int k = kk*32 + (lane>>4)*8 + j;
    float v = (o < 512) ? We1[(size_t)o*1076 + k] : We1[(size_t)(o-512)*1076 + 512 + k];
    wabp[i] = (__bf16)v;
  }
  if (i < 512*64){
    int j = i & 7, lane = (i>>3) & 63, kk = (i>>9) & 3, cb = i>>11;
    int o = cb*32 + (lane & 31);
    int k = kk*16 + (lane>>5)*8 + j;
    float v = (k < 51) ? We1[(size_t)o*1076 + 1024 + k]
            : (k == 51 ? We1[(size_t)o*1076 + 1075]
            : (k == 52 ? be1[o] : 0.f));
    weaTp[i] = (__bf16)v;
  }
  if (i < 512*512){
    int j = i & 7, lane = (i>>3) & 63, kk = (i>>9) & 31, cb = i>>14;
    int row = cb*32 + (lane & 31);
    int k = kk*16 + (lane>>5)*8 + j;
    we2p[i] = (__bf16)We2[(size_t)row*512 + k];
    wc1p[i] = (__bf16)Wc1[(size_t)row*512 + k];
  }
  if (i < 256*1024){ wn1b[i] = (__bf16)Wn1[i]; }
  if (i < 256*256){ wn2b[i] = (__bf16)Wn2[i]; }
  if (i < N_EDGES){ atomicAdd(&deg[eidx[i]], 1); }   // fused hist
}

// ------------------------------------------------- counting sort by row ----
__global__ __launch_bounds__(1024) void scan_kernel(const int* __restrict__ deg,
                                                    int* __restrict__ base){
  __shared__ int part[1024];
  int tid = threadIdx.x;
  int b = tid * 16;
  int local[16];
  int s = 0;
  #pragma unroll
  for (int i = 0; i < 16; ++i){ local[i] = deg[b+i]; s += local[i]; }
  part[tid] = s;
  __syncthreads();
  for (int off = 1; off < 1024; off <<= 1){
    int v = 0;
    if (tid >= off) v = part[tid-off];
    __syncthreads();
    part[tid] += v;
    __syncthreads();
  }
  int run = part[tid] - s;   // exclusive prefix of this chunk
  #pragma unroll
  for (int i = 0; i < 16; ++i){ base[b+i] = run; run += local[i]; }
}

__global__ void scatter_kernel(const int* __restrict__ eidx, const int* __restrict__ base,
                               int* __restrict__ cursor, int* __restrict__ perm){
  int e = blockIdx.x * 256 + threadIdx.x;
  if (e < N_EDGES){
    int r = eidx[e];
    int p = atomicAdd(&cursor[r], 1);
    perm[base[r] + p] = e;
  }
}

// ------------------------------------------------------------- gemm AB ----
__global__ __launch_bounds__(256) void gemm_ab_kernel(const float* __restrict__ h,
                                                      const __bf16* __restrict__ wabp,
                                                      __bf16* __restrict__ AB){
  __shared__ __align__(16) __bf16 At[64*512];  // 64KB, swizzled
  int tid = threadIdx.x;
  int bid = blockIdx.x;
  int r0 = (bid >> 1) * 64;
  int cc0 = (bid & 1) * 4;
  char* ab = (char*)At;
  for (int it = 0; it < 32; ++it){
    int idx = it*1024 + tid*4;
    int row = idx >> 9, col = idx & 511;
    float4 v = *reinterpret_cast<const float4*>(h + (size_t)(r0+row)*512 + col);
    bf16x4 p = {(__bf16)v.x, (__bf16)v.y, (__bf16)v.z, (__bf16)v.w};
    *reinterpret_cast<bf16x4*>(ab + row*1024 + ((col*2) ^ ((row&7)<<4))) = p;
  }
  __syncthreads();
  int lane = tid & 63, wid = tid >> 6;
  int col16 = lane & 15, g = lane >> 4;
  int arow = wid*16 + col16;
  for (int cc = cc0; cc < cc0 + 4; ++cc){
    f32x4 acc[8];
    #pragma unroll
    for (int t = 0; t < 8; ++t) acc[t] = f32x4{0.f,0.f,0.f,0.f};
    for (int kk = 0; kk < 16; ++kk){
      bf16x8 af = *reinterpret_cast<const bf16x8*>(ab + arow*1024 + ((kk*64 + g*16) ^ ((arow&7)<<4)));
      #pragma unroll
      for (int t = 0; t < 8; ++t){
        bf16x8 bfr = *reinterpret_cast<const bf16x8*>(wabp + (size_t)(((cc*8+t)*16+kk)*512) + lane*8);
        acc[t] = mfma16(af, bfr, acc[t]);
      }
    }
    #pragma unroll
    for (int t = 0; t < 8; ++t){
      int oc = cc*128 + t*16 + col16;
      #pragma unroll
      for (int i2 = 0; i2 < 4; ++i2){
        int row = r0 + wid*16 + g*4 + i2;
        AB[(size_t)row*1024 + oc] = (__bf16)acc[t][i2];
      }
    }
  }
}

// --------------------------------------- K=512 phase, SWAPPED operands ----
// Ring depth 2 (bq pre-primed); e1t swizzle upgraded to 4-bit ((row&15)<<4)
// -> 16 slots, 2-way bank aliasing (free) for the 32-row A-fragment reads.
__device__ __forceinline__ void gemm_phase_sw(const char* e1b, const __bf16* __restrict__ Bw,
                                              int c31, int hi, f32x16 acc[2][2],
                                              bf16x8 bq[2][2]){
  for (int kkb = 0; kkb < 16; ++kkb){
    #pragma unroll
    for (int s = 0; s < 2; ++s){
      int kk = kkb*2 + s;
      bf16x8 af[2];
      #pragma unroll
      for (int rt = 0; rt < 2; ++rt){
        int arow = rt*32 + c31;
        af[rt] = *reinterpret_cast<const bf16x8*>(e1b + arow*1024 + ((kk*32 + hi*16) ^ ((arow&15)<<4)));
      }
      #pragma unroll
      for (int ct = 0; ct < 2; ++ct)
        #pragma unroll
        for (int rt = 0; rt < 2; ++rt)
          acc[rt][ct] = mfma32(bq[s][ct], af[rt], acc[rt][ct]);
      if (kk < 30){
        #pragma unroll
        for (int ct = 0; ct < 2; ++ct)
          bq[s][ct] = *reinterpret_cast<const bf16x8*>(Bw + ct*16384 + (kk+2)*512);
      }
    }
  }
}

// ------------------------------------------------------- fused edge op ----
__global__ __launch_bounds__(512, 4) void edge_kernel(
    const int* __restrict__ eidx, const int* __restrict__ perm,
    const float* __restrict__ edge_attr,
    const float* __restrict__ pos,
    const __bf16* __restrict__ AB, const __bf16* __restrict__ weaTp,
    const __bf16* __restrict__ we2p, const __bf16* __restrict__ wc1p,
    const float* __restrict__ b2,
    const float* __restrict__ bc1, const float* __restrict__ wc2,
    float* __restrict__ agg, float* __restrict__ pos_out)
{
  __shared__ __align__(16) __bf16 e1t[TE*512];   // 64KB, 4-bit swizzle
  // 8KB pool: swizzled ea tile during P0 (3-bit swizzle: 128B rows); biases after
  __shared__ __align__(16) char pool[8192];
  __shared__ float diffs[3][TE];
  __shared__ float rad[TE];
  __shared__ int   rl[TE], cl[TE], el[TE];
  __shared__ float cupart[8][TE];
  __shared__ float cuf[TE];
  __shared__ unsigned long long segmask;

  int tid = threadIdx.x;
  int e0 = blockIdx.x * TE;   // no swizzle: sorted tiles stay temporally close

  if (tid < TE){
    int eid = perm[e0 + tid];
    el[tid] = eid;
    int r = eidx[eid], c = eidx[N_EDGES + eid];
    rl[tid] = r; cl[tid] = c;
    float dx = pos[r*3+0]-pos[c*3+0];
    float dy = pos[r*3+1]-pos[c*3+1];
    float dz = pos[r*3+2]-pos[c*3+2];
    diffs[0][tid]=dx; diffs[1][tid]=dy; diffs[2][tid]=dz;
    float rr = dx*dx + dy*dy + dz*dz;
    rad[tid] = fminf(fmaxf(rr, 1e-8f), 100.f);
  }
  __syncthreads();

  // segment-boundary mask over the sorted 64 rows (wave 0 only)
  if (tid < 64){
    unsigned long long m = __ballot(tid > 0 && rl[tid] != rl[tid-1]);
    if (tid == 0) segmask = m;
  }

  // stage edge_attr (+radial k=51, one k=52, zero pad) swizzled bf16 [TE][64]
  {
    char* eb = pool;
    for (int i = tid; i < TE*64; i += 512){
      int e = i >> 6, k = i & 63;
      float v = (k < 51) ? edge_attr[(size_t)el[e]*51 + k]
              : (k == 51 ? rad[e] : (k == 52 ? 1.0f : 0.f));
      *reinterpret_cast<__bf16*>(eb + e*128 + ((k*2) ^ ((e&7)<<4))) = (__bf16)v;
    }
  }
  // prefill e1t with gather-sum (bf16, 4-bit swizzle); bias via weaT k=52
  {
    int e = tid >> 3, q = tid & 7;
    size_t baseR = (size_t)rl[e]*1024;
    size_t baseC = (size_t)cl[e]*1024 + 512;
    char* eb = (char*)e1t;
    #pragma unroll
    for (int c = 0; c < 8; ++c){
      int o0 = q*8 + c*64;
      bf16x8 ga = *reinterpret_cast<const bf16x8*>(AB + baseR + o0);
      bf16x8 gb = *reinterpret_cast<const bf16x8*>(AB + baseC + o0);
      bf16x8 outv;
      #pragma unroll
      for (int j = 0; j < 8; ++j) outv[j] = (__bf16)((float)ga[j] + (float)gb[j]);
      *reinterpret_cast<bf16x8*>(eb + e*1024 + ((o0*2) ^ ((e&15)<<4))) = outv;
    }
  }
  __syncthreads();

  int lane = tid & 63, wid = tid >> 6;
  int c31 = lane & 31, hi = lane >> 5;
  int colbase = wid * 64;
  char* e1b = (char*)e1t;
  float* bpool = (float*)pool;   // [0..512)=b2, [512..1024)=bc1, [1024..1536)=wc2

  // P0: e1 = silu(prefill + ea@Wea^T) — swapped operands, vectorized b64 RMW
  {
    f32x16 acc[2][2];
    #pragma unroll
    for (int rt = 0; rt < 2; ++rt)
      #pragma unroll
      for (int ct = 0; ct < 2; ++ct)
        #pragma unroll
        for (int r = 0; r < 16; ++r) acc[rt][ct][r] = 0.f;
    const char* eb = pool;
    #pragma unroll
    for (int kk = 0; kk < 4; ++kk){
      bf16x8 af[2];
      #pragma unroll
      for (int rt = 0; rt < 2; ++rt){
        int arow = rt*32 + c31;
        af[rt] = *reinterpret_cast<const bf16x8*>(eb + arow*128 + ((kk*32 + hi*16) ^ ((arow&7)<<4)));
      }
      #pragma unroll
      for (int ct = 0; ct < 2; ++ct){
        bf16x8 bfr = *reinterpret_cast<const bf16x8*>(weaTp + (wid*2+ct)*2048 + kk*512 + lane*8);
        #pragma unroll
        for (int rt = 0; rt < 2; ++rt) acc[rt][ct] = mfma32(bfr, af[rt], acc[rt][ct]);
      }
    }
    #pragma unroll
    for (int rt = 0; rt < 2; ++rt){
      int edge = rt*32 + c31;
      #pragma unroll
      for (int ct = 0; ct < 2; ++ct){
        #pragma unroll
        for (int q = 0; q < 4; ++q){
          int oc0 = colbase + ct*32 + 8*q + 4*hi;
          char* p = e1b + edge*1024 + ((oc0*2) ^ ((edge&15)<<4));
          bf16x4 pre = *reinterpret_cast<const bf16x4*>(p);
          bf16x4 outv;
          #pragma unroll
          for (int j = 0; j < 4; ++j){
            float v = (float)pre[j] + acc[rt][ct][4*q+j];
            outv[j] = (__bf16)silu_f(v);
          }
          *reinterpret_cast<bf16x4*>(p) = outv;
        }
      }
    }
  }

  // prime P1's B-ring BEFORE the barrier (independent of LDS state)
  const __bf16* Bw1 = we2p + wid*32768 + lane*8;
  bf16x8 bq1[2][2];
  #pragma unroll
  for (int s = 0; s < 2; ++s)
    #pragma unroll
    for (int ct = 0; ct < 2; ++ct)
      bq1[s][ct] = *reinterpret_cast<const bf16x8*>(Bw1 + ct*16384 + s*512);

  __syncthreads();   // eat reads done -> pool is now free for biases

  // stage biases into the pool (read after the next barrier)
  bpool[tid]        = b2[tid];
  bpool[512 + tid]  = bc1[tid];
  bpool[1024 + tid] = wc2[tid];

  // P1: e2 = silu(e1 @ We2^T + b2); e2 -> e1t (vectorized b64 stores).
  // Epilogue writes + AGG both touch ONLY this wave's 64-col strip, so they
  // run before the barrier; the barrier then covers P2's all-strip reads.
  {
    f32x16 acc[2][2];
    #pragma unroll
    for (int rt = 0; rt < 2; ++rt)
      #pragma unroll
      for (int ct = 0; ct < 2; ++ct)
        #pragma unroll
        for (int r = 0; r < 16; ++r) acc[rt][ct][r] = 0.f;
    gemm_phase_sw(e1b, Bw1, c31, hi, acc, bq1);
    __syncthreads();   // all waves done READING e1 (before overwrite); biases visible
    #pragma unroll
    for (int rt = 0; rt < 2; ++rt){
      int edge = rt*32 + c31;
      #pragma unroll
      for (int ct = 0; ct < 2; ++ct){
        #pragma unroll
        for (int q = 0; q < 4; ++q){
          f32x4 b2v = *reinterpret_cast<const f32x4*>(bpool + colbase + ct*32 + 8*q + 4*hi);
          bf16x4 outv;
          #pragma unroll
          for (int j = 0; j < 4; ++j)
            outv[j] = (__bf16)silu_f(acc[rt][ct][4*q+j] + b2v[j]);
          int oc0 = colbase + ct*32 + 8*q + 4*hi;
          *reinterpret_cast<bf16x4*>(e1b + edge*1024 + ((oc0*2) ^ ((edge&15)<<4))) = outv;
        }
      }
    }
  }

  // prime P2's B-ring (covered by AGG below)
  const __bf16* Bw2 = wc1p + wid*32768 + lane*8;
  bf16x8 bq2[2][2];
  #pragma unroll
  for (int s = 0; s < 2; ++s)
    #pragma unroll
    for (int ct = 0; ct < 2; ++ct)
      bq2[s][ct] = *reinterpret_cast<const bf16x8*>(Bw2 + ct*16384 + s*512);

  // AGG: col=tid lies in this wave's own strip -> no barrier needed before
  {
    int col = tid;  // 512 threads == 512 cols
    unsigned long long m = segmask;
    float a = 0.f;
    #pragma unroll
    for (int e = 0; e < TE; ++e){
      if (e > 0 && ((m >> e) & 1)){
        atomicAdd(&agg[(size_t)rl[e-1]*512 + col], a);
        a = 0.f;
      }
      a += (float)*reinterpret_cast<const __bf16*>(e1b + e*1024 + ((col*2) ^ ((e&15)<<4)));
    }
    atomicAdd(&agg[(size_t)rl[TE-1]*512 + col], a);
  }
  __syncthreads();   // all e2 strips written -> P2 may read everything

  // P2: c1 = silu(e2 @ Wc1^T + bc1); cu = c1 . wc2 (lane-local + 1 shuffle)
  {
    f32x16 acc[2][2];
    #pragma unroll
    for (int rt = 0; rt < 2; ++rt)
      #pragma unroll
      for (int ct = 0; ct < 2; ++ct)
        #pragma unroll
        for (int r = 0; r < 16; ++r) acc[rt][ct][r] = 0.f;
    gemm_phase_sw(e1b, Bw2, c31, hi, acc, bq2);
    #pragma unroll
    for (int rt = 0; rt < 2; ++rt){
      float pv = 0.f;
      #pragma unroll
      for (int ct = 0; ct < 2; ++ct){
        #pragma unroll
        for (int q = 0; q < 4; ++q){
          f32x4 bcv = *reinterpret_cast<const f32x4*>(bpool + 512 + colbase + ct*32 + 8*q + 4*hi);
          f32x4 wcv = *reinterpret_cast<const f32x4*>(bpool + 1024 + colbase + ct*32 + 8*q + 4*hi);
          #pragma unroll
          for (int j = 0; j < 4; ++j)
            pv += silu_f(acc[rt][ct][4*q+j] + bcv[j]) * wcv[j];
        }
      }
      pv += __shfl_xor(pv, 32, 64);
      if (hi == 0) cupart[wid][rt*32 + c31] = pv;
    }
  }
  __syncthreads();

  if (tid < TE){
    float cu0 = 0.f;
    #pragma unroll
    for (int w = 0; w < 8; ++w) cu0 += cupart[w][tid];
    float cu = fminf(fmaxf(cu0, -1.f), 1.f);
    if (!isfinite(cu0)) cu = 0.f;
    cuf[tid] = cu;
  }
  __syncthreads();

  // POS: segmented per-axis sum (3 threads), mask-driven, unrolled
  if (tid < 3){
    int d = tid;
    unsigned long long m = segmask;
    float a = 0.f;
    #pragma unroll
    for (int e = 0; e < TE; ++e){
      if (e > 0 && ((m >> e) & 1)){
        atomicAdd(&pos_out[(size_t)rl[e-1]*3 + d], a);
        a = 0.f;
      }
      a += diffs[d][e] * cuf[e];
    }
    atomicAdd(&pos_out[(size_t)rl[TE-1]*3 + d], a);
  }
}

// ------------------------------------------------------------ node MLP ----
__global__ __launch_bounds__(256) void node1_kernel(const float* __restrict__ h,
                                                    const float* __restrict__ agg,
                                                    const __bf16* __restrict__ wn1b,
                                                    const float* __restrict__ bn1,
                                                    __bf16* __restrict__ h1){
  __shared__ __align__(16) __bf16 At[32*1024];  // 64KB, row stride 2048B, swizzled
  int tid = threadIdx.x;
  int r0 = blockIdx.x * 32;
  char* ab = (char*)At;
  for (int it = 0; it < 32; ++it){
    int idx = it*1024 + tid*4;
    int row = idx >> 10, col = idx & 1023;
    float4 v;
    if (col < 512) v = *reinterpret_cast<const float4*>(h   + (size_t)(r0+row)*512 + col);
    else           v = *reinterpret_cast<const float4*>(agg + (size_t)(r0+row)*512 + (col-512));
    bf16x4 p = {(__bf16)v.x, (__bf16)v.y, (__bf16)v.z, (__bf16)v.w};
    *reinterpret_cast<bf16x4*>(ab + row*2048 + ((col*2) ^ ((row&7)<<4))) = p;
  }
  __syncthreads();
  int lane = tid & 63, wid = tid >> 6;
  int col16 = lane & 15, g = lane >> 4;
  int rw = wid & 1, cw = wid >> 1;
  int arow = rw*16 + col16;
  f32x4 acc[8];
  #pragma unroll
  for (int t = 0; t < 8; ++t) acc[t] = f32x4{0.f,0.f,0.f,0.f};
  for (int kk = 0; kk < 32; ++kk){
    bf16x8 af = *reinterpret_cast<const bf16x8*>(ab + arow*2048 + ((kk*64 + g*16) ^ ((arow&7)<<4)));
    #pragma unroll
    for (int t = 0; t < 8; ++t){
      int oc = cw*128 + t*16 + col16;
      bf16x8 bfr = *reinterpret_cast<const bf16x8*>(wn1b + (size_t)oc*1024 + kk*32 + g*8);
      acc[t] = mfma16(af, bfr, acc[t]);
    }
  }
  #pragma unroll
  for (int t = 0; t < 8; ++t){
    int oc = cw*128 + t*16 + col16;
    #pragma unroll
    for (int i2 = 0; i2 < 4; ++i2){
      int row = r0 + rw*16 + g*4 + i2;
      h1[(size_t)row*256 + oc] = (__bf16)silu_f(acc[t][i2] + bn1[oc]);
    }
  }
}

__global__ __launch_bounds__(256) void node2_kernel(const __bf16* __restrict__ h1,
                                                    const __bf16* __restrict__ wn2b,
                                                    const float* __restrict__ bn2,
                                                    float* __restrict__ hout){
  __shared__ __align__(16) __bf16 At[64*256];  // 32KB, row stride 512B, swizzled
  int tid = threadIdx.x;
  int r0 = blockIdx.x * 64;
  char* ab = (char*)At;
  for (int it = 0; it < 8; ++it){
    int idx = it*2048 + tid*8;
    int row = idx >> 8, col = idx & 255;
    bf16x8 v = *reinterpret_cast<const bf16x8*>(h1 + (size_t)(r0+row)*256 + col);
    *reinterpret_cast<bf16x8*>(ab + row*512 + ((col*2) ^ ((row&7)<<4))) = v;
  }
  __syncthreads();
  int lane = tid & 63, wid = tid >> 6;
  int col16 = lane & 15, g = lane >> 4;
  int arow = wid*16 + col16;
  f32x4 acc[16];
  #pragma unroll
  for (int t = 0; t < 16; ++t) acc[t] = f32x4{0.f,0.f,0.f,0.f};
  for (int kk = 0; kk < 8; ++kk){
    bf16x8 af = *reinterpret_cast<const bf16x8*>(ab + arow*512 + ((kk*64 + g*16) ^ ((arow&7)<<4)));
    #pragma unroll
    for (int t = 0; t < 16; ++t){
      int oc = t*16 + col16;
      bf16x8 bfr = *reinterpret_cast<const bf16x8*>(wn2b + (size_t)oc*256 + kk*32 + g*8);
      acc[t] = mfma16(af, bfr, acc[t]);
    }
  }
  #pragma unroll
  for (int t = 0; t < 16; ++t){
    int oc = t*16 + col16;
    #pragma unroll
    for (int i2 = 0; i2 < 4; ++i2){
      int row = r0 + wid*16 + g*4 + i2;
      hout[(size_t)row*256 + oc] = acc[t][i2] + bn2[oc];
    }
  }
}

// -------------------------------------------------------------- launch ----
extern "C" void kernel_launch(void* const* d_in, const int* in_sizes, int n_in,
                              void* d_out, int out_size, void* d_ws, size_t ws_size,
                              hipStream_t stream){
  const float* h   = (const float*)d_in[0];
  const int*   ei  = (const int*)d_in[1];
  const float* ea  = (const float*)d_in[2];
  const float* pos = (const float*)d_in[3];
  const float* We1 = (const float*)d_in[4];
  const float* be1 = (const float*)d_in[5];
  const float* We2 = (const float*)d_in[6];
  const float* be2 = (const float*)d_in[7];
  const float* Wc1 = (const float*)d_in[8];
  const float* bc1 = (const float*)d_in[9];
  const float* Wc2 = (const float*)d_in[10];
  const float* Wn1 = (const float*)d_in[11];
  const float* bn1 = (const float*)d_in[12];
  const float* Wn2 = (const float*)d_in[13];
  const float* bn2 = (const float*)d_in[14];

  char* ws = (char*)d_ws;
  size_t off = 0;
  auto carve = [&](size_t bytes) -> char* {
    char* p = ws + off; off += (bytes + 255) & ~(size_t)255; return p;
  };
  __bf16* wabp  = (__bf16*)carve((size_t)1024*512*2);
  __bf16* weaTp = (__bf16*)carve((size_t)512*64*2);
  __bf16* we2p  = (__bf16*)carve((size_t)512*512*2);
  __bf16* wc1p  = (__bf16*)carve((size_t)512*512*2);
  __bf16* wn1b  = (__bf16*)carve((size_t)256*1024*2);
  __bf16* wn2b  = (__bf16*)carve((size_t)256*256*2);
  __bf16* AB    = (__bf16*)carve((size_t)N_NODES*1024*2);
  float*  agg   = (float*) carve((size_t)N_NODES*512*4);
  __bf16* h1    = (__bf16*)carve((size_t)N_NODES*256*2);
  int*    deg    = (int*) carve((size_t)N_NODES*4);
  int*    basep  = (int*) carve((size_t)N_NODES*4);
  int*    cursor = (int*) carve((size_t)N_NODES*4);
  int*    perm   = (int*) carve((size_t)N_EDGES*4);

  float* hout = (float*)d_out;
  float* pout = (float*)d_out + (size_t)N_NODES*256;

  hipMemsetAsync(agg, 0, (size_t)N_NODES*512*4, stream);
  hipMemsetAsync(deg, 0, (size_t)N_NODES*4, stream);
  hipMemsetAsync(cursor, 0, (size_t)N_NODES*4, stream);
  hipMemcpyAsync((void*)pout, (const void*)pos, (size_t)N_NODES*3*4,
                 hipMemcpyDeviceToDevice, stream);

  prep_kernel<<<2048, 256, 0, stream>>>(We1, be1, We2, Wc1, Wn1, Wn2, ei,
                                        wabp, weaTp, we2p, wc1p, wn1b, wn2b, deg);
  scan_kernel<<<1, 1024, 0, stream>>>(deg, basep);
  scatter_kernel<<<N_EDGES/256, 256, 0, stream>>>(ei, basep, cursor, perm);
  gemm_ab_kernel<<<512, 256, 0, stream>>>(h, wabp, AB);
  edge_kernel<<<N_EDGES/TE, 512, 0, stream>>>(ei, perm, ea, pos, AB, weaTp, we2p, wc1p,
                                              be2, bc1, Wc2, agg, pout);
  node1_kernel<<<N_NODES/32, 256, 0, stream>>>(h, agg, wn1b, bn1, h1);
  node2_kernel<<<N_NODES/64, 256, 0, stream>>>(h1, wn2b, bn2, hout);
}

// Round 18
// 548.619 us; speedup vs baseline: 2.0706x; 1.0623x over previous
//
#include <hip/hip_runtime.h>

#define N_NODES 16384
#define N_EDGES 262144
#define TE 64   // edges per workgroup in edge kernel

typedef __attribute__((ext_vector_type(8))) __bf16 bf16x8;
typedef __attribute__((ext_vector_type(4))) __bf16 bf16x4;
typedef __attribute__((ext_vector_type(4))) float f32x4;
typedef __attribute__((ext_vector_type(16))) float f32x16;

// fast silu: v_rcp_f32 instead of precise-division sequence
__device__ __forceinline__ float silu_f(float x){
  return x * __builtin_amdgcn_rcpf(1.f + __expf(-x));
}

__device__ __forceinline__ f32x4 mfma16(bf16x8 a, bf16x8 b, f32x4 c){
  return __builtin_amdgcn_mfma_f32_16x16x32_bf16(a, b, c, 0, 0, 0);
}
__device__ __forceinline__ f32x16 mfma32(bf16x8 a, bf16x8 b, f32x16 c){
  return __builtin_amdgcn_mfma_f32_32x32x16_bf16(a, b, c, 0, 0, 0);
}

// ------------------------------------------------------ prep (+hist) ----
// ALL GEMM B-operands PACKED into MFMA-fragment order (1 KB contiguous per
// fragment load):
//  wabp [cc8][t8][kk16][lane][8]   weaTp [cb16][kk4][lane][8]
//  we2p/wc1p [cb16][kk32][lane][8]
//  wn1p [cw2][t8][kk32][lane][8]   wn2p [t16][kk8][lane][8]
__global__ void prep_kernel(const float* __restrict__ We1, const float* __restrict__ be1,
                            const float* __restrict__ We2,
                            const float* __restrict__ Wc1, const float* __restrict__ Wn1,
                            const float* __restrict__ Wn2, const int* __restrict__ eidx,
                            __bf16* wabp, __bf16* weaTp, __bf16* we2p, __bf16* wc1p,
                            __bf16* wn1p, __bf16* wn2p, int* __restrict__ deg){
  int i = blockIdx.x * 256 + threadIdx.x;
  if (i < 1024*512){
    int j = i & 7, lane = (i>>3) & 63, kk = (i>>9) & 15, t = (i>>13) & 7, cc = i>>16;
    int o = cc*128 + t*16 + (lane & 15);
    int k = kk*32 + (lane>>4)*8 + j;
    float v = (o < 512) ? We1[(size_t)o*1076 + k] : We1[(size_t)(o-512)*1076 + 512 + k];
    wabp[i] = (__bf16)v;
  }
  if (i < 512*64){
    int j = i & 7, lane = (i>>3) & 63, kk = (i>>9) & 3, cb = i>>11;
    int o = cb*32 + (lane & 31);
    int k = kk*16 + (lane>>5)*8 + j;
    float v = (k < 51) ? We1[(size_t)o*1076 + 1024 + k]
            : (k == 51 ? We1[(size_t)o*1076 + 1075]
            : (k == 52 ? be1[o] : 0.f));
    weaTp[i] = (__bf16)v;
  }
  if (i < 512*512){
    int j = i & 7, lane = (i>>3) & 63, kk = (i>>9) & 31, cb = i>>14;
    int row = cb*32 + (lane & 31);
    int k = kk*16 + (lane>>5)*8 + j;
    we2p[i] = (__bf16)We2[(size_t)row*512 + k];
    wc1p[i] = (__bf16)Wc1[(size_t)row*512 + k];
  }
  if (i < 256*1024){
    int j = i & 7, lane = (i>>3) & 63, kk = (i>>9) & 31, t = (i>>14) & 7, cw = i>>17;
    int o = cw*128 + t*16 + (lane & 15);
    int k = kk*32 + (lane>>4)*8 + j;
    wn1p[i] = (__bf16)Wn1[(size_t)o*1024 + k];
  }
  if (i < 256*256){
    int j = i & 7, lane = (i>>3) & 63, kk = (i>>9) & 7, t = i>>12;
    int o = t*16 + (lane & 15);
    int k = kk*32 + (lane>>4)*8 + j;
    wn2p[i] = (__bf16)Wn2[(size_t)o*256 + k];
  }
  if (i < N_EDGES){ atomicAdd(&deg[eidx[i]], 1); }   // fused hist
}

// ------------------------------------------------- counting sort by row ----
__global__ __launch_bounds__(1024) void scan_kernel(const int* __restrict__ deg,
                                                    int* __restrict__ base){
  __shared__ int part[1024];
  int tid = threadIdx.x;
  int b = tid * 16;
  int local[16];
  int s = 0;
  #pragma unroll
  for (int i = 0; i < 16; ++i){ local[i] = deg[b+i]; s += local[i]; }
  part[tid] = s;
  __syncthreads();
  for (int off = 1; off < 1024; off <<= 1){
    int v = 0;
    if (tid >= off) v = part[tid-off];
    __syncthreads();
    part[tid] += v;
    __syncthreads();
  }
  int run = part[tid] - s;   // exclusive prefix of this chunk
  #pragma unroll
  for (int i = 0; i < 16; ++i){ base[b+i] = run; run += local[i]; }
}

__global__ void scatter_kernel(const int* __restrict__ eidx, const int* __restrict__ base,
                               int* __restrict__ cursor, int* __restrict__ perm){
  int e = blockIdx.x * 256 + threadIdx.x;
  if (e < N_EDGES){
    int r = eidx[e];
    int p = atomicAdd(&cursor[r], 1);
    perm[base[r] + p] = e;
  }
}

// ------------------------------------------------------------- gemm AB ----
__global__ __launch_bounds__(256) void gemm_ab_kernel(const float* __restrict__ h,
                                                      const __bf16* __restrict__ wabp,
                                                      __bf16* __restrict__ AB){
  __shared__ __align__(16) __bf16 At[64*512];  // 64KB, swizzled
  int tid = threadIdx.x;
  int bid = blockIdx.x;
  int r0 = (bid >> 1) * 64;
  int cc0 = (bid & 1) * 4;
  char* ab = (char*)At;
  for (int it = 0; it < 32; ++it){
    int idx = it*1024 + tid*4;
    int row = idx >> 9, col = idx & 511;
    float4 v = *reinterpret_cast<const float4*>(h + (size_t)(r0+row)*512 + col);
    bf16x4 p = {(__bf16)v.x, (__bf16)v.y, (__bf16)v.z, (__bf16)v.w};
    *reinterpret_cast<bf16x4*>(ab + row*1024 + ((col*2) ^ ((row&7)<<4))) = p;
  }
  __syncthreads();
  int lane = tid & 63, wid = tid >> 6;
  int col16 = lane & 15, g = lane >> 4;
  int arow = wid*16 + col16;
  for (int cc = cc0; cc < cc0 + 4; ++cc){
    f32x4 acc[8];
    #pragma unroll
    for (int t = 0; t < 8; ++t) acc[t] = f32x4{0.f,0.f,0.f,0.f};
    for (int kk = 0; kk < 16; ++kk){
      bf16x8 af = *reinterpret_cast<const bf16x8*>(ab + arow*1024 + ((kk*64 + g*16) ^ ((arow&7)<<4)));
      #pragma unroll
      for (int t = 0; t < 8; ++t){
        bf16x8 bfr = *reinterpret_cast<const bf16x8*>(wabp + (size_t)(((cc*8+t)*16+kk)*512) + lane*8);
        acc[t] = mfma16(af, bfr, acc[t]);
      }
    }
    #pragma unroll
    for (int t = 0; t < 8; ++t){
      int oc = cc*128 + t*16 + col16;
      #pragma unroll
      for (int i2 = 0; i2 < 4; ++i2){
        int row = r0 + wid*16 + g*4 + i2;
        AB[(size_t)row*1024 + oc] = (__bf16)acc[t][i2];
      }
    }
  }
}

// --------------------------------------- K=512 phase, SWAPPED operands ----
__device__ __forceinline__ void gemm_phase_sw(const char* e1b, const __bf16* __restrict__ Bw,
                                              int c31, int hi, f32x16 acc[2][2],
                                              bf16x8 bq[2][2]){
  for (int kkb = 0; kkb < 16; ++kkb){
    #pragma unroll
    for (int s = 0; s < 2; ++s){
      int kk = kkb*2 + s;
      bf16x8 af[2];
      #pragma unroll
      for (int rt = 0; rt < 2; ++rt){
        int arow = rt*32 + c31;
        af[rt] = *reinterpret_cast<const bf16x8*>(e1b + arow*1024 + ((kk*32 + hi*16) ^ ((arow&15)<<4)));
      }
      #pragma unroll
      for (int ct = 0; ct < 2; ++ct)
        #pragma unroll
        for (int rt = 0; rt < 2; ++rt)
          acc[rt][ct] = mfma32(bq[s][ct], af[rt], acc[rt][ct]);
      if (kk < 30){
        #pragma unroll
        for (int ct = 0; ct < 2; ++ct)
          bq[s][ct] = *reinterpret_cast<const bf16x8*>(Bw + ct*16384 + (kk+2)*512);
      }
    }
  }
}

// ------------------------------------------------------- fused edge op ----
__global__ __launch_bounds__(512, 4) void edge_kernel(
    const int* __restrict__ eidx, const int* __restrict__ perm,
    const float* __restrict__ edge_attr,
    const float* __restrict__ pos,
    const __bf16* __restrict__ AB, const __bf16* __restrict__ weaTp,
    const __bf16* __restrict__ we2p, const __bf16* __restrict__ wc1p,
    const float* __restrict__ b2,
    const float* __restrict__ bc1, const float* __restrict__ wc2,
    float* __restrict__ agg, float* __restrict__ pos_out)
{
  __shared__ __align__(16) __bf16 e1t[TE*512];   // 64KB, 4-bit swizzle
  __shared__ __align__(16) char pool[8192];
  __shared__ float diffs[3][TE];
  __shared__ float rad[TE];
  __shared__ int   rl[TE], cl[TE], el[TE];
  __shared__ float cupart[8][TE];
  __shared__ float cuf[TE];
  __shared__ unsigned long long segmask;

  int tid = threadIdx.x;
  int e0 = blockIdx.x * TE;

  if (tid < TE){
    int eid = perm[e0 + tid];
    el[tid] = eid;
    int r = eidx[eid], c = eidx[N_EDGES + eid];
    rl[tid] = r; cl[tid] = c;
    float dx = pos[r*3+0]-pos[c*3+0];
    float dy = pos[r*3+1]-pos[c*3+1];
    float dz = pos[r*3+2]-pos[c*3+2];
    diffs[0][tid]=dx; diffs[1][tid]=dy; diffs[2][tid]=dz;
    float rr = dx*dx + dy*dy + dz*dz;
    rad[tid] = fminf(fmaxf(rr, 1e-8f), 100.f);
  }
  __syncthreads();

  if (tid < 64){
    unsigned long long m = __ballot(tid > 0 && rl[tid] != rl[tid-1]);
    if (tid == 0) segmask = m;
  }

  // stage edge_attr (+radial k=51, one k=52, zero pad) swizzled bf16 [TE][64]
  {
    char* eb = pool;
    for (int i = tid; i < TE*64; i += 512){
      int e = i >> 6, k = i & 63;
      float v = (k < 51) ? edge_attr[(size_t)el[e]*51 + k]
              : (k == 51 ? rad[e] : (k == 52 ? 1.0f : 0.f));
      *reinterpret_cast<__bf16*>(eb + e*128 + ((k*2) ^ ((e&7)<<4))) = (__bf16)v;
    }
  }
  // prefill e1t with gather-sum (bf16, 4-bit swizzle); bias via weaT k=52
  {
    int e = tid >> 3, q = tid & 7;
    size_t baseR = (size_t)rl[e]*1024;
    size_t baseC = (size_t)cl[e]*1024 + 512;
    char* eb = (char*)e1t;
    #pragma unroll
    for (int c = 0; c < 8; ++c){
      int o0 = q*8 + c*64;
      bf16x8 ga = *reinterpret_cast<const bf16x8*>(AB + baseR + o0);
      bf16x8 gb = *reinterpret_cast<const bf16x8*>(AB + baseC + o0);
      bf16x8 outv;
      #pragma unroll
      for (int j = 0; j < 8; ++j) outv[j] = (__bf16)((float)ga[j] + (float)gb[j]);
      *reinterpret_cast<bf16x8*>(eb + e*1024 + ((o0*2) ^ ((e&15)<<4))) = outv;
    }
  }
  __syncthreads();

  int lane = tid & 63, wid = tid >> 6;
  int c31 = lane & 31, hi = lane >> 5;
  int colbase = wid * 64;
  char* e1b = (char*)e1t;
  float* bpool = (float*)pool;

  // P0: e1 = silu(prefill + ea@Wea^T)
  {
    f32x16 acc[2][2];
    #pragma unroll
    for (int rt = 0; rt < 2; ++rt)
      #pragma unroll
      for (int ct = 0; ct < 2; ++ct)
        #pragma unroll
        for (int r = 0; r < 16; ++r) acc[rt][ct][r] = 0.f;
    const char* eb = pool;
    #pragma unroll
    for (int kk = 0; kk < 4; ++kk){
      bf16x8 af[2];
      #pragma unroll
      for (int rt = 0; rt < 2; ++rt){
        int arow = rt*32 + c31;
        af[rt] = *reinterpret_cast<const bf16x8*>(eb + arow*128 + ((kk*32 + hi*16) ^ ((arow&7)<<4)));
      }
      #pragma unroll
      for (int ct = 0; ct < 2; ++ct){
        bf16x8 bfr = *reinterpret_cast<const bf16x8*>(weaTp + (wid*2+ct)*2048 + kk*512 + lane*8);
        #pragma unroll
        for (int rt = 0; rt < 2; ++rt) acc[rt][ct] = mfma32(bfr, af[rt], acc[rt][ct]);
      }
    }
    #pragma unroll
    for (int rt = 0; rt < 2; ++rt){
      int edge = rt*32 + c31;
      #pragma unroll
      for (int ct = 0; ct < 2; ++ct){
        #pragma unroll
        for (int q = 0; q < 4; ++q){
          int oc0 = colbase + ct*32 + 8*q + 4*hi;
          char* p = e1b + edge*1024 + ((oc0*2) ^ ((edge&15)<<4));
          bf16x4 pre = *reinterpret_cast<const bf16x4*>(p);
          bf16x4 outv;
          #pragma unroll
          for (int j = 0; j < 4; ++j){
            float v = (float)pre[j] + acc[rt][ct][4*q+j];
            outv[j] = (__bf16)silu_f(v);
          }
          *reinterpret_cast<bf16x4*>(p) = outv;
        }
      }
    }
  }

  // prime P1's B-ring BEFORE the barrier
  const __bf16* Bw1 = we2p + wid*32768 + lane*8;
  bf16x8 bq1[2][2];
  #pragma unroll
  for (int s = 0; s < 2; ++s)
    #pragma unroll
    for (int ct = 0; ct < 2; ++ct)
      bq1[s][ct] = *reinterpret_cast<const bf16x8*>(Bw1 + ct*16384 + s*512);

  __syncthreads();   // ea reads done -> pool free for biases

  bpool[tid]        = b2[tid];
  bpool[512 + tid]  = bc1[tid];
  bpool[1024 + tid] = wc2[tid];

  // P1: e2 = silu(e1 @ We2^T + b2)
  {
    f32x16 acc[2][2];
    #pragma unroll
    for (int rt = 0; rt < 2; ++rt)
      #pragma unroll
      for (int ct = 0; ct < 2; ++ct)
        #pragma unroll
        for (int r = 0; r < 16; ++r) acc[rt][ct][r] = 0.f;
    gemm_phase_sw(e1b, Bw1, c31, hi, acc, bq1);
    __syncthreads();   // all waves done reading e1; biases visible
    #pragma unroll
    for (int rt = 0; rt < 2; ++rt){
      int edge = rt*32 + c31;
      #pragma unroll
      for (int ct = 0; ct < 2; ++ct){
        #pragma unroll
        for (int q = 0; q < 4; ++q){
          f32x4 b2v = *reinterpret_cast<const f32x4*>(bpool + colbase + ct*32 + 8*q + 4*hi);
          bf16x4 outv;
          #pragma unroll
          for (int j = 0; j < 4; ++j)
            outv[j] = (__bf16)silu_f(acc[rt][ct][4*q+j] + b2v[j]);
          int oc0 = colbase + ct*32 + 8*q + 4*hi;
          *reinterpret_cast<bf16x4*>(e1b + edge*1024 + ((oc0*2) ^ ((edge&15)<<4))) = outv;
        }
      }
    }
  }

  // prime P2's B-ring (covered by AGG below)
  const __bf16* Bw2 = wc1p + wid*32768 + lane*8;
  bf16x8 bq2[2][2];
  #pragma unroll
  for (int s = 0; s < 2; ++s)
    #pragma unroll
    for (int ct = 0; ct < 2; ++ct)
      bq2[s][ct] = *reinterpret_cast<const bf16x8*>(Bw2 + ct*16384 + s*512);

  // AGG: col=tid lies in this wave's own just-written strip
  {
    int col = tid;
    unsigned long long m = segmask;
    float a = 0.f;
    #pragma unroll
    for (int e = 0; e < TE; ++e){
      if (e > 0 && ((m >> e) & 1)){
        atomicAdd(&agg[(size_t)rl[e-1]*512 + col], a);
        a = 0.f;
      }
      a += (float)*reinterpret_cast<const __bf16*>(e1b + e*1024 + ((col*2) ^ ((e&15)<<4)));
    }
    atomicAdd(&agg[(size_t)rl[TE-1]*512 + col], a);
  }
  __syncthreads();   // all e2 strips written -> P2 reads everything

  // P2: c1 = silu(e2 @ Wc1^T + bc1); cu = c1 . wc2
  {
    f32x16 acc[2][2];
    #pragma unroll
    for (int rt = 0; rt < 2; ++rt)
      #pragma unroll
      for (int ct = 0; ct < 2; ++ct)
        #pragma unroll
        for (int r = 0; r < 16; ++r) acc[rt][ct][r] = 0.f;
    gemm_phase_sw(e1b, Bw2, c31, hi, acc, bq2);
    #pragma unroll
    for (int rt = 0; rt < 2; ++rt){
      float pv = 0.f;
      #pragma unroll
      for (int ct = 0; ct < 2; ++ct){
        #pragma unroll
        for (int q = 0; q < 4; ++q){
          f32x4 bcv = *reinterpret_cast<const f32x4*>(bpool + 512 + colbase + ct*32 + 8*q + 4*hi);
          f32x4 wcv = *reinterpret_cast<const f32x4*>(bpool + 1024 + colbase + ct*32 + 8*q + 4*hi);
          #pragma unroll
          for (int j = 0; j < 4; ++j)
            pv += silu_f(acc[rt][ct][4*q+j] + bcv[j]) * wcv[j];
        }
      }
      pv += __shfl_xor(pv, 32, 64);
      if (hi == 0) cupart[wid][rt*32 + c31] = pv;
    }
  }
  __syncthreads();

  if (tid < TE){
    float cu0 = 0.f;
    #pragma unroll
    for (int w = 0; w < 8; ++w) cu0 += cupart[w][tid];
    float cu = fminf(fmaxf(cu0, -1.f), 1.f);
    if (!isfinite(cu0)) cu = 0.f;
    cuf[tid] = cu;
  }
  __syncthreads();

  if (tid < 3){
    int d = tid;
    unsigned long long m = segmask;
    float a = 0.f;
    #pragma unroll
    for (int e = 0; e < TE; ++e){
      if (e > 0 && ((m >> e) & 1)){
        atomicAdd(&pos_out[(size_t)rl[e-1]*3 + d], a);
        a = 0.f;
      }
      a += diffs[d][e] * cuf[e];
    }
    atomicAdd(&pos_out[(size_t)rl[TE-1]*3 + d], a);
  }
}

// ------------------------------------------------------------ node MLP ----
__global__ __launch_bounds__(256) void node1_kernel(const float* __restrict__ h,
                                                    const float* __restrict__ agg,
                                                    const __bf16* __restrict__ wn1p,
                                                    const float* __restrict__ bn1,
                                                    __bf16* __restrict__ h1){
  __shared__ __align__(16) __bf16 At[32*1024];  // 64KB, row stride 2048B, swizzled
  int tid = threadIdx.x;
  int r0 = blockIdx.x * 32;
  char* ab = (char*)At;
  for (int it = 0; it < 32; ++it){
    int idx = it*1024 + tid*4;
    int row = idx >> 10, col = idx & 1023;
    float4 v;
    if (col < 512) v = *reinterpret_cast<const float4*>(h   + (size_t)(r0+row)*512 + col);
    else           v = *reinterpret_cast<const float4*>(agg + (size_t)(r0+row)*512 + (col-512));
    bf16x4 p = {(__bf16)v.x, (__bf16)v.y, (__bf16)v.z, (__bf16)v.w};
    *reinterpret_cast<bf16x4*>(ab + row*2048 + ((col*2) ^ ((row&7)<<4))) = p;
  }
  __syncthreads();
  int lane = tid & 63, wid = tid >> 6;
  int col16 = lane & 15, g = lane >> 4;
  int rw = wid & 1, cw = wid >> 1;
  int arow = rw*16 + col16;
  f32x4 acc[8];
  #pragma unroll
  for (int t = 0; t < 8; ++t) acc[t] = f32x4{0.f,0.f,0.f,0.f};
  for (int kk = 0; kk < 32; ++kk){
    bf16x8 af = *reinterpret_cast<const bf16x8*>(ab + arow*2048 + ((kk*64 + g*16) ^ ((arow&7)<<4)));
    #pragma unroll
    for (int t = 0; t < 8; ++t){
      bf16x8 bfr = *reinterpret_cast<const bf16x8*>(wn1p + (size_t)(((cw*8+t)*32+kk)*512) + lane*8);
      acc[t] = mfma16(af, bfr, acc[t]);
    }
  }
  #pragma unroll
  for (int t = 0; t < 8; ++t){
    int oc = cw*128 + t*16 + col16;
    #pragma unroll
    for (int i2 = 0; i2 < 4; ++i2){
      int row = r0 + rw*16 + g*4 + i2;
      h1[(size_t)row*256 + oc] = (__bf16)silu_f(acc[t][i2] + bn1[oc]);
    }
  }
}

__global__ __launch_bounds__(256) void node2_kernel(const __bf16* __restrict__ h1,
                                                    const __bf16* __restrict__ wn2p,
                                                    const float* __restrict__ bn2,
                                                    float* __restrict__ hout){
  __shared__ __align__(16) __bf16 At[64*256];  // 32KB, row stride 512B, swizzled
  int tid = threadIdx.x;
  int r0 = blockIdx.x * 64;
  char* ab = (char*)At;
  for (int it = 0; it < 8; ++it){
    int idx = it*2048 + tid*8;
    int row = idx >> 8, col = idx & 255;
    bf16x8 v = *reinterpret_cast<const bf16x8*>(h1 + (size_t)(r0+row)*256 + col);
    *reinterpret_cast<bf16x8*>(ab + row*512 + ((col*2) ^ ((row&7)<<4))) = v;
  }
  __syncthreads();
  int lane = tid & 63, wid = tid >> 6;
  int col16 = lane & 15, g = lane >> 4;
  int arow = wid*16 + col16;
  f32x4 acc[16];
  #pragma unroll
  for (int t = 0; t < 16; ++t) acc[t] = f32x4{0.f,0.f,0.f,0.f};
  for (int kk = 0; kk < 8; ++kk){
    bf16x8 af = *reinterpret_cast<const bf16x8*>(ab + arow*512 + ((kk*64 + g*16) ^ ((arow&7)<<4)));
    #pragma unroll
    for (int t = 0; t < 16; ++t){
      bf16x8 bfr = *reinterpret_cast<const bf16x8*>(wn2p + (size_t)((t*8+kk)*512) + lane*8);
      acc[t] = mfma16(af, bfr, acc[t]);
    }
  }
  #pragma unroll
  for (int t = 0; t < 16; ++t){
    int oc = t*16 + col16;
    #pragma unroll
    for (int i2 = 0; i2 < 4; ++i2){
      int row = r0 + wid*16 + g*4 + i2;
      hout[(size_t)row*256 + oc] = acc[t][i2] + bn2[oc];
    }
  }
}

// -------------------------------------------------------------- launch ----
extern "C" void kernel_launch(void* const* d_in, const int* in_sizes, int n_in,
                              void* d_out, int out_size, void* d_ws, size_t ws_size,
                              hipStream_t stream){
  const float* h   = (const float*)d_in[0];
  const int*   ei  = (const int*)d_in[1];
  const float* ea  = (const float*)d_in[2];
  const float* pos = (const float*)d_in[3];
  const float* We1 = (const float*)d_in[4];
  const float* be1 = (const float*)d_in[5];
  const float* We2 = (const float*)d_in[6];
  const float* be2 = (const float*)d_in[7];
  const float* Wc1 = (const float*)d_in[8];
  const float* bc1 = (const float*)d_in[9];
  const float* Wc2 = (const float*)d_in[10];
  const float* Wn1 = (const float*)d_in[11];
  const float* bn1 = (const float*)d_in[12];
  const float* Wn2 = (const float*)d_in[13];
  const float* bn2 = (const float*)d_in[14];

  char* ws = (char*)d_ws;
  size_t off = 0;
  auto carve = [&](size_t bytes) -> char* {
    char* p = ws + off; off += (bytes + 255) & ~(size_t)255; return p;
  };
  __bf16* wabp  = (__bf16*)carve((size_t)1024*512*2);
  __bf16* weaTp = (__bf16*)carve((size_t)512*64*2);
  __bf16* we2p  = (__bf16*)carve((size_t)512*512*2);
  __bf16* wc1p  = (__bf16*)carve((size_t)512*512*2);
  __bf16* wn1p  = (__bf16*)carve((size_t)256*1024*2);
  __bf16* wn2p  = (__bf16*)carve((size_t)256*256*2);
  __bf16* AB    = (__bf16*)carve((size_t)N_NODES*1024*2);
  float*  agg   = (float*) carve((size_t)N_NODES*512*4);
  __bf16* h1    = (__bf16*)carve((size_t)N_NODES*256*2);
  int*    deg    = (int*) carve((size_t)N_NODES*4);
  int*    basep  = (int*) carve((size_t)N_NODES*4);
  int*    cursor = (int*) carve((size_t)N_NODES*4);
  int*    perm   = (int*) carve((size_t)N_EDGES*4);

  float* hout = (float*)d_out;
  float* pout = (float*)d_out + (size_t)N_NODES*256;

  hipMemsetAsync(agg, 0, (size_t)N_NODES*512*4, stream);
  hipMemsetAsync(deg, 0, (size_t)N_NODES*4, stream);
  hipMemsetAsync(cursor, 0, (size_t)N_NODES*4, stream);
  hipMemcpyAsync((void*)pout, (const void*)pos, (size_t)N_NODES*3*4,
                 hipMemcpyDeviceToDevice, stream);

  prep_kernel<<<2048, 256, 0, stream>>>(We1, be1, We2, Wc1, Wn1, Wn2, ei,
                                        wabp, weaTp, we2p, wc1p, wn1p, wn2p, deg);
  scan_kernel<<<1, 1024, 0, stream>>>(deg, basep);
  scatter_kernel<<<N_EDGES/256, 256, 0, stream>>>(ei, basep, cursor, perm);
  gemm_ab_kernel<<<512, 256, 0, stream>>>(h, wabp, AB);
  edge_kernel<<<N_EDGES/TE, 512, 0, stream>>>(ei, perm, ea, pos, AB, weaTp, we2p, wc1p,
                                              be2, bc1, Wc2, agg, pout);
  node1_kernel<<<N_NODES/32, 256, 0, stream>>>(h, agg, wn1p, bn1, h1);
  node2_kernel<<<N_NODES/64, 256, 0, stream>>>(h1, wn2p, bn2, hout);
}

// Round 19
// 519.116 us; speedup vs baseline: 2.1882x; 1.0568x over previous
//
#include <hip/hip_runtime.h>

#define N_NODES 16384
#define N_EDGES 262144
#define TE 64   // edges per workgroup in edge kernel

typedef __attribute__((ext_vector_type(8))) __bf16 bf16x8;
typedef __attribute__((ext_vector_type(4))) __bf16 bf16x4;
typedef __attribute__((ext_vector_type(4))) float f32x4;
typedef __attribute__((ext_vector_type(16))) float f32x16;

// fast silu: v_rcp_f32 instead of precise-division sequence
__device__ __forceinline__ float silu_f(float x){
  return x * __builtin_amdgcn_rcpf(1.f + __expf(-x));
}

__device__ __forceinline__ f32x4 mfma16(bf16x8 a, bf16x8 b, f32x4 c){
  return __builtin_amdgcn_mfma_f32_16x16x32_bf16(a, b, c, 0, 0, 0);
}
__device__ __forceinline__ f32x16 mfma32(bf16x8 a, bf16x8 b, f32x16 c){
  return __builtin_amdgcn_mfma_f32_32x32x16_bf16(a, b, c, 0, 0, 0);
}

// ------------------------------------------------------ prep (+hist) ----
// ALL GEMM B-operands PACKED into MFMA-fragment order (1 KB contiguous per
// fragment load):
//  wabp [cc8][t8][kk16][lane][8]   weaTp [cb16][kk4][lane][8]
//  we2p/wc1p [cb16][kk32][lane][8]
//  wn1p [cw2][t8][kk32][lane][8]   wn2p [t16][kk8][lane][8]
__global__ void prep_kernel(const float* __restrict__ We1, const float* __restrict__ be1,
                            const float* __restrict__ We2,
                            const float* __restrict__ Wc1, const float* __restrict__ Wn1,
                            const float* __restrict__ Wn2, const int* __restrict__ eidx,
                            __bf16* wabp, __bf16* weaTp, __bf16* we2p, __bf16* wc1p,
                            __bf16* wn1p, __bf16* wn2p, int* __restrict__ deg){
  int i = blockIdx.x * 256 + threadIdx.x;
  if (i < 1024*512){
    int j = i & 7, lane = (i>>3) & 63, kk = (i>>9) & 15, t = (i>>13) & 7, cc = i>>16;
    int o = cc*128 + t*16 + (lane & 15);
    int k = kk*32 + (lane>>4)*8 + j;
    float v = (o < 512) ? We1[(size_t)o*1076 + k] : We1[(size_t)(o-512)*1076 + 512 + k];
    wabp[i] = (__bf16)v;
  }
  if (i < 512*64){
    int j = i & 7, lane = (i>>3) & 63, kk = (i>>9) & 3, cb = i>>11;
    int o = cb*32 + (lane & 31);
    int k = kk*16 + (lane>>5)*8 + j;
    float v = (k < 51) ? We1[(size_t)o*1076 + 1024 + k]
            : (k == 51 ? We1[(size_t)o*1076 + 1075]
            : (k == 52 ? be1[o] : 0.f));
    weaTp[i] = (__bf16)v;
  }
  if (i < 512*512){
    int j = i & 7, lane = (i>>3) & 63, kk = (i>>9) & 31, cb = i>>14;
    int row = cb*32 + (lane & 31);
    int k = kk*16 + (lane>>5)*8 + j;
    we2p[i] = (__bf16)We2[(size_t)row*512 + k];
    wc1p[i] = (__bf16)Wc1[(size_t)row*512 + k];
  }
  if (i < 256*1024){
    int j = i & 7, lane = (i>>3) & 63, kk = (i>>9) & 31, t = (i>>14) & 7, cw = i>>17;
    int o = cw*128 + t*16 + (lane & 15);
    int k = kk*32 + (lane>>4)*8 + j;
    wn1p[i] = (__bf16)Wn1[(size_t)o*1024 + k];
  }
  if (i < 256*256){
    int j = i & 7, lane = (i>>3) & 63, kk = (i>>9) & 7, t = i>>12;
    int o = t*16 + (lane & 15);
    int k = kk*32 + (lane>>4)*8 + j;
    wn2p[i] = (__bf16)Wn2[(size_t)o*256 + k];
  }
  if (i < N_EDGES){ atomicAdd(&deg[eidx[i]], 1); }   // fused hist
}

// ------------------------------------------------- counting sort by row ----
__global__ __launch_bounds__(1024) void scan_kernel(const int* __restrict__ deg,
                                                    int* __restrict__ base){
  __shared__ int part[1024];
  int tid = threadIdx.x;
  int b = tid * 16;
  int local[16];
  int s = 0;
  #pragma unroll
  for (int i = 0; i < 16; ++i){ local[i] = deg[b+i]; s += local[i]; }
  part[tid] = s;
  __syncthreads();
  for (int off = 1; off < 1024; off <<= 1){
    int v = 0;
    if (tid >= off) v = part[tid-off];
    __syncthreads();
    part[tid] += v;
    __syncthreads();
  }
  int run = part[tid] - s;   // exclusive prefix of this chunk
  #pragma unroll
  for (int i = 0; i < 16; ++i){ base[b+i] = run; run += local[i]; }
}

__global__ void scatter_kernel(const int* __restrict__ eidx, const int* __restrict__ base,
                               int* __restrict__ cursor, int* __restrict__ perm){
  int e = blockIdx.x * 256 + threadIdx.x;
  if (e < N_EDGES){
    int r = eidx[e];
    int p = atomicAdd(&cursor[r], 1);
    perm[base[r] + p] = e;
  }
}

// ------------------------------------------------------------- gemm AB ----
__global__ __launch_bounds__(256) void gemm_ab_kernel(const float* __restrict__ h,
                                                      const __bf16* __restrict__ wabp,
                                                      __bf16* __restrict__ AB){
  __shared__ __align__(16) __bf16 At[64*512];  // 64KB, swizzled
  int tid = threadIdx.x;
  int bid = blockIdx.x;
  int r0 = (bid >> 1) * 64;
  int cc0 = (bid & 1) * 4;
  char* ab = (char*)At;
  for (int it = 0; it < 32; ++it){
    int idx = it*1024 + tid*4;
    int row = idx >> 9, col = idx & 511;
    float4 v = *reinterpret_cast<const float4*>(h + (size_t)(r0+row)*512 + col);
    bf16x4 p = {(__bf16)v.x, (__bf16)v.y, (__bf16)v.z, (__bf16)v.w};
    *reinterpret_cast<bf16x4*>(ab + row*1024 + ((col*2) ^ ((row&7)<<4))) = p;
  }
  __syncthreads();
  int lane = tid & 63, wid = tid >> 6;
  int col16 = lane & 15, g = lane >> 4;
  int arow = wid*16 + col16;
  for (int cc = cc0; cc < cc0 + 4; ++cc){
    f32x4 acc[8];
    #pragma unroll
    for (int t = 0; t < 8; ++t) acc[t] = f32x4{0.f,0.f,0.f,0.f};
    for (int kk = 0; kk < 16; ++kk){
      bf16x8 af = *reinterpret_cast<const bf16x8*>(ab + arow*1024 + ((kk*64 + g*16) ^ ((arow&7)<<4)));
      #pragma unroll
      for (int t = 0; t < 8; ++t){
        bf16x8 bfr = *reinterpret_cast<const bf16x8*>(wabp + (size_t)(((cc*8+t)*16+kk)*512) + lane*8);
        acc[t] = mfma16(af, bfr, acc[t]);
      }
    }
    #pragma unroll
    for (int t = 0; t < 8; ++t){
      int oc = cc*128 + t*16 + col16;
      #pragma unroll
      for (int i2 = 0; i2 < 4; ++i2){
        int row = r0 + wid*16 + g*4 + i2;
        AB[(size_t)row*1024 + oc] = (__bf16)acc[t][i2];
      }
    }
  }
}

// --------------------------------------- K=512 phase, SWAPPED operands ----
__device__ __forceinline__ void gemm_phase_sw(const char* e1b, const __bf16* __restrict__ Bw,
                                              int c31, int hi, f32x16 acc[2][2],
                                              bf16x8 bq[2][2]){
  for (int kkb = 0; kkb < 16; ++kkb){
    #pragma unroll
    for (int s = 0; s < 2; ++s){
      int kk = kkb*2 + s;
      bf16x8 af[2];
      #pragma unroll
      for (int rt = 0; rt < 2; ++rt){
        int arow = rt*32 + c31;
        af[rt] = *reinterpret_cast<const bf16x8*>(e1b + arow*1024 + ((kk*32 + hi*16) ^ ((arow&15)<<4)));
      }
      #pragma unroll
      for (int ct = 0; ct < 2; ++ct)
        #pragma unroll
        for (int rt = 0; rt < 2; ++rt)
          acc[rt][ct] = mfma32(bq[s][ct], af[rt], acc[rt][ct]);
      if (kk < 30){
        #pragma unroll
        for (int ct = 0; ct < 2; ++ct)
          bq[s][ct] = *reinterpret_cast<const bf16x8*>(Bw + ct*16384 + (kk+2)*512);
      }
    }
  }
}

// ------------------------------------------------------- fused edge op ----
__global__ __launch_bounds__(512, 4) void edge_kernel(
    const int* __restrict__ eidx, const int* __restrict__ perm,
    const float* __restrict__ edge_attr,
    const float* __restrict__ pos,
    const __bf16* __restrict__ AB, const __bf16* __restrict__ weaTp,
    const __bf16* __restrict__ we2p, const __bf16* __restrict__ wc1p,
    const float* __restrict__ b2,
    const float* __restrict__ bc1, const float* __restrict__ wc2,
    float* __restrict__ agg, float* __restrict__ pos_out)
{
  __shared__ __align__(16) __bf16 e1t[TE*512];   // 64KB, 4-bit swizzle
  __shared__ __align__(16) char pool[8192];
  __shared__ float diffs[3][TE];
  __shared__ float rad[TE];
  __shared__ int   rl[TE], cl[TE], el[TE];
  __shared__ float cupart[8][TE];
  __shared__ float cuf[TE];
  __shared__ unsigned long long segmask;

  int tid = threadIdx.x;
  int e0 = blockIdx.x * TE;

  if (tid < TE){
    int eid = perm[e0 + tid];
    el[tid] = eid;
    int r = eidx[eid], c = eidx[N_EDGES + eid];
    rl[tid] = r; cl[tid] = c;
    float dx = pos[r*3+0]-pos[c*3+0];
    float dy = pos[r*3+1]-pos[c*3+1];
    float dz = pos[r*3+2]-pos[c*3+2];
    diffs[0][tid]=dx; diffs[1][tid]=dy; diffs[2][tid]=dz;
    float rr = dx*dx + dy*dy + dz*dz;
    rad[tid] = fminf(fmaxf(rr, 1e-8f), 100.f);
  }
  __syncthreads();

  if (tid < 64){
    unsigned long long m = __ballot(tid > 0 && rl[tid] != rl[tid-1]);
    if (tid == 0) segmask = m;
  }

  // stage edge_attr (+radial k=51, one k=52, zero pad) swizzled bf16 [TE][64]
  {
    char* eb = pool;
    for (int i = tid; i < TE*64; i += 512){
      int e = i >> 6, k = i & 63;
      float v = (k < 51) ? edge_attr[(size_t)el[e]*51 + k]
              : (k == 51 ? rad[e] : (k == 52 ? 1.0f : 0.f));
      *reinterpret_cast<__bf16*>(eb + e*128 + ((k*2) ^ ((e&7)<<4))) = (__bf16)v;
    }
  }
  // prefill e1t with gather-sum (bf16, 4-bit swizzle); bias via weaT k=52
  {
    int e = tid >> 3, q = tid & 7;
    size_t baseR = (size_t)rl[e]*1024;
    size_t baseC = (size_t)cl[e]*1024 + 512;
    char* eb = (char*)e1t;
    #pragma unroll
    for (int c = 0; c < 8; ++c){
      int o0 = q*8 + c*64;
      bf16x8 ga = *reinterpret_cast<const bf16x8*>(AB + baseR + o0);
      bf16x8 gb = *reinterpret_cast<const bf16x8*>(AB + baseC + o0);
      bf16x8 outv;
      #pragma unroll
      for (int j = 0; j < 8; ++j) outv[j] = (__bf16)((float)ga[j] + (float)gb[j]);
      *reinterpret_cast<bf16x8*>(eb + e*1024 + ((o0*2) ^ ((e&15)<<4))) = outv;
    }
  }
  __syncthreads();

  int lane = tid & 63, wid = tid >> 6;
  int c31 = lane & 31, hi = lane >> 5;
  int colbase = wid * 64;
  char* e1b = (char*)e1t;
  float* bpool = (float*)pool;

  // P0: e1 = silu(prefill + ea@Wea^T)
  {
    f32x16 acc[2][2];
    #pragma unroll
    for (int rt = 0; rt < 2; ++rt)
      #pragma unroll
      for (int ct = 0; ct < 2; ++ct)
        #pragma unroll
        for (int r = 0; r < 16; ++r) acc[rt][ct][r] = 0.f;
    const char* eb = pool;
    #pragma unroll
    for (int kk = 0; kk < 4; ++kk){
      bf16x8 af[2];
      #pragma unroll
      for (int rt = 0; rt < 2; ++rt){
        int arow = rt*32 + c31;
        af[rt] = *reinterpret_cast<const bf16x8*>(eb + arow*128 + ((kk*32 + hi*16) ^ ((arow&7)<<4)));
      }
      #pragma unroll
      for (int ct = 0; ct < 2; ++ct){
        bf16x8 bfr = *reinterpret_cast<const bf16x8*>(weaTp + (wid*2+ct)*2048 + kk*512 + lane*8);
        #pragma unroll
        for (int rt = 0; rt < 2; ++rt) acc[rt][ct] = mfma32(bfr, af[rt], acc[rt][ct]);
      }
    }
    #pragma unroll
    for (int rt = 0; rt < 2; ++rt){
      int edge = rt*32 + c31;
      #pragma unroll
      for (int ct = 0; ct < 2; ++ct){
        #pragma unroll
        for (int q = 0; q < 4; ++q){
          int oc0 = colbase + ct*32 + 8*q + 4*hi;
          char* p = e1b + edge*1024 + ((oc0*2) ^ ((edge&15)<<4));
          bf16x4 pre = *reinterpret_cast<const bf16x4*>(p);
          bf16x4 outv;
          #pragma unroll
          for (int j = 0; j < 4; ++j){
            float v = (float)pre[j] + acc[rt][ct][4*q+j];
            outv[j] = (__bf16)silu_f(v);
          }
          *reinterpret_cast<bf16x4*>(p) = outv;
        }
      }
    }
  }

  // prime P1's B-ring BEFORE the barrier
  const __bf16* Bw1 = we2p + wid*32768 + lane*8;
  bf16x8 bq1[2][2];
  #pragma unroll
  for (int s = 0; s < 2; ++s)
    #pragma unroll
    for (int ct = 0; ct < 2; ++ct)
      bq1[s][ct] = *reinterpret_cast<const bf16x8*>(Bw1 + ct*16384 + s*512);

  __syncthreads();   // ea reads done -> pool free for biases

  bpool[tid]        = b2[tid];
  bpool[512 + tid]  = bc1[tid];
  bpool[1024 + tid] = wc2[tid];

  // P1: e2 = silu(e1 @ We2^T + b2)
  {
    f32x16 acc[2][2];
    #pragma unroll
    for (int rt = 0; rt < 2; ++rt)
      #pragma unroll
      for (int ct = 0; ct < 2; ++ct)
        #pragma unroll
        for (int r = 0; r < 16; ++r) acc[rt][ct][r] = 0.f;
    gemm_phase_sw(e1b, Bw1, c31, hi, acc, bq1);
    __syncthreads();   // all waves done reading e1; biases visible
    #pragma unroll
    for (int rt = 0; rt < 2; ++rt){
      int edge = rt*32 + c31;
      #pragma unroll
      for (int ct = 0; ct < 2; ++ct){
        #pragma unroll
        for (int q = 0; q < 4; ++q){
          f32x4 b2v = *reinterpret_cast<const f32x4*>(bpool + colbase + ct*32 + 8*q + 4*hi);
          bf16x4 outv;
          #pragma unroll
          for (int j = 0; j < 4; ++j)
            outv[j] = (__bf16)silu_f(acc[rt][ct][4*q+j] + b2v[j]);
          int oc0 = colbase + ct*32 + 8*q + 4*hi;
          *reinterpret_cast<bf16x4*>(e1b + edge*1024 + ((oc0*2) ^ ((edge&15)<<4))) = outv;
        }
      }
    }
  }

  // prime P2's B-ring (covered by AGG below)
  const __bf16* Bw2 = wc1p + wid*32768 + lane*8;
  bf16x8 bq2[2][2];
  #pragma unroll
  for (int s = 0; s < 2; ++s)
    #pragma unroll
    for (int ct = 0; ct < 2; ++ct)
      bq2[s][ct] = *reinterpret_cast<const bf16x8*>(Bw2 + ct*16384 + s*512);

  // AGG: col=tid lies in this wave's own just-written strip
  {
    int col = tid;
    unsigned long long m = segmask;
    float a = 0.f;
    #pragma unroll
    for (int e = 0; e < TE; ++e){
      if (e > 0 && ((m >> e) & 1)){
        atomicAdd(&agg[(size_t)rl[e-1]*512 + col], a);
        a = 0.f;
      }
      a += (float)*reinterpret_cast<const __bf16*>(e1b + e*1024 + ((col*2) ^ ((e&15)<<4)));
    }
    atomicAdd(&agg[(size_t)rl[TE-1]*512 + col], a);
  }
  __syncthreads();   // all e2 strips written -> P2 reads everything

  // P2: c1 = silu(e2 @ Wc1^T + bc1); cu = c1 . wc2
  {
    f32x16 acc[2][2];
    #pragma unroll
    for (int rt = 0; rt < 2; ++rt)
      #pragma unroll
      for (int ct = 0; ct < 2; ++ct)
        #pragma unroll
        for (int r = 0; r < 16; ++r) acc[rt][ct][r] = 0.f;
    gemm_phase_sw(e1b, Bw2, c31, hi, acc, bq2);
    #pragma unroll
    for (int rt = 0; rt < 2; ++rt){
      float pv = 0.f;
      #pragma unroll
      for (int ct = 0; ct < 2; ++ct){
        #pragma unroll
        for (int q = 0; q < 4; ++q){
          f32x4 bcv = *reinterpret_cast<const f32x4*>(bpool + 512 + colbase + ct*32 + 8*q + 4*hi);
          f32x4 wcv = *reinterpret_cast<const f32x4*>(bpool + 1024 + colbase + ct*32 + 8*q + 4*hi);
          #pragma unroll
          for (int j = 0; j < 4; ++j)
            pv += silu_f(acc[rt][ct][4*q+j] + bcv[j]) * wcv[j];
        }
      }
      pv += __shfl_xor(pv, 32, 64);
      if (hi == 0) cupart[wid][rt*32 + c31] = pv;
    }
  }
  __syncthreads();

  if (tid < TE){
    float cu0 = 0.f;
    #pragma unroll
    for (int w = 0; w < 8; ++w) cu0 += cupart[w][tid];
    float cu = fminf(fmaxf(cu0, -1.f), 1.f);
    if (!isfinite(cu0)) cu = 0.f;
    cuf[tid] = cu;
  }
  __syncthreads();

  if (tid < 3){
    int d = tid;
    unsigned long long m = segmask;
    float a = 0.f;
    #pragma unroll
    for (int e = 0; e < TE; ++e){
      if (e > 0 && ((m >> e) & 1)){
        atomicAdd(&pos_out[(size_t)rl[e-1]*3 + d], a);
        a = 0.f;
      }
      a += diffs[d][e] * cuf[e];
    }
    atomicAdd(&pos_out[(size_t)rl[TE-1]*3 + d], a);
  }
}

// ------------------------------------------- fused node MLP (n1 + n2) ----
// 32 rows per wg. GEMM1 (K=1024) -> h1 tile in LDS (reusing At) -> GEMM2
// (K=256) -> hout. Saves the h1 HBM round-trip and one kernel launch.
__global__ __launch_bounds__(256) void node_kernel(const float* __restrict__ h,
                                                   const float* __restrict__ agg,
                                                   const __bf16* __restrict__ wn1p,
                                                   const float* __restrict__ bn1,
                                                   const __bf16* __restrict__ wn2p,
                                                   const float* __restrict__ bn2,
                                                   float* __restrict__ hout){
  __shared__ __align__(16) __bf16 At[32*1024];  // 64KB; first 16KB reused for h1 tile
  int tid = threadIdx.x;
  int r0 = blockIdx.x * 32;
  char* ab = (char*)At;
  for (int it = 0; it < 32; ++it){
    int idx = it*1024 + tid*4;
    int row = idx >> 10, col = idx & 1023;
    float4 v;
    if (col < 512) v = *reinterpret_cast<const float4*>(h   + (size_t)(r0+row)*512 + col);
    else           v = *reinterpret_cast<const float4*>(agg + (size_t)(r0+row)*512 + (col-512));
    bf16x4 p = {(__bf16)v.x, (__bf16)v.y, (__bf16)v.z, (__bf16)v.w};
    *reinterpret_cast<bf16x4*>(ab + row*2048 + ((col*2) ^ ((row&7)<<4))) = p;
  }
  __syncthreads();
  int lane = tid & 63, wid = tid >> 6;
  int col16 = lane & 15, g = lane >> 4;
  int rw = wid & 1, cw = wid >> 1;
  int arow = rw*16 + col16;

  // GEMM1: h1 = silu(x @ Wn1^T + bn1), per-wave 16 rows x 128 cols
  f32x4 acc[8];
  #pragma unroll
  for (int t = 0; t < 8; ++t) acc[t] = f32x4{0.f,0.f,0.f,0.f};
  for (int kk = 0; kk < 32; ++kk){
    bf16x8 af = *reinterpret_cast<const bf16x8*>(ab + arow*2048 + ((kk*64 + g*16) ^ ((arow&7)<<4)));
    #pragma unroll
    for (int t = 0; t < 8; ++t){
      bf16x8 bfr = *reinterpret_cast<const bf16x8*>(wn1p + (size_t)(((cw*8+t)*32+kk)*512) + lane*8);
      acc[t] = mfma16(af, bfr, acc[t]);
    }
  }
  __syncthreads();   // all At reads done -> safe to overwrite with h1 tile

  // write h1 tile [32][256] bf16 (row stride 512B, swizzled) into At space
  #pragma unroll
  for (int t = 0; t < 8; ++t){
    int oc = cw*128 + t*16 + col16;
    #pragma unroll
    for (int i2 = 0; i2 < 4; ++i2){
      int row = rw*16 + g*4 + i2;
      *reinterpret_cast<__bf16*>(ab + row*512 + ((oc*2) ^ ((row&7)<<4))) =
          (__bf16)silu_f(acc[t][i2] + bn1[oc]);
    }
  }
  __syncthreads();

  // GEMM2: hout = h1 @ Wn2^T + bn2 (K=256), per-wave 16 rows x 128 cols
  f32x4 acc2[8];
  #pragma unroll
  for (int t = 0; t < 8; ++t) acc2[t] = f32x4{0.f,0.f,0.f,0.f};
  for (int kk = 0; kk < 8; ++kk){
    bf16x8 af = *reinterpret_cast<const bf16x8*>(ab + arow*512 + ((kk*64 + g*16) ^ ((arow&7)<<4)));
    #pragma unroll
    for (int t = 0; t < 8; ++t){
      bf16x8 bfr = *reinterpret_cast<const bf16x8*>(wn2p + (size_t)(((cw*8+t)*8+kk)*512) + lane*8);
      acc2[t] = mfma16(af, bfr, acc2[t]);
    }
  }
  #pragma unroll
  for (int t = 0; t < 8; ++t){
    int oc = cw*128 + t*16 + col16;
    #pragma unroll
    for (int i2 = 0; i2 < 4; ++i2){
      int row = r0 + rw*16 + g*4 + i2;
      hout[(size_t)row*256 + oc] = acc2[t][i2] + bn2[oc];
    }
  }
}

// -------------------------------------------------------------- launch ----
extern "C" void kernel_launch(void* const* d_in, const int* in_sizes, int n_in,
                              void* d_out, int out_size, void* d_ws, size_t ws_size,
                              hipStream_t stream){
  const float* h   = (const float*)d_in[0];
  const int*   ei  = (const int*)d_in[1];
  const float* ea  = (const float*)d_in[2];
  const float* pos = (const float*)d_in[3];
  const float* We1 = (const float*)d_in[4];
  const float* be1 = (const float*)d_in[5];
  const float* We2 = (const float*)d_in[6];
  const float* be2 = (const float*)d_in[7];
  const float* Wc1 = (const float*)d_in[8];
  const float* bc1 = (const float*)d_in[9];
  const float* Wc2 = (const float*)d_in[10];
  const float* Wn1 = (const float*)d_in[11];
  const float* bn1 = (const float*)d_in[12];
  const float* Wn2 = (const float*)d_in[13];
  const float* bn2 = (const float*)d_in[14];

  char* ws = (char*)d_ws;
  size_t off = 0;
  auto carve = [&](size_t bytes) -> char* {
    char* p = ws + off; off += (bytes + 255) & ~(size_t)255; return p;
  };
  __bf16* wabp  = (__bf16*)carve((size_t)1024*512*2);
  __bf16* weaTp = (__bf16*)carve((size_t)512*64*2);
  __bf16* we2p  = (__bf16*)carve((size_t)512*512*2);
  __bf16* wc1p  = (__bf16*)carve((size_t)512*512*2);
  __bf16* wn1p  = (__bf16*)carve((size_t)256*1024*2);
  __bf16* wn2p  = (__bf16*)carve((size_t)256*256*2);
  __bf16* AB    = (__bf16*)carve((size_t)N_NODES*1024*2);
  float*  agg   = (float*) carve((size_t)N_NODES*512*4);
  int*    deg    = (int*) carve((size_t)N_NODES*4);
  int*    basep  = (int*) carve((size_t)N_NODES*4);
  int*    cursor = (int*) carve((size_t)N_NODES*4);
  int*    perm   = (int*) carve((size_t)N_EDGES*4);

  float* hout = (float*)d_out;
  float* pout = (float*)d_out + (size_t)N_NODES*256;

  hipMemsetAsync(agg, 0, (size_t)N_NODES*512*4, stream);
  hipMemsetAsync(deg, 0, (size_t)N_NODES*4, stream);
  hipMemsetAsync(cursor, 0, (size_t)N_NODES*4, stream);
  hipMemcpyAsync((void*)pout, (const void*)pos, (size_t)N_NODES*3*4,
                 hipMemcpyDeviceToDevice, stream);

  prep_kernel<<<2048, 256, 0, stream>>>(We1, be1, We2, Wc1, Wn1, Wn2, ei,
                                        wabp, weaTp, we2p, wc1p, wn1p, wn2p, deg);
  scan_kernel<<<1, 1024, 0, stream>>>(deg, basep);
  scatter_kernel<<<N_EDGES/256, 256, 0, stream>>>(ei, basep, cursor, perm);
  gemm_ab_kernel<<<512, 256, 0, stream>>>(h, wabp, AB);
  edge_kernel<<<N_EDGES/TE, 512, 0, stream>>>(ei, perm, ea, pos, AB, weaTp, we2p, wc1p,
                                              be2, bc1, Wc2, agg, pout);
  node_kernel<<<N_NODES/32, 256, 0, stream>>>(h, agg, wn1p, bn1, wn2p, bn2, hout);
}